// Round 6
// baseline (368.984 us; speedup 1.0000x reference)
//
#include <hip/hip_runtime.h>
#include <cstdint>

// ---- JAX PRNG mode switches -------------------------------------------------
#define JPART 1
#define PART_XOR 1

constexpr uint32_t N20   = 1u << 20;
constexpr uint32_t NHALF = 1u << 19;
constexpr uint32_t NSPEC = NHALF + 1;
constexpr uint32_t SPEC_STRIDE = 524544;

struct Hdr {
  float e_r, e_i, amp_r, amp_i;
  int   phi_r, phi_i;
  float nhe_r, nhe_i;
  float scale_s[4];
};
struct KeyArgs { uint32_t k[8][2]; };

typedef __attribute__((ext_vector_type(8))) short short8;
typedef __attribute__((ext_vector_type(16))) float f32x16;

__device__ inline f32x16 zero16() {
  f32x16 v;
  #pragma unroll
  for (int i = 0; i < 16; ++i) v[i] = 0.f;
  return v;
}

__device__ inline unsigned short f2bf(float f) {
  uint32_t u = __float_as_uint(f);
  return (unsigned short)((u + 0x7fffu + ((u >> 16) & 1u)) >> 16);
}

// ---- Threefry2x32-20 (exact JAX cipher) ------------------------------------
__host__ __device__ inline void tf2x32(uint32_t k0, uint32_t k1, uint32_t x0, uint32_t x1,
                                       uint32_t& o0, uint32_t& o1) {
  const uint32_t ks0 = k0, ks1 = k1, ks2 = k0 ^ k1 ^ 0x1BD11BDAu;
  const uint32_t ks[3] = { ks0, ks1, ks2 };
  x0 += ks0; x1 += ks1;
  const int rot[2][4] = { {13,15,26,6}, {17,29,16,24} };
  for (int g = 0; g < 5; ++g) {
    const int* rr = rot[g & 1];
    for (int i = 0; i < 4; ++i) {
      x0 += x1;
      x1 = (x1 << rr[i]) | (x1 >> (32 - rr[i]));
      x1 ^= x0;
    }
    x0 += ks[(g + 1) % 3];
    x1 += ks[(g + 2) % 3] + (uint32_t)(g + 1);
  }
  o0 = x0; o1 = x1;
}

// ---- XLA ErfInv32 polynomial ------------------------------------------------
__device__ inline float erfinv_xla(float x) {
  float w = -log1pf(-x * x);
  float p;
  if (w < 5.0f) {
    w -= 2.5f;
    p = 2.81022636e-08f;
    p = fmaf(p, w, 3.43273939e-07f);
    p = fmaf(p, w, -3.5233877e-06f);
    p = fmaf(p, w, -4.39150654e-06f);
    p = fmaf(p, w, 0.00021858087f);
    p = fmaf(p, w, -0.00125372503f);
    p = fmaf(p, w, -0.00417768164f);
    p = fmaf(p, w, 0.246640727f);
    p = fmaf(p, w, 1.50140941f);
  } else {
    w = sqrtf(w) - 3.0f;
    p = -0.000200214257f;
    p = fmaf(p, w, 0.000100950558f);
    p = fmaf(p, w, 0.00134934322f);
    p = fmaf(p, w, -0.00367342844f);
    p = fmaf(p, w, 0.00573950773f);
    p = fmaf(p, w, -0.0076224613f);
    p = fmaf(p, w, 0.00943887047f);
    p = fmaf(p, w, 1.00167406f);
    p = fmaf(p, w, 2.83297682f);
  }
  return p * x;
}

__device__ inline float normal_from_bits(uint32_t bits) {
  uint32_t fb = (bits >> 9) | 0x3f800000u;
  float f = __uint_as_float(fb) - 1.0f;
  const float LO = -0.99999994f;
  float u = f * 2.0f + LO;
  u = fmaxf(LO, u);
  return 1.41421356f * erfinv_xla(u);
}

__device__ inline float sscale_f(uint32_t k, float nhe) {
  uint32_t kk = k ? k : 1u;
  return powf((float)kk * (1.0f / 1048576.0f), nhe);
}

__device__ inline float2 cmul(float2 a, float2 b) {
  return make_float2(a.x * b.x - a.y * b.y, a.x * b.y + a.y * b.x);
}
__device__ inline float2 wexp(float u) {
  float s, c; sincospif(2.0f * u, &s, &c); return make_float2(c, s);
}
__device__ inline float2 cadd(float2 a, float2 b){ return make_float2(a.x+b.x, a.y+b.y); }
__device__ inline float2 csub(float2 a, float2 b){ return make_float2(a.x-b.x, a.y-b.y); }
__device__ inline float2 cmuli(float2 a){ return make_float2(-a.y, a.x); }  // * (+i)

// LDS address swizzle for the FFT exchanges: <=4-way on all phases
__device__ inline int sA(int p) { return p ^ (((p >> 6) & 3) << 2) ^ ((p >> 8) & 3); }

// radix-4 DIF butterfly, sign +i, with twiddle W = omega^{n'}
__device__ inline void bfly(float2& y0, float2& y1, float2& y2, float2& y3, float2 W) {
  float2 a = cadd(y0, y2), b = csub(y0, y2);
  float2 c = cadd(y1, y3), d = cmuli(csub(y1, y3));
  float2 W2 = cmul(W, W), W3 = cmul(W2, W);
  y0 = cadd(a, c);
  y1 = cmul(cadd(b, d), W);
  y2 = cmul(csub(a, c), W2);
  y3 = cmul(csub(b, d), W3);
}

// 1024-pt FFT core (sign +), 64 threads, 16 pts/thread, 2 barriers.
// In: r[s] = x[64*s + w]. Out: rc[4*e1+e0] = X[256*e0 + 64*e1 + klo(w)],
// klo = 16*(w&3) + 4*((w>>2)&3) + (w>>4).
__device__ inline void fft1024_core(float2* r, float2* rc, float2* buf, int w) {
  // stage 0 (N=1024, combines e4) + stage 1 (N=256, combines e3)
  #pragma unroll
  for (int e3 = 0; e3 < 4; ++e3) {
    float2 W = wexp((float)((e3 << 6) + w) * (1.0f / 1024.0f));
    bfly(r[e3], r[e3 + 4], r[e3 + 8], r[e3 + 12], W);
  }
  {
    float2 W = wexp((float)w * (1.0f / 256.0f));
    #pragma unroll
    for (int e4 = 0; e4 < 4; ++e4)
      bfly(r[(e4 << 2) + 0], r[(e4 << 2) + 1], r[(e4 << 2) + 2], r[(e4 << 2) + 3], W);
  }
  #pragma unroll
  for (int s = 0; s < 16; ++s) buf[sA((s << 6) + w)] = r[s];
  __syncthreads();
  // phase B: thread digits (e4,e3,e0); stage 2 (combines e2) + stage 3 (combines e1)
  {
    const int e0 = w & 3;
    const int pbase = ((w >> 4) << 8) + (((w >> 2) & 3) << 6) + e0;
    float2 rb[16];
    #pragma unroll
    for (int e2 = 0; e2 < 4; ++e2)
      #pragma unroll
      for (int e1 = 0; e1 < 4; ++e1)
        rb[(e2 << 2) + e1] = buf[sA(pbase + (e2 << 4) + (e1 << 2))];
    #pragma unroll
    for (int e1 = 0; e1 < 4; ++e1) {
      float2 W = wexp((float)((e1 << 2) + e0) * (1.0f / 64.0f));
      bfly(rb[e1], rb[e1 + 4], rb[e1 + 8], rb[e1 + 12], W);
    }
    {
      float2 W = wexp((float)e0 * (1.0f / 16.0f));
      #pragma unroll
      for (int e2 = 0; e2 < 4; ++e2)
        bfly(rb[(e2 << 2) + 0], rb[(e2 << 2) + 1], rb[(e2 << 2) + 2], rb[(e2 << 2) + 3], W);
    }
    #pragma unroll
    for (int e2 = 0; e2 < 4; ++e2)
      #pragma unroll
      for (int e1 = 0; e1 < 4; ++e1)
        buf[sA(pbase + (e2 << 4) + (e1 << 2))] = rb[(e2 << 2) + e1];
  }
  __syncthreads();
  // phase C: thread digits (e4,e3,e2); stage 4 (combines e0), W = 1
  {
    const int cbase = ((w >> 4) << 8) + (((w >> 2) & 3) << 6) + ((w & 3) << 4);
    #pragma unroll
    for (int e1 = 0; e1 < 4; ++e1)
      #pragma unroll
      for (int e0 = 0; e0 < 4; ++e0)
        rc[(e1 << 2) + e0] = buf[sA(cbase + (e1 << 2) + e0)];
    #pragma unroll
    for (int e1 = 0; e1 < 4; ++e1) {
      float2 x0 = rc[(e1 << 2)], x1 = rc[(e1 << 2) + 1], x2 = rc[(e1 << 2) + 2], x3 = rc[(e1 << 2) + 3];
      float2 a = cadd(x0, x2), b = csub(x0, x2);
      float2 c = cadd(x1, x3), d = cmuli(csub(x1, x3));
      rc[(e1 << 2)]     = cadd(a, c);
      rc[(e1 << 2) + 1] = cadd(b, d);
      rc[(e1 << 2) + 2] = csub(a, c);
      rc[(e1 << 2) + 3] = csub(b, d);
    }
  }
}

// ---- scalars ----------------------------------------------------------------
__device__ inline float med8_dev(const float* p) {
  float v[8];
  for (int i = 0; i < 8; ++i) v[i] = p[i];
  for (int i = 1; i < 8; ++i) { float key = v[i]; int j = i - 1;
    while (j >= 0 && v[j] > key) { v[j + 1] = v[j]; --j; } v[j + 1] = key; }
  return 0.5f * (v[3] + v[4]);
}

__global__ void k_scalars(Hdr* h, const float* er, const float* ei, const float* ar,
                          const float* ai, const float* pr, const float* pim) {
  if (threadIdx.x || blockIdx.x) return;
  float mer = med8_dev(er), mei = med8_dev(ei);
  h->e_r = mer; h->e_i = mei;
  h->amp_r = med8_dev(ar); h->amp_i = med8_dev(ai);
  h->phi_r = (int)med8_dev(pr);
  h->phi_i = (int)med8_dev(pim);
  h->nhe_r = -0.5f * mer; h->nhe_i = -0.5f * mei;
}

__global__ void k_sumw2(const Hdr* __restrict__ h, float* __restrict__ partials) {
  __shared__ float sr_[256], si_[256];
  const float nher = h->nhe_r, nhei = h->nhe_i;
  float sr = 0.f, si = 0.f;
  for (int j = 0; j < 4; ++j) {
    uint32_t k = (uint32_t)(blockIdx.x * 1024 + j * 256 + threadIdx.x) + 1u;
    float fk = (float)k * (1.0f / 1048576.0f);
    float wr = powf(fk, nher), wi = powf(fk, nhei);
    if (k == NHALF) { wr *= 0.5f; wi *= 0.5f; }
    sr += wr * wr; si += wi * wi;
  }
  sr_[threadIdx.x] = sr; si_[threadIdx.x] = si; __syncthreads();
  for (int off = 128; off > 0; off >>= 1) {
    if ((int)threadIdx.x < off) { sr_[threadIdx.x] += sr_[threadIdx.x + off];
                                  si_[threadIdx.x] += si_[threadIdx.x + off]; }
    __syncthreads();
  }
  if (!threadIdx.x) { partials[blockIdx.x * 2] = sr_[0]; partials[blockIdx.x * 2 + 1] = si_[0]; }
}

__global__ void k_sumw2_fin(Hdr* h, const float* partials) {
  if (threadIdx.x || blockIdx.x) return;
  float Sr = 0.f, Si = 0.f;
  for (int b = 0; b < 512; ++b) { Sr += partials[b * 2]; Si += partials[b * 2 + 1]; }
  float sig_r = 2.0f * sqrtf(Sr) * (1.0f / 1048576.0f);
  float sig_i = 2.0f * sqrtf(Si) * (1.0f / 1048576.0f);
  float s0 = h->amp_r / (sig_r * 1048576.0f);
  float s1 = (h->amp_i * h->amp_i) / (sig_i * 1048576.0f);
  h->scale_s[0] = s0; h->scale_s[1] = s1; h->scale_s[2] = s0; h->scale_s[3] = s1;
}

// ---- wsum -------------------------------------------------------------------
__global__ void k_wsum(const float* __restrict__ w1, const float* __restrict__ w2,
                       float2* __restrict__ wsum) {
  int idx = blockIdx.x * 256 + threadIdx.x;
  int sel = idx >> 16, rem = idx & 65535;
  const float* w = sel ? w2 : w1;
  int c = rem >> 10, m1 = (rem >> 5) & 31, m2 = rem & 31;
  size_t base = (size_t)c * 131072 + (size_t)m1 * 64 + (size_t)m2 * 2;
  float sr = 0.f, si = 0.f;
  for (int oc = 0; oc < 64; ++oc) { sr += w[base + (size_t)oc * 2048]; si += w[base + (size_t)oc * 2048 + 1]; }
  wsum[idx] = make_float2(sr, si);
}

// ---- noise spectra ----------------------------------------------------------
__global__ void k_noise_spec(float2* __restrict__ spec, const Hdr* __restrict__ h, KeyArgs ka) {
  const int combo = blockIdx.y;
  const int s = combo >> 1, part = combo & 1;
  const float nhe = ((s & 1) == 0) ? h->nhe_r : h->nhe_i;
  const uint32_t K0 = ka.k[combo][0], K1 = ka.k[combo][1];
  float2* sp = spec + (size_t)s * SPEC_STRIDE;
  const int i = blockIdx.x * 256 + threadIdx.x;
#if JPART
  if (i >= (int)NSPEC) return;
  uint32_t o0, o1; tf2x32(K0, K1, 0u, (uint32_t)i, o0, o1);
#if PART_XOR
  uint32_t bits = o0 ^ o1;
#else
  uint32_t bits = o1;
#endif
  float val = normal_from_bits(bits) * sscale_f((uint32_t)i, nhe);
  if (i == 0 || i == (int)NHALF) val = part ? 0.0f : val * 1.41421356f;
  if (part) sp[i].y = val; else sp[i].x = val;
#else
  if (i >= 262145) return;
  uint32_t c1 = (i == 262144) ? 0u : (uint32_t)(i + 262145);
  uint32_t o0, o1; tf2x32(K0, K1, (uint32_t)i, c1, o0, o1);
  {
    uint32_t k = (uint32_t)i;
    float v = normal_from_bits(o0) * sscale_f(k, nhe);
    if (k == 0u) v = part ? 0.0f : v * 1.41421356f;
    if (part) sp[k].y = v; else sp[k].x = v;
  }
  if (i < 262144) {
    uint32_t k = (uint32_t)i + 262145u;
    float v = normal_from_bits(o1) * sscale_f(k, nhe);
    if (k == NHALF) v = part ? 0.0f : v * 1.41421356f;
    if (part) sp[k].y = v; else sp[k].x = v;
  }
#endif
}

// ---- irfft(2^20) stage 1: per k1, FFT over k2; G[arr][k1][j2] ---------------
__global__ __launch_bounds__(256) void k_fft_s1(const float2* __restrict__ spec,
                                                float2* __restrict__ G) {
  __shared__ float2 buf4[4][1024];
  const int b = blockIdx.x;
  const int lin = (b & 7) * 128 + (b >> 3);        // XCD-chunked (1024 = 8*128)
  const int arr = lin >> 8;
  const int g = threadIdx.x >> 6, w = threadIdx.x & 63;
  const int k1 = ((lin & 255) << 2) + g;
  const float2* sp = spec + (size_t)arr * SPEC_STRIDE;

  float2 r[16], rc[16];
  #pragma unroll
  for (int s = 0; s < 16; ++s) {
    int p = (s << 6) + w;
    uint32_t k = (uint32_t)k1 + ((uint32_t)p << 10);
    float2 cv;
    if (k <= NHALF) cv = sp[k];
    else { float2 v = sp[N20 - k]; cv = make_float2(v.x, -v.y); }
    r[s] = cv;
  }
  fft1024_core(r, rc, buf4[g], w);
  float2* gp = G + ((size_t)arr << 20) + ((size_t)k1 << 10);
  const int klo = ((w & 3) << 4) + (((w >> 2) & 3) << 2) + (w >> 4);
  #pragma unroll
  for (int e1 = 0; e1 < 4; ++e1)
    #pragma unroll
    for (int e0 = 0; e0 < 4; ++e0) {
      int k = (e0 << 8) + (e1 << 6) + klo;
      float2 tw = wexp((float)(k * k1) * (1.0f / 1048576.0f));
      gp[k] = cmul(rc[(e1 << 2) + e0], tw);
    }
}

// ---- stage 2: per j2, FFT over k1 -------------------------------------------
__global__ __launch_bounds__(256) void k_fft_s2(const float2* __restrict__ G,
                                                float* __restrict__ noise,
                                                const Hdr* __restrict__ h) {
  __shared__ float2 buf4[4][1024];
  const int b = blockIdx.x;
  const int lin = (b & 7) * 128 + (b >> 3);
  const int arr = lin >> 8;
  const int g = threadIdx.x >> 6, w = threadIdx.x & 63;
  const int j2 = ((lin & 255) << 2) + g;

  float2 r[16], rc[16];
  const float2* gp = G + ((size_t)arr << 20) + (size_t)j2;
  #pragma unroll
  for (int s = 0; s < 16; ++s) r[s] = gp[(size_t)((s << 6) + w) << 10];
  fft1024_core(r, rc, buf4[g], w);
  const float sc = h->scale_s[arr];
  float* np_ = noise + ((size_t)arr << 20) + ((size_t)j2 << 10);
  const int klo = ((w & 3) << 4) + (((w >> 2) & 3) << 2) + (w >> 4);
  #pragma unroll
  for (int e1 = 0; e1 < 4; ++e1)
    #pragma unroll
    for (int e0 = 0; e0 < 4; ++e0) {
      int k = (e0 << 8) + (e1 << 6) + klo;
      np_[k] = rc[(e1 << 2) + e0].x * sc;
    }
}

// ---- constants: A_E, B2T (inverse) + ET, Fc, Fs, Fns (forward) --------------
__global__ __launch_bounds__(256) void k_prep(unsigned short* __restrict__ A_E,
                                              unsigned short* __restrict__ B2T,
                                              unsigned short* __restrict__ ET,
                                              unsigned short* __restrict__ Fc,
                                              unsigned short* __restrict__ Fs,
                                              unsigned short* __restrict__ Fns) {
  int t = blockIdx.x * 256 + threadIdx.x;
  if (t < 32768) {
    int y = t >> 7, p = t & 127;
    int kyp = p & 63; int ky = (kyp < 32) ? kyp : kyp + 192;
    float s, c; sincospif(2.0f * (float)((ky * y) & 255) * (1.0f / 256.0f), &s, &c);
    A_E[t] = f2bf((p < 64) ? c : s);
  } else if (t < 49152) {
    int u = t - 32768;
    int x = u >> 6, j = u & 63, kx = j & 31;
    float s, c; sincospif(2.0f * (float)((kx * x) & 255) * (1.0f / 256.0f), &s, &c);
    float v = (j < 32) ? ((kx == 0) ? 1.0f : 2.0f * c)
                       : ((kx == 0) ? 0.0f : -2.0f * s);
    B2T[u] = f2bf(v * (1.0f / 65536.0f));
  } else if (t < 65536) {
    int u = t - 49152;                      // ET[col 64][xx 256]
    int col = u >> 8, xx = u & 255; int kx = col & 31;
    float s, c; sincospif(2.0f * (float)((kx * xx) & 255) * (1.0f / 256.0f), &s, &c);
    ET[u] = f2bf((col < 32) ? c : -s);
  } else if (t < 114688) {
    int u = (t - 65536) & 16383;            // F*[kyp 64][y 256]
    int which = (t - 65536) >> 14;          // 0:Fc 1:Fs 2:Fns
    int kyp = u >> 8, y = u & 255; int ky = (kyp < 32) ? kyp : kyp + 192;
    float s, c; sincospif(2.0f * (float)((ky * y) & 255) * (1.0f / 256.0f), &s, &c);
    if (which == 0) Fc[u] = f2bf(c);
    else if (which == 1) Fs[u] = f2bf(s);
    else Fns[u] = f2bf(-s);
  }
}

// ---- fused forward + inverse per image --------------------------------------
__global__ __launch_bounds__(256) void k_fused(const float* __restrict__ x,
    const float2* __restrict__ wsum, const float* __restrict__ noise,
    const Hdr* __restrict__ h,
    const unsigned short* __restrict__ ET, const unsigned short* __restrict__ Fc,
    const unsigned short* __restrict__ Fs, const unsigned short* __restrict__ Fns,
    const unsigned short* __restrict__ A_E, const unsigned short* __restrict__ B2T,
    float* __restrict__ out) {
  __shared__ char lds[65536];
  char* X1T = lds + 32768;                    // [64 col][256 y] bf16, swizzled
  const int bc = blockIdx.x, t = threadIdx.x;
  const int c = bc & 63;
  const int l = t & 63, w = t >> 6, lr = l & 31, kg = l >> 5;
  const int rt = w >> 1, ct = w & 1;
  const float* xim = x + ((size_t)bc << 16);

  // ---- forward stage 1: X1T = bf16(x) . ET^T, 4 y-tiles
  for (int yt = 0; yt < 4; ++yt) {
    __syncthreads();
    #pragma unroll
    for (int i = 0; i < 16; ++i) {
      int f4 = i * 256 + t;
      int r = f4 >> 6, c4 = f4 & 63;
      float4 v = *(const float4*)(xim + (size_t)(((yt << 6) + r) << 8) + (c4 << 2));
      ushort4 b4; b4.x = f2bf(v.x); b4.y = f2bf(v.y); b4.z = f2bf(v.z); b4.w = f2bf(v.w);
      int byte = ((r << 9) + (c4 << 3)) ^ ((r & 7) << 4);
      *(ushort4*)(lds + byte) = b4;
    }
    __syncthreads();
    f32x16 a1 = zero16();
    const int arow = (rt << 5) + lr;
    const int bcol = (ct << 5) + lr;
    #pragma unroll
    for (int s = 0; s < 16; ++s) {
      short8 af = *(const short8*)(lds + (((arow << 9) + (s << 5) + (kg << 4)) ^ ((arow & 7) << 4)));
      short8 bf = *(const short8*)(ET + (bcol << 8) + (s << 4) + (kg << 3));
      a1 = __builtin_amdgcn_mfma_f32_32x32x16_bf16(af, bf, a1, 0, 0, 0);
    }
    #pragma unroll
    for (int r4 = 0; r4 < 4; ++r4) {
      int y0 = (yt << 6) + (rt << 5) + (r4 << 3) + (kg << 2);
      ushort4 p4;
      p4.x = f2bf(a1[r4 * 4 + 0]); p4.y = f2bf(a1[r4 * 4 + 1]);
      p4.z = f2bf(a1[r4 * 4 + 2]); p4.w = f2bf(a1[r4 * 4 + 3]);
      int byte = ((bcol << 9) + (y0 << 1)) ^ ((bcol & 7) << 4);
      *(ushort4*)(X1T + byte) = p4;
    }
  }
  __syncthreads();

  // ---- forward stage 2: O = F . X1
  {
    const int re_im = w >> 1, kt = w & 1;
    const unsigned short* A1p = re_im ? Fns : Fs;
    const int b0row = (re_im ? 32 : 0) + lr;
    const int b1row = (re_im ? 0 : 32) + lr;
    const int a2row = (kt << 5) + lr;
    f32x16 a2 = zero16();
    #pragma unroll
    for (int s = 0; s < 16; ++s) {
      short8 a0f = *(const short8*)(Fc  + (a2row << 8) + (s << 4) + (kg << 3));
      short8 a1f = *(const short8*)(A1p + (a2row << 8) + (s << 4) + (kg << 3));
      short8 b0f = *(const short8*)(X1T + (((b0row << 9) + (s << 5) + (kg << 4)) ^ ((b0row & 7) << 4)));
      short8 b1f = *(const short8*)(X1T + (((b1row << 9) + (s << 5) + (kg << 4)) ^ ((b1row & 7) << 4)));
      a2 = __builtin_amdgcn_mfma_f32_32x32x16_bf16(a0f, b0f, a2, 0, 0, 0);
      a2 = __builtin_amdgcn_mfma_f32_32x32x16_bf16(a1f, b1f, a2, 0, 0, 0);
    }
    float* Osm = (float*)(lds + (re_im << 13));   // re @0, im @8192
    #pragma unroll
    for (int i = 0; i < 16; ++i) {
      int row = (kt << 5) + (i & 3) + ((i >> 2) << 3) + (kg << 2);
      Osm[(row << 5) + lr] = a2[i];
    }
  }
  __syncthreads();

  // ---- epilogue: wsum mul + noise subtract -> ofs (LDS float2, [32768,49152))
  {
    const int phir = h->phi_r, phii = h->phi_i;
    const float* Ore = (const float*)lds;
    const float* Oim = (const float*)(lds + 8192);
    float2* ofs2 = (float2*)(lds + 32768);
    #pragma unroll
    for (int r = 0; r < 8; ++r) {
      int idx = (r << 8) + t;
      int kyp = idx >> 5, kx = idx & 31;
      int sel = kyp >> 5, m1 = kyp & 31;
      float2 av = make_float2(Ore[idx], Oim[idx]);
      float2 wv = wsum[((size_t)sel << 16) + (size_t)(((c << 5) | m1) << 5) + (size_t)kx];
      float2 v;
      v.x = av.x * wv.x - av.y * wv.y;
      v.y = av.x * wv.y + av.y * wv.x;
      uint32_t p = ((uint32_t)((bc << 5) | m1) << 5) | (uint32_t)kx;
      uint32_t qr = (p - (uint32_t)phir) & (N20 - 1u);
      uint32_t qi = (p - (uint32_t)phii) & (N20 - 1u);
      const float* nr = noise + ((size_t)(sel ? 2 : 0) << 20);
      const float* ni = noise + ((size_t)(sel ? 3 : 1) << 20);
      v.x -= nr[((qr & 1023u) << 10) | (qr >> 10)];
      v.y -= ni[((qi & 1023u) << 10) | (qi >> 10)];
      ofs2[idx] = v;
    }
  }
  __syncthreads();

  // ---- build Mt[64 j][128 p] bf16 swizzled at [49152,65536)
  {
    const float* ofs = (const float*)(lds + 32768);
    char* Mt = lds + 49152;
    #pragma unroll
    for (int i = 0; i < 32; ++i) {
      int idx = t + (i << 8);
      int p = idx >> 6, j = idx & 63;
      int kyp = p & 63;
      float v;
      if (p < 64) v = (j < 32) ? ofs[(kyp << 6) + (j << 1)]
                               : ofs[(kyp << 6) + ((j - 32) << 1) + 1];
      else        v = (j < 32) ? -ofs[(kyp << 6) + (j << 1) + 1]
                               : ofs[(kyp << 6) + ((j - 32) << 1)];
      int byte = ((j << 8) + (p << 1)) ^ ((j & 7) << 4);
      *(unsigned short*)(Mt + byte) = f2bf(v);
    }
  }
  __syncthreads();

  // ---- GEMM1: T = A_E . M ; Tb bf16 swizzled at [0,32768)
  {
    const char* Mt = lds + 49152;
    char* Tb = lds;
    f32x16 acc[2][2];
    acc[0][0] = zero16(); acc[0][1] = zero16(); acc[1][0] = zero16(); acc[1][1] = zero16();
    #pragma unroll
    for (int s = 0; s < 8; ++s) {
      short8 af[2], bf[2];
      #pragma unroll
      for (int rt2 = 0; rt2 < 2; ++rt2) {
        int row = (w << 6) + (rt2 << 5) + lr;
        af[rt2] = *(const short8*)(A_E + (row << 7) + (s << 4) + (kg << 3));
      }
      #pragma unroll
      for (int ct2 = 0; ct2 < 2; ++ct2) {
        int j = (ct2 << 5) + lr;
        int byte = ((j << 8) + (s << 5) + (kg << 4)) ^ ((j & 7) << 4);
        bf[ct2] = *(const short8*)(Mt + byte);
      }
      #pragma unroll
      for (int rt2 = 0; rt2 < 2; ++rt2)
        #pragma unroll
        for (int ct2 = 0; ct2 < 2; ++ct2)
          acc[rt2][ct2] = __builtin_amdgcn_mfma_f32_32x32x16_bf16(af[rt2], bf[ct2], acc[rt2][ct2], 0, 0, 0);
    }
    __syncthreads();   // Mt/Ore reads done block-wide before Tb overwrites [0,32K)? Tb disjoint from Mt; barrier orders Osm region reuse
    #pragma unroll
    for (int rt2 = 0; rt2 < 2; ++rt2)
      #pragma unroll
      for (int ct2 = 0; ct2 < 2; ++ct2)
        #pragma unroll
        for (int r = 0; r < 16; ++r) {
          int row = (w << 6) + (rt2 << 5) + (r & 3) + (((r >> 2) & 3) << 3) + (kg << 2);
          int col = (ct2 << 5) + lr;
          int byte = ((row << 7) + (col << 1)) ^ ((row & 7) << 4);
          *(unsigned short*)(Tb + byte) = f2bf(acc[rt2][ct2][r]);
        }
  }
  __syncthreads();

  // ---- GEMM2: out = T . B2
  {
    const char* Tb = lds;
    short8 ta[2][4];
    #pragma unroll
    for (int rt2 = 0; rt2 < 2; ++rt2)
      #pragma unroll
      for (int ks = 0; ks < 4; ++ks) {
        int row = (w << 6) + (rt2 << 5) + lr;
        int byte = ((row << 7) + (ks << 5) + (kg << 4)) ^ ((row & 7) << 4);
        ta[rt2][ks] = *(const short8*)(Tb + byte);
      }
    float* op = out + ((size_t)bc << 16);
    #pragma unroll
    for (int cc = 0; cc < 4; ++cc) {
      short8 b2[2][4];
      #pragma unroll
      for (int cx = 0; cx < 2; ++cx)
        #pragma unroll
        for (int ks = 0; ks < 4; ++ks) {
          int xx = (cc << 6) + (cx << 5) + lr;
          b2[cx][ks] = *(const short8*)(B2T + (xx << 6) + (ks << 4) + (kg << 3));
        }
      f32x16 a2[2][2];
      a2[0][0] = zero16(); a2[0][1] = zero16(); a2[1][0] = zero16(); a2[1][1] = zero16();
      #pragma unroll
      for (int ks = 0; ks < 4; ++ks)
        #pragma unroll
        for (int rt2 = 0; rt2 < 2; ++rt2)
          #pragma unroll
          for (int cx = 0; cx < 2; ++cx)
            a2[rt2][cx] = __builtin_amdgcn_mfma_f32_32x32x16_bf16(ta[rt2][ks], b2[cx][ks], a2[rt2][cx], 0, 0, 0);
      #pragma unroll
      for (int rt2 = 0; rt2 < 2; ++rt2)
        #pragma unroll
        for (int cx = 0; cx < 2; ++cx)
          #pragma unroll
          for (int r = 0; r < 16; ++r) {
            int row = (w << 6) + (rt2 << 5) + (r & 3) + (((r >> 2) & 3) << 3) + (kg << 2);
            int xx = (cc << 6) + (cx << 5) + lr;
            op[(row << 8) + xx] = a2[rt2][cx][r];
          }
    }
  }
}

// ---- host -------------------------------------------------------------------
extern "C" void kernel_launch(void* const* d_in, const int* in_sizes, int n_in,
                              void* d_out, int out_size, void* d_ws, size_t ws_size,
                              hipStream_t stream) {
  (void)in_sizes; (void)n_in; (void)out_size; (void)ws_size;
  const float* x   = (const float*)d_in[0];
  const float* w1  = (const float*)d_in[1];
  const float* w2  = (const float*)d_in[2];
  const float* er  = (const float*)d_in[3];
  const float* ei  = (const float*)d_in[4];
  const float* ar  = (const float*)d_in[5];
  const float* ai  = (const float*)d_in[6];
  const float* pr  = (const float*)d_in[7];
  const float* pim = (const float*)d_in[8];
  float* out = (float*)d_out;

  char* ws = (char*)d_ws;
  Hdr*    hdr      = (Hdr*)ws;
  float*  partials = (float*)(ws + 0x1000);
  float2* wsum     = (float2*)(ws + 0x10000);
  unsigned short* A_E = (unsigned short*)(ws + 0x130000);
  unsigned short* B2T = (unsigned short*)(ws + 0x140000);
  unsigned short* ET  = (unsigned short*)(ws + 0x148000);
  unsigned short* Fc  = (unsigned short*)(ws + 0x150000);
  unsigned short* Fs  = (unsigned short*)(ws + 0x158000);
  unsigned short* Fns = (unsigned short*)(ws + 0x160000);
  float2* spec     = (float2*)(ws + 0x200000);
  float2* G        = (float2*)(ws + 0x1400000);
  float*  noise    = (float*)(ws + 0x3400000);

  auto splitk = [](const uint32_t k[2], uint32_t a[2], uint32_t b[2]) {
#if JPART
    tf2x32(k[0], k[1], 0u, 0u, a[0], a[1]);
    tf2x32(k[0], k[1], 0u, 1u, b[0], b[1]);
#else
    uint32_t r0[2], r1[2];
    tf2x32(k[0], k[1], 0u, 2u, r0[0], r0[1]);
    tf2x32(k[0], k[1], 1u, 3u, r1[0], r1[1]);
    a[0] = r0[0]; a[1] = r1[0]; b[0] = r0[1]; b[1] = r1[1];
#endif
  };
  uint32_t root[2] = { 0u, 42u };
  uint32_t kA[2], kB[2], k1A[2], k2A[2], k1B[2], k2B[2];
  splitk(root, kA, kB);
  splitk(kA, k1A, k2A);
  splitk(kB, k1B, k2B);
  KeyArgs ka;
  splitk(k1A, ka.k[0], ka.k[1]);
  splitk(k2A, ka.k[2], ka.k[3]);
  splitk(k1B, ka.k[4], ka.k[5]);
  splitk(k2B, ka.k[6], ka.k[7]);

  hipLaunchKernelGGL(k_scalars,    dim3(1),        dim3(64),  0, stream, hdr, er, ei, ar, ai, pr, pim);
  hipLaunchKernelGGL(k_sumw2,      dim3(512),      dim3(256), 0, stream, hdr, partials);
  hipLaunchKernelGGL(k_sumw2_fin,  dim3(1),        dim3(64),  0, stream, hdr, partials);
  hipLaunchKernelGGL(k_wsum,       dim3(512),      dim3(256), 0, stream, w1, w2, wsum);
  hipLaunchKernelGGL(k_prep,       dim3(448),      dim3(256), 0, stream, A_E, B2T, ET, Fc, Fs, Fns);
  hipLaunchKernelGGL(k_noise_spec, dim3(2049, 8),  dim3(256), 0, stream, spec, hdr, ka);
  hipLaunchKernelGGL(k_fft_s1,     dim3(1024),     dim3(256), 0, stream, spec, G);
  hipLaunchKernelGGL(k_fft_s2,     dim3(1024),     dim3(256), 0, stream, G, noise, hdr);
  hipLaunchKernelGGL(k_fused,      dim3(1024),     dim3(256), 0, stream, x, wsum, noise, hdr, ET, Fc, Fs, Fns, A_E, B2T, out);
}

// Round 7
// 366.633 us; speedup vs baseline: 1.0064x; 1.0064x over previous
//
#include <hip/hip_runtime.h>
#include <cstdint>

// ---- JAX PRNG mode switches -------------------------------------------------
#define JPART 1
#define PART_XOR 1

constexpr uint32_t N20   = 1u << 20;
constexpr uint32_t NHALF = 1u << 19;
constexpr uint32_t NSPEC = NHALF + 1;
constexpr uint32_t SPEC_STRIDE = 524544;

struct Hdr {
  float e_r, e_i, amp_r, amp_i;
  int   phi_r, phi_i;
  float nhe_r, nhe_i;
  float scale_s[4];
};
struct KeyArgs { uint32_t k[8][2]; };

typedef __attribute__((ext_vector_type(8))) short short8;
typedef __attribute__((ext_vector_type(16))) float f32x16;

__device__ inline f32x16 zero16() {
  f32x16 v;
  #pragma unroll
  for (int i = 0; i < 16; ++i) v[i] = 0.f;
  return v;
}

__device__ inline unsigned short f2bf(float f) {
  uint32_t u = __float_as_uint(f);
  return (unsigned short)((u + 0x7fffu + ((u >> 16) & 1u)) >> 16);
}

// ---- Threefry2x32-20 (exact JAX cipher) ------------------------------------
__host__ __device__ inline void tf2x32(uint32_t k0, uint32_t k1, uint32_t x0, uint32_t x1,
                                       uint32_t& o0, uint32_t& o1) {
  const uint32_t ks0 = k0, ks1 = k1, ks2 = k0 ^ k1 ^ 0x1BD11BDAu;
  const uint32_t ks[3] = { ks0, ks1, ks2 };
  x0 += ks0; x1 += ks1;
  const int rot[2][4] = { {13,15,26,6}, {17,29,16,24} };
  for (int g = 0; g < 5; ++g) {
    const int* rr = rot[g & 1];
    for (int i = 0; i < 4; ++i) {
      x0 += x1;
      x1 = (x1 << rr[i]) | (x1 >> (32 - rr[i]));
      x1 ^= x0;
    }
    x0 += ks[(g + 1) % 3];
    x1 += ks[(g + 2) % 3] + (uint32_t)(g + 1);
  }
  o0 = x0; o1 = x1;
}

// ---- XLA ErfInv32 polynomial ------------------------------------------------
__device__ inline float erfinv_xla(float x) {
  float w = -log1pf(-x * x);
  float p;
  if (w < 5.0f) {
    w -= 2.5f;
    p = 2.81022636e-08f;
    p = fmaf(p, w, 3.43273939e-07f);
    p = fmaf(p, w, -3.5233877e-06f);
    p = fmaf(p, w, -4.39150654e-06f);
    p = fmaf(p, w, 0.00021858087f);
    p = fmaf(p, w, -0.00125372503f);
    p = fmaf(p, w, -0.00417768164f);
    p = fmaf(p, w, 0.246640727f);
    p = fmaf(p, w, 1.50140941f);
  } else {
    w = sqrtf(w) - 3.0f;
    p = -0.000200214257f;
    p = fmaf(p, w, 0.000100950558f);
    p = fmaf(p, w, 0.00134934322f);
    p = fmaf(p, w, -0.00367342844f);
    p = fmaf(p, w, 0.00573950773f);
    p = fmaf(p, w, -0.0076224613f);
    p = fmaf(p, w, 0.00943887047f);
    p = fmaf(p, w, 1.00167406f);
    p = fmaf(p, w, 2.83297682f);
  }
  return p * x;
}

__device__ inline float normal_from_bits(uint32_t bits) {
  uint32_t fb = (bits >> 9) | 0x3f800000u;
  float f = __uint_as_float(fb) - 1.0f;
  const float LO = -0.99999994f;
  float u = f * 2.0f + LO;
  u = fmaxf(LO, u);
  return 1.41421356f * erfinv_xla(u);
}

__device__ inline float sscale_f(uint32_t k, float nhe) {
  uint32_t kk = k ? k : 1u;
  return powf((float)kk * (1.0f / 1048576.0f), nhe);
}

__device__ inline float2 cmul(float2 a, float2 b) {
  return make_float2(a.x * b.x - a.y * b.y, a.x * b.y + a.y * b.x);
}
__device__ inline float2 wexp(float u) {
  float s, c; sincospif(2.0f * u, &s, &c); return make_float2(c, s);
}
__device__ inline float2 cadd(float2 a, float2 b){ return make_float2(a.x+b.x, a.y+b.y); }
__device__ inline float2 csub(float2 a, float2 b){ return make_float2(a.x-b.x, a.y-b.y); }
__device__ inline float2 cmuli(float2 a){ return make_float2(-a.y, a.x); }  // * (+i)

// LDS address swizzle for the FFT exchanges: <=4-way on all phases
__device__ inline int sA(int p) { return p ^ (((p >> 6) & 3) << 2) ^ ((p >> 8) & 3); }

// radix-4 DIF butterfly, sign +i, with twiddle W = omega^{n'}
__device__ inline void bfly(float2& y0, float2& y1, float2& y2, float2& y3, float2 W) {
  float2 a = cadd(y0, y2), b = csub(y0, y2);
  float2 c = cadd(y1, y3), d = cmuli(csub(y1, y3));
  float2 W2 = cmul(W, W), W3 = cmul(W2, W);
  y0 = cadd(a, c);
  y1 = cmul(cadd(b, d), W);
  y2 = cmul(csub(a, c), W2);
  y3 = cmul(csub(b, d), W3);
}

// 1024-pt FFT core (sign +), 64 threads, 16 pts/thread, 2 barriers.
__device__ inline void fft1024_core(float2* r, float2* rc, float2* buf, int w) {
  #pragma unroll
  for (int e3 = 0; e3 < 4; ++e3) {
    float2 W = wexp((float)((e3 << 6) + w) * (1.0f / 1024.0f));
    bfly(r[e3], r[e3 + 4], r[e3 + 8], r[e3 + 12], W);
  }
  {
    float2 W = wexp((float)w * (1.0f / 256.0f));
    #pragma unroll
    for (int e4 = 0; e4 < 4; ++e4)
      bfly(r[(e4 << 2) + 0], r[(e4 << 2) + 1], r[(e4 << 2) + 2], r[(e4 << 2) + 3], W);
  }
  #pragma unroll
  for (int s = 0; s < 16; ++s) buf[sA((s << 6) + w)] = r[s];
  __syncthreads();
  {
    const int e0 = w & 3;
    const int pbase = ((w >> 4) << 8) + (((w >> 2) & 3) << 6) + e0;
    float2 rb[16];
    #pragma unroll
    for (int e2 = 0; e2 < 4; ++e2)
      #pragma unroll
      for (int e1 = 0; e1 < 4; ++e1)
        rb[(e2 << 2) + e1] = buf[sA(pbase + (e2 << 4) + (e1 << 2))];
    #pragma unroll
    for (int e1 = 0; e1 < 4; ++e1) {
      float2 W = wexp((float)((e1 << 2) + e0) * (1.0f / 64.0f));
      bfly(rb[e1], rb[e1 + 4], rb[e1 + 8], rb[e1 + 12], W);
    }
    {
      float2 W = wexp((float)e0 * (1.0f / 16.0f));
      #pragma unroll
      for (int e2 = 0; e2 < 4; ++e2)
        bfly(rb[(e2 << 2) + 0], rb[(e2 << 2) + 1], rb[(e2 << 2) + 2], rb[(e2 << 2) + 3], W);
    }
    #pragma unroll
    for (int e2 = 0; e2 < 4; ++e2)
      #pragma unroll
      for (int e1 = 0; e1 < 4; ++e1)
        buf[sA(pbase + (e2 << 4) + (e1 << 2))] = rb[(e2 << 2) + e1];
  }
  __syncthreads();
  {
    const int cbase = ((w >> 4) << 8) + (((w >> 2) & 3) << 6) + ((w & 3) << 4);
    #pragma unroll
    for (int e1 = 0; e1 < 4; ++e1)
      #pragma unroll
      for (int e0 = 0; e0 < 4; ++e0)
        rc[(e1 << 2) + e0] = buf[sA(cbase + (e1 << 2) + e0)];
    #pragma unroll
    for (int e1 = 0; e1 < 4; ++e1) {
      float2 x0 = rc[(e1 << 2)], x1 = rc[(e1 << 2) + 1], x2 = rc[(e1 << 2) + 2], x3 = rc[(e1 << 2) + 3];
      float2 a = cadd(x0, x2), b = csub(x0, x2);
      float2 c = cadd(x1, x3), d = cmuli(csub(x1, x3));
      rc[(e1 << 2)]     = cadd(a, c);
      rc[(e1 << 2) + 1] = cadd(b, d);
      rc[(e1 << 2) + 2] = csub(a, c);
      rc[(e1 << 2) + 3] = csub(b, d);
    }
  }
}

// ---- scalars ----------------------------------------------------------------
__device__ inline float med8_dev(const float* p) {
  float v[8];
  for (int i = 0; i < 8; ++i) v[i] = p[i];
  for (int i = 1; i < 8; ++i) { float key = v[i]; int j = i - 1;
    while (j >= 0 && v[j] > key) { v[j + 1] = v[j]; --j; } v[j + 1] = key; }
  return 0.5f * (v[3] + v[4]);
}

__global__ void k_scalars(Hdr* h, const float* er, const float* ei, const float* ar,
                          const float* ai, const float* pr, const float* pim) {
  if (threadIdx.x || blockIdx.x) return;
  float mer = med8_dev(er), mei = med8_dev(ei);
  h->e_r = mer; h->e_i = mei;
  h->amp_r = med8_dev(ar); h->amp_i = med8_dev(ai);
  h->phi_r = (int)med8_dev(pr);
  h->phi_i = (int)med8_dev(pim);
  h->nhe_r = -0.5f * mer; h->nhe_i = -0.5f * mei;
}

__global__ void k_sumw2(const Hdr* __restrict__ h, float* __restrict__ partials) {
  __shared__ float sr_[256], si_[256];
  const float nher = h->nhe_r, nhei = h->nhe_i;
  float sr = 0.f, si = 0.f;
  for (int j = 0; j < 4; ++j) {
    uint32_t k = (uint32_t)(blockIdx.x * 1024 + j * 256 + threadIdx.x) + 1u;
    float fk = (float)k * (1.0f / 1048576.0f);
    float wr = powf(fk, nher), wi = powf(fk, nhei);
    if (k == NHALF) { wr *= 0.5f; wi *= 0.5f; }
    sr += wr * wr; si += wi * wi;
  }
  sr_[threadIdx.x] = sr; si_[threadIdx.x] = si; __syncthreads();
  for (int off = 128; off > 0; off >>= 1) {
    if ((int)threadIdx.x < off) { sr_[threadIdx.x] += sr_[threadIdx.x + off];
                                  si_[threadIdx.x] += si_[threadIdx.x + off]; }
    __syncthreads();
  }
  if (!threadIdx.x) { partials[blockIdx.x * 2] = sr_[0]; partials[blockIdx.x * 2 + 1] = si_[0]; }
}

__global__ void k_sumw2_fin(Hdr* h, const float* partials) {
  if (threadIdx.x || blockIdx.x) return;
  float Sr = 0.f, Si = 0.f;
  for (int b = 0; b < 512; ++b) { Sr += partials[b * 2]; Si += partials[b * 2 + 1]; }
  float sig_r = 2.0f * sqrtf(Sr) * (1.0f / 1048576.0f);
  float sig_i = 2.0f * sqrtf(Si) * (1.0f / 1048576.0f);
  float s0 = h->amp_r / (sig_r * 1048576.0f);
  float s1 = (h->amp_i * h->amp_i) / (sig_i * 1048576.0f);
  h->scale_s[0] = s0; h->scale_s[1] = s1; h->scale_s[2] = s0; h->scale_s[3] = s1;
}

// ---- wsum -------------------------------------------------------------------
__global__ void k_wsum(const float* __restrict__ w1, const float* __restrict__ w2,
                       float2* __restrict__ wsum) {
  int idx = blockIdx.x * 256 + threadIdx.x;
  int sel = idx >> 16, rem = idx & 65535;
  const float* w = sel ? w2 : w1;
  int c = rem >> 10, m1 = (rem >> 5) & 31, m2 = rem & 31;
  size_t base = (size_t)c * 131072 + (size_t)m1 * 64 + (size_t)m2 * 2;
  float sr = 0.f, si = 0.f;
  for (int oc = 0; oc < 64; ++oc) { sr += w[base + (size_t)oc * 2048]; si += w[base + (size_t)oc * 2048 + 1]; }
  wsum[idx] = make_float2(sr, si);
}

// ---- noise spectra ----------------------------------------------------------
__global__ void k_noise_spec(float2* __restrict__ spec, const Hdr* __restrict__ h, KeyArgs ka) {
  const int combo = blockIdx.y;
  const int s = combo >> 1, part = combo & 1;
  const float nhe = ((s & 1) == 0) ? h->nhe_r : h->nhe_i;
  const uint32_t K0 = ka.k[combo][0], K1 = ka.k[combo][1];
  float2* sp = spec + (size_t)s * SPEC_STRIDE;
  const int i = blockIdx.x * 256 + threadIdx.x;
#if JPART
  if (i >= (int)NSPEC) return;
  uint32_t o0, o1; tf2x32(K0, K1, 0u, (uint32_t)i, o0, o1);
#if PART_XOR
  uint32_t bits = o0 ^ o1;
#else
  uint32_t bits = o1;
#endif
  float val = normal_from_bits(bits) * sscale_f((uint32_t)i, nhe);
  if (i == 0 || i == (int)NHALF) val = part ? 0.0f : val * 1.41421356f;
  if (part) sp[i].y = val; else sp[i].x = val;
#else
  if (i >= 262145) return;
  uint32_t c1 = (i == 262144) ? 0u : (uint32_t)(i + 262145);
  uint32_t o0, o1; tf2x32(K0, K1, (uint32_t)i, c1, o0, o1);
  {
    uint32_t k = (uint32_t)i;
    float v = normal_from_bits(o0) * sscale_f(k, nhe);
    if (k == 0u) v = part ? 0.0f : v * 1.41421356f;
    if (part) sp[k].y = v; else sp[k].x = v;
  }
  if (i < 262144) {
    uint32_t k = (uint32_t)i + 262145u;
    float v = normal_from_bits(o1) * sscale_f(k, nhe);
    if (k == NHALF) v = part ? 0.0f : v * 1.41421356f;
    if (part) sp[k].y = v; else sp[k].x = v;
  }
#endif
}

// ---- irfft(2^20) stage 1 ----------------------------------------------------
__global__ __launch_bounds__(256) void k_fft_s1(const float2* __restrict__ spec,
                                                float2* __restrict__ G) {
  __shared__ float2 buf4[4][1024];
  const int b = blockIdx.x;
  const int lin = (b & 7) * 128 + (b >> 3);
  const int arr = lin >> 8;
  const int g = threadIdx.x >> 6, w = threadIdx.x & 63;
  const int k1 = ((lin & 255) << 2) + g;
  const float2* sp = spec + (size_t)arr * SPEC_STRIDE;

  float2 r[16], rc[16];
  #pragma unroll
  for (int s = 0; s < 16; ++s) {
    int p = (s << 6) + w;
    uint32_t k = (uint32_t)k1 + ((uint32_t)p << 10);
    float2 cv;
    if (k <= NHALF) cv = sp[k];
    else { float2 v = sp[N20 - k]; cv = make_float2(v.x, -v.y); }
    r[s] = cv;
  }
  fft1024_core(r, rc, buf4[g], w);
  float2* gp = G + ((size_t)arr << 20) + ((size_t)k1 << 10);
  const int klo = ((w & 3) << 4) + (((w >> 2) & 3) << 2) + (w >> 4);
  #pragma unroll
  for (int e1 = 0; e1 < 4; ++e1)
    #pragma unroll
    for (int e0 = 0; e0 < 4; ++e0) {
      int k = (e0 << 8) + (e1 << 6) + klo;
      float2 tw = wexp((float)(k * k1) * (1.0f / 1048576.0f));
      gp[k] = cmul(rc[(e1 << 2) + e0], tw);
    }
}

// ---- stage 2: per j2, FFT over k1; noiseP[arr][j2][j1] ----------------------
__global__ __launch_bounds__(256) void k_fft_s2(const float2* __restrict__ G,
                                                float* __restrict__ noiseP,
                                                const Hdr* __restrict__ h) {
  __shared__ float2 buf4[4][1024];
  const int b = blockIdx.x;
  const int lin = (b & 7) * 128 + (b >> 3);
  const int arr = lin >> 8;
  const int g = threadIdx.x >> 6, w = threadIdx.x & 63;
  const int j2 = ((lin & 255) << 2) + g;

  float2 r[16], rc[16];
  const float2* gp = G + ((size_t)arr << 20) + (size_t)j2;
  #pragma unroll
  for (int s = 0; s < 16; ++s) r[s] = gp[(size_t)((s << 6) + w) << 10];
  fft1024_core(r, rc, buf4[g], w);
  const float sc = h->scale_s[arr];
  float* np_ = noiseP + ((size_t)arr << 20) + ((size_t)j2 << 10);
  const int klo = ((w & 3) << 4) + (((w >> 2) & 3) << 2) + (w >> 4);
  #pragma unroll
  for (int e1 = 0; e1 < 4; ++e1)
    #pragma unroll
    for (int e0 = 0; e0 < 4; ++e0) {
      int k = (e0 << 8) + (e1 << 6) + klo;
      np_[k] = rc[(e1 << 2) + e0].x * sc;
    }
}

// ---- noise linearize: transpose 1024x1024 + roll fold -----------------------
// noiseP[s][j2][j1] holds time sample n = j2 + 1024*j1.
// noiseL[s][(n + phi_s) & mask] = sample(n)  =>  noiseL[s][p] = td[(p-phi_s)&mask]
__global__ __launch_bounds__(256) void k_ntrans(const float* __restrict__ noiseP,
                                                float* __restrict__ noiseL,
                                                const Hdr* __restrict__ h) {
  __shared__ float tile[64][65];
  const int b = blockIdx.x;               // 1024 = 4 streams * 256 tiles
  const int s = b >> 8, tid = b & 255;
  const int R0 = (tid >> 4) << 6;         // j2 block
  const int C0 = (tid & 15) << 6;         // j1 block
  const int t = threadIdx.x;
  const int tx = t & 63, ty = t >> 6;
  const int phi = (s & 1) ? h->phi_i : h->phi_r;
  const float* src = noiseP + ((size_t)s << 20);
  float* dst = noiseL + ((size_t)s << 20);
  #pragma unroll
  for (int i = 0; i < 16; ++i) {
    int r = (i << 2) + ty;
    tile[r][tx] = src[(size_t)((R0 + r) << 10) + (size_t)(C0 + tx)];
  }
  __syncthreads();
  #pragma unroll
  for (int i = 0; i < 16; ++i) {
    int c = (i << 2) + ty;
    int n = ((C0 + c) << 10) + R0 + tx;   // time index
    uint32_t q = (uint32_t)(n + phi) & (N20 - 1u);
    dst[q] = tile[tx][c];
  }
}

// ---- constants: A_E, B2T (inverse) + ET, Fc, Fs, Fns (forward) --------------
__global__ __launch_bounds__(256) void k_prep(unsigned short* __restrict__ A_E,
                                              unsigned short* __restrict__ B2T,
                                              unsigned short* __restrict__ ET,
                                              unsigned short* __restrict__ Fc,
                                              unsigned short* __restrict__ Fs,
                                              unsigned short* __restrict__ Fns) {
  int t = blockIdx.x * 256 + threadIdx.x;
  if (t < 32768) {
    int y = t >> 7, p = t & 127;
    int kyp = p & 63; int ky = (kyp < 32) ? kyp : kyp + 192;
    float s, c; sincospif(2.0f * (float)((ky * y) & 255) * (1.0f / 256.0f), &s, &c);
    A_E[t] = f2bf((p < 64) ? c : s);
  } else if (t < 49152) {
    int u = t - 32768;
    int x = u >> 6, j = u & 63, kx = j & 31;
    float s, c; sincospif(2.0f * (float)((kx * x) & 255) * (1.0f / 256.0f), &s, &c);
    float v = (j < 32) ? ((kx == 0) ? 1.0f : 2.0f * c)
                       : ((kx == 0) ? 0.0f : -2.0f * s);
    B2T[u] = f2bf(v * (1.0f / 65536.0f));
  } else if (t < 65536) {
    int u = t - 49152;
    int col = u >> 8, xx = u & 255; int kx = col & 31;
    float s, c; sincospif(2.0f * (float)((kx * xx) & 255) * (1.0f / 256.0f), &s, &c);
    ET[u] = f2bf((col < 32) ? c : -s);
  } else if (t < 114688) {
    int u = (t - 65536) & 16383;
    int which = (t - 65536) >> 14;
    int kyp = u >> 8, y = u & 255; int ky = (kyp < 32) ? kyp : kyp + 192;
    float s, c; sincospif(2.0f * (float)((ky * y) & 255) * (1.0f / 256.0f), &s, &c);
    if (which == 0) Fc[u] = f2bf(c);
    else if (which == 1) Fs[u] = f2bf(s);
    else Fns[u] = f2bf(-s);
  }
}

// ---- fused forward + inverse per image --------------------------------------
__global__ __launch_bounds__(256) void k_fused(const float* __restrict__ x,
    const float2* __restrict__ wsum, const float* __restrict__ noiseL,
    const unsigned short* __restrict__ ET, const unsigned short* __restrict__ Fc,
    const unsigned short* __restrict__ Fs, const unsigned short* __restrict__ Fns,
    const unsigned short* __restrict__ A_E, const unsigned short* __restrict__ B2T,
    float* __restrict__ out) {
  __shared__ char lds[65536];
  char* X1T = lds + 32768;
  const int bc = blockIdx.x, t = threadIdx.x;
  const int c = bc & 63;
  const int l = t & 63, w = t >> 6, lr = l & 31, kg = l >> 5;
  const int rt = w >> 1, ct = w & 1;
  const float* xim = x + ((size_t)bc << 16);

  // ---- forward stage 1: X1T = bf16(x) . ET^T, 4 y-tiles
  for (int yt = 0; yt < 4; ++yt) {
    __syncthreads();
    #pragma unroll
    for (int i = 0; i < 16; ++i) {
      int f4 = i * 256 + t;
      int r = f4 >> 6, c4 = f4 & 63;
      float4 v = *(const float4*)(xim + (size_t)(((yt << 6) + r) << 8) + (c4 << 2));
      ushort4 b4; b4.x = f2bf(v.x); b4.y = f2bf(v.y); b4.z = f2bf(v.z); b4.w = f2bf(v.w);
      int byte = ((r << 9) + (c4 << 3)) ^ ((r & 7) << 4);
      *(ushort4*)(lds + byte) = b4;
    }
    __syncthreads();
    f32x16 a1 = zero16();
    const int arow = (rt << 5) + lr;
    const int bcol = (ct << 5) + lr;
    #pragma unroll
    for (int s = 0; s < 16; ++s) {
      short8 af = *(const short8*)(lds + (((arow << 9) + (s << 5) + (kg << 4)) ^ ((arow & 7) << 4)));
      short8 bf = *(const short8*)(ET + (bcol << 8) + (s << 4) + (kg << 3));
      a1 = __builtin_amdgcn_mfma_f32_32x32x16_bf16(af, bf, a1, 0, 0, 0);
    }
    #pragma unroll
    for (int r4 = 0; r4 < 4; ++r4) {
      int y0 = (yt << 6) + (rt << 5) + (r4 << 3) + (kg << 2);
      ushort4 p4;
      p4.x = f2bf(a1[r4 * 4 + 0]); p4.y = f2bf(a1[r4 * 4 + 1]);
      p4.z = f2bf(a1[r4 * 4 + 2]); p4.w = f2bf(a1[r4 * 4 + 3]);
      int byte = ((bcol << 9) + (y0 << 1)) ^ ((bcol & 7) << 4);
      *(ushort4*)(X1T + byte) = p4;
    }
  }
  __syncthreads();

  // ---- forward stage 2: O = F . X1
  {
    const int re_im = w >> 1, kt = w & 1;
    const unsigned short* A1p = re_im ? Fns : Fs;
    const int b0row = (re_im ? 32 : 0) + lr;
    const int b1row = (re_im ? 0 : 32) + lr;
    const int a2row = (kt << 5) + lr;
    f32x16 a2 = zero16();
    #pragma unroll
    for (int s = 0; s < 16; ++s) {
      short8 a0f = *(const short8*)(Fc  + (a2row << 8) + (s << 4) + (kg << 3));
      short8 a1f = *(const short8*)(A1p + (a2row << 8) + (s << 4) + (kg << 3));
      short8 b0f = *(const short8*)(X1T + (((b0row << 9) + (s << 5) + (kg << 4)) ^ ((b0row & 7) << 4)));
      short8 b1f = *(const short8*)(X1T + (((b1row << 9) + (s << 5) + (kg << 4)) ^ ((b1row & 7) << 4)));
      a2 = __builtin_amdgcn_mfma_f32_32x32x16_bf16(a0f, b0f, a2, 0, 0, 0);
      a2 = __builtin_amdgcn_mfma_f32_32x32x16_bf16(a1f, b1f, a2, 0, 0, 0);
    }
    float* Osm = (float*)(lds + (re_im << 13));
    #pragma unroll
    for (int i = 0; i < 16; ++i) {
      int row = (kt << 5) + (i & 3) + ((i >> 2) << 3) + (kg << 2);
      Osm[(row << 5) + lr] = a2[i];
    }
  }
  __syncthreads();

  // ---- epilogue: wsum mul + linear noise subtract -> ofs
  {
    const float* Ore = (const float*)lds;
    const float* Oim = (const float*)(lds + 8192);
    float2* ofs2 = (float2*)(lds + 32768);
    #pragma unroll
    for (int r = 0; r < 8; ++r) {
      int idx = (r << 8) + t;
      int kyp = idx >> 5, kx = idx & 31;
      int sel = kyp >> 5, m1 = kyp & 31;
      float2 av = make_float2(Ore[idx], Oim[idx]);
      float2 wv = wsum[((size_t)sel << 16) + (size_t)(((c << 5) | m1) << 5) + (size_t)kx];
      float2 v;
      v.x = av.x * wv.x - av.y * wv.y;
      v.y = av.x * wv.y + av.y * wv.x;
      uint32_t p = ((uint32_t)((bc << 5) | m1) << 5) | (uint32_t)kx;
      const float* nlr = noiseL + ((size_t)(sel ? 2 : 0) << 20);
      const float* nli = noiseL + ((size_t)(sel ? 3 : 1) << 20);
      v.x -= nlr[p];
      v.y -= nli[p];
      ofs2[idx] = v;
    }
  }
  __syncthreads();

  // ---- build Mt[64 j][128 p] bf16 swizzled at [49152,65536)
  {
    const float* ofs = (const float*)(lds + 32768);
    char* Mt = lds + 49152;
    #pragma unroll
    for (int i = 0; i < 32; ++i) {
      int idx = t + (i << 8);
      int p = idx >> 6, j = idx & 63;
      int kyp = p & 63;
      float v;
      if (p < 64) v = (j < 32) ? ofs[(kyp << 6) + (j << 1)]
                               : ofs[(kyp << 6) + ((j - 32) << 1) + 1];
      else        v = (j < 32) ? -ofs[(kyp << 6) + (j << 1) + 1]
                               : ofs[(kyp << 6) + ((j - 32) << 1)];
      int byte = ((j << 8) + (p << 1)) ^ ((j & 7) << 4);
      *(unsigned short*)(Mt + byte) = f2bf(v);
    }
  }
  __syncthreads();

  // ---- GEMM1: T = A_E . M ; Tb bf16 swizzled at [0,32768)
  {
    const char* Mt = lds + 49152;
    char* Tb = lds;
    f32x16 acc[2][2];
    acc[0][0] = zero16(); acc[0][1] = zero16(); acc[1][0] = zero16(); acc[1][1] = zero16();
    #pragma unroll
    for (int s = 0; s < 8; ++s) {
      short8 af[2], bf[2];
      #pragma unroll
      for (int rt2 = 0; rt2 < 2; ++rt2) {
        int row = (w << 6) + (rt2 << 5) + lr;
        af[rt2] = *(const short8*)(A_E + (row << 7) + (s << 4) + (kg << 3));
      }
      #pragma unroll
      for (int ct2 = 0; ct2 < 2; ++ct2) {
        int j = (ct2 << 5) + lr;
        int byte = ((j << 8) + (s << 5) + (kg << 4)) ^ ((j & 7) << 4);
        bf[ct2] = *(const short8*)(Mt + byte);
      }
      #pragma unroll
      for (int rt2 = 0; rt2 < 2; ++rt2)
        #pragma unroll
        for (int ct2 = 0; ct2 < 2; ++ct2)
          acc[rt2][ct2] = __builtin_amdgcn_mfma_f32_32x32x16_bf16(af[rt2], bf[ct2], acc[rt2][ct2], 0, 0, 0);
    }
    __syncthreads();
    #pragma unroll
    for (int rt2 = 0; rt2 < 2; ++rt2)
      #pragma unroll
      for (int ct2 = 0; ct2 < 2; ++ct2)
        #pragma unroll
        for (int r = 0; r < 16; ++r) {
          int row = (w << 6) + (rt2 << 5) + (r & 3) + (((r >> 2) & 3) << 3) + (kg << 2);
          int col = (ct2 << 5) + lr;
          int byte = ((row << 7) + (col << 1)) ^ ((row & 7) << 4);
          *(unsigned short*)(Tb + byte) = f2bf(acc[rt2][ct2][r]);
        }
  }
  __syncthreads();

  // ---- GEMM2: out = T . B2
  {
    const char* Tb = lds;
    short8 ta[2][4];
    #pragma unroll
    for (int rt2 = 0; rt2 < 2; ++rt2)
      #pragma unroll
      for (int ks = 0; ks < 4; ++ks) {
        int row = (w << 6) + (rt2 << 5) + lr;
        int byte = ((row << 7) + (ks << 5) + (kg << 4)) ^ ((row & 7) << 4);
        ta[rt2][ks] = *(const short8*)(Tb + byte);
      }
    float* op = out + ((size_t)bc << 16);
    #pragma unroll
    for (int cc = 0; cc < 4; ++cc) {
      short8 b2[2][4];
      #pragma unroll
      for (int cx = 0; cx < 2; ++cx)
        #pragma unroll
        for (int ks = 0; ks < 4; ++ks) {
          int xx = (cc << 6) + (cx << 5) + lr;
          b2[cx][ks] = *(const short8*)(B2T + (xx << 6) + (ks << 4) + (kg << 3));
        }
      f32x16 a2[2][2];
      a2[0][0] = zero16(); a2[0][1] = zero16(); a2[1][0] = zero16(); a2[1][1] = zero16();
      #pragma unroll
      for (int ks = 0; ks < 4; ++ks)
        #pragma unroll
        for (int rt2 = 0; rt2 < 2; ++rt2)
          #pragma unroll
          for (int cx = 0; cx < 2; ++cx)
            a2[rt2][cx] = __builtin_amdgcn_mfma_f32_32x32x16_bf16(ta[rt2][ks], b2[cx][ks], a2[rt2][cx], 0, 0, 0);
      #pragma unroll
      for (int rt2 = 0; rt2 < 2; ++rt2)
        #pragma unroll
        for (int cx = 0; cx < 2; ++cx)
          #pragma unroll
          for (int r = 0; r < 16; ++r) {
            int row = (w << 6) + (rt2 << 5) + (r & 3) + (((r >> 2) & 3) << 3) + (kg << 2);
            int xx = (cc << 6) + (cx << 5) + lr;
            op[(row << 8) + xx] = a2[rt2][cx][r];
          }
    }
  }
}

// ---- host -------------------------------------------------------------------
extern "C" void kernel_launch(void* const* d_in, const int* in_sizes, int n_in,
                              void* d_out, int out_size, void* d_ws, size_t ws_size,
                              hipStream_t stream) {
  (void)in_sizes; (void)n_in; (void)out_size; (void)ws_size;
  const float* x   = (const float*)d_in[0];
  const float* w1  = (const float*)d_in[1];
  const float* w2  = (const float*)d_in[2];
  const float* er  = (const float*)d_in[3];
  const float* ei  = (const float*)d_in[4];
  const float* ar  = (const float*)d_in[5];
  const float* ai  = (const float*)d_in[6];
  const float* pr  = (const float*)d_in[7];
  const float* pim = (const float*)d_in[8];
  float* out = (float*)d_out;

  char* ws = (char*)d_ws;
  Hdr*    hdr      = (Hdr*)ws;
  float*  partials = (float*)(ws + 0x1000);
  float2* wsum     = (float2*)(ws + 0x10000);
  unsigned short* A_E = (unsigned short*)(ws + 0x130000);
  unsigned short* B2T = (unsigned short*)(ws + 0x140000);
  unsigned short* ET  = (unsigned short*)(ws + 0x148000);
  unsigned short* Fc  = (unsigned short*)(ws + 0x150000);
  unsigned short* Fs  = (unsigned short*)(ws + 0x158000);
  unsigned short* Fns = (unsigned short*)(ws + 0x160000);
  float2* spec     = (float2*)(ws + 0x200000);
  float2* G        = (float2*)(ws + 0x1400000);   // 32MB; dead after fft_s2
  float*  noiseL   = (float*)(ws + 0x1400000);    // 16MB over G
  float*  noiseP   = (float*)(ws + 0x3400000);    // 16MB

  auto splitk = [](const uint32_t k[2], uint32_t a[2], uint32_t b[2]) {
#if JPART
    tf2x32(k[0], k[1], 0u, 0u, a[0], a[1]);
    tf2x32(k[0], k[1], 0u, 1u, b[0], b[1]);
#else
    uint32_t r0[2], r1[2];
    tf2x32(k[0], k[1], 0u, 2u, r0[0], r0[1]);
    tf2x32(k[0], k[1], 1u, 3u, r1[0], r1[1]);
    a[0] = r0[0]; a[1] = r1[0]; b[0] = r0[1]; b[1] = r1[1];
#endif
  };
  uint32_t root[2] = { 0u, 42u };
  uint32_t kA[2], kB[2], k1A[2], k2A[2], k1B[2], k2B[2];
  splitk(root, kA, kB);
  splitk(kA, k1A, k2A);
  splitk(kB, k1B, k2B);
  KeyArgs ka;
  splitk(k1A, ka.k[0], ka.k[1]);
  splitk(k2A, ka.k[2], ka.k[3]);
  splitk(k1B, ka.k[4], ka.k[5]);
  splitk(k2B, ka.k[6], ka.k[7]);

  hipLaunchKernelGGL(k_scalars,    dim3(1),        dim3(64),  0, stream, hdr, er, ei, ar, ai, pr, pim);
  hipLaunchKernelGGL(k_sumw2,      dim3(512),      dim3(256), 0, stream, hdr, partials);
  hipLaunchKernelGGL(k_sumw2_fin,  dim3(1),        dim3(64),  0, stream, hdr, partials);
  hipLaunchKernelGGL(k_wsum,       dim3(512),      dim3(256), 0, stream, w1, w2, wsum);
  hipLaunchKernelGGL(k_prep,       dim3(448),      dim3(256), 0, stream, A_E, B2T, ET, Fc, Fs, Fns);
  hipLaunchKernelGGL(k_noise_spec, dim3(2049, 8),  dim3(256), 0, stream, spec, hdr, ka);
  hipLaunchKernelGGL(k_fft_s1,     dim3(1024),     dim3(256), 0, stream, spec, G);
  hipLaunchKernelGGL(k_fft_s2,     dim3(1024),     dim3(256), 0, stream, G, noiseP, hdr);
  hipLaunchKernelGGL(k_ntrans,     dim3(1024),     dim3(256), 0, stream, noiseP, noiseL, hdr);
  hipLaunchKernelGGL(k_fused,      dim3(1024),     dim3(256), 0, stream, x, wsum, noiseL, ET, Fc, Fs, Fns, A_E, B2T, out);
}

// Round 8
// 313.294 us; speedup vs baseline: 1.1778x; 1.1703x over previous
//
#include <hip/hip_runtime.h>
#include <cstdint>

// ---- JAX PRNG mode switches -------------------------------------------------
#define JPART 1
#define PART_XOR 1

constexpr uint32_t N20   = 1u << 20;
constexpr uint32_t NHALF = 1u << 19;
constexpr uint32_t NSPEC = NHALF + 1;
constexpr uint32_t SPEC_STRIDE = 524544;

struct Hdr {
  float e_r, e_i, amp_r, amp_i;
  int   phi_r, phi_i;
  float nhe_r, nhe_i;
  float scale_s[4];
};
struct KeyArgs { uint32_t k[8][2]; };

typedef __attribute__((ext_vector_type(8))) short short8;
typedef __attribute__((ext_vector_type(16))) float f32x16;

__device__ inline f32x16 zero16() {
  f32x16 v;
  #pragma unroll
  for (int i = 0; i < 16; ++i) v[i] = 0.f;
  return v;
}

__device__ inline unsigned short f2bf(float f) {
  uint32_t u = __float_as_uint(f);
  return (unsigned short)((u + 0x7fffu + ((u >> 16) & 1u)) >> 16);
}

// ---- Threefry2x32-20 (exact JAX cipher) ------------------------------------
__host__ __device__ inline void tf2x32(uint32_t k0, uint32_t k1, uint32_t x0, uint32_t x1,
                                       uint32_t& o0, uint32_t& o1) {
  const uint32_t ks0 = k0, ks1 = k1, ks2 = k0 ^ k1 ^ 0x1BD11BDAu;
  const uint32_t ks[3] = { ks0, ks1, ks2 };
  x0 += ks0; x1 += ks1;
  const int rot[2][4] = { {13,15,26,6}, {17,29,16,24} };
  for (int g = 0; g < 5; ++g) {
    const int* rr = rot[g & 1];
    for (int i = 0; i < 4; ++i) {
      x0 += x1;
      x1 = (x1 << rr[i]) | (x1 >> (32 - rr[i]));
      x1 ^= x0;
    }
    x0 += ks[(g + 1) % 3];
    x1 += ks[(g + 2) % 3] + (uint32_t)(g + 1);
  }
  o0 = x0; o1 = x1;
}

// ---- XLA ErfInv32 polynomial ------------------------------------------------
__device__ inline float erfinv_xla(float x) {
  float w = -log1pf(-x * x);
  float p;
  if (w < 5.0f) {
    w -= 2.5f;
    p = 2.81022636e-08f;
    p = fmaf(p, w, 3.43273939e-07f);
    p = fmaf(p, w, -3.5233877e-06f);
    p = fmaf(p, w, -4.39150654e-06f);
    p = fmaf(p, w, 0.00021858087f);
    p = fmaf(p, w, -0.00125372503f);
    p = fmaf(p, w, -0.00417768164f);
    p = fmaf(p, w, 0.246640727f);
    p = fmaf(p, w, 1.50140941f);
  } else {
    w = sqrtf(w) - 3.0f;
    p = -0.000200214257f;
    p = fmaf(p, w, 0.000100950558f);
    p = fmaf(p, w, 0.00134934322f);
    p = fmaf(p, w, -0.00367342844f);
    p = fmaf(p, w, 0.00573950773f);
    p = fmaf(p, w, -0.0076224613f);
    p = fmaf(p, w, 0.00943887047f);
    p = fmaf(p, w, 1.00167406f);
    p = fmaf(p, w, 2.83297682f);
  }
  return p * x;
}

__device__ inline float normal_from_bits(uint32_t bits) {
  uint32_t fb = (bits >> 9) | 0x3f800000u;
  float f = __uint_as_float(fb) - 1.0f;
  const float LO = -0.99999994f;
  float u = f * 2.0f + LO;
  u = fmaxf(LO, u);
  return 1.41421356f * erfinv_xla(u);
}

__device__ inline float sscale_f(uint32_t k, float nhe) {
  uint32_t kk = k ? k : 1u;
  return powf((float)kk * (1.0f / 1048576.0f), nhe);
}

__device__ inline float2 cmul(float2 a, float2 b) {
  return make_float2(a.x * b.x - a.y * b.y, a.x * b.y + a.y * b.x);
}
__device__ inline float2 wexp(float u) {
  float s, c; sincospif(2.0f * u, &s, &c); return make_float2(c, s);
}
__device__ inline float2 cadd(float2 a, float2 b){ return make_float2(a.x+b.x, a.y+b.y); }
__device__ inline float2 csub(float2 a, float2 b){ return make_float2(a.x-b.x, a.y-b.y); }
__device__ inline float2 cmuli(float2 a){ return make_float2(-a.y, a.x); }  // * (+i)

// LDS address swizzle for the FFT exchanges: <=4-way on all phases
__device__ inline int sA(int p) { return p ^ (((p >> 6) & 3) << 2) ^ ((p >> 8) & 3); }

// radix-4 DIF butterfly, sign +i, with twiddle W = omega^{n'}
__device__ inline void bfly(float2& y0, float2& y1, float2& y2, float2& y3, float2 W) {
  float2 a = cadd(y0, y2), b = csub(y0, y2);
  float2 c = cadd(y1, y3), d = cmuli(csub(y1, y3));
  float2 W2 = cmul(W, W), W3 = cmul(W2, W);
  y0 = cadd(a, c);
  y1 = cmul(cadd(b, d), W);
  y2 = cmul(csub(a, c), W2);
  y3 = cmul(csub(b, d), W3);
}

// 1024-pt FFT core (sign +), 64 threads, 16 pts/thread, 2 barriers.
__device__ inline void fft1024_core(float2* r, float2* rc, float2* buf, int w) {
  #pragma unroll
  for (int e3 = 0; e3 < 4; ++e3) {
    float2 W = wexp((float)((e3 << 6) + w) * (1.0f / 1024.0f));
    bfly(r[e3], r[e3 + 4], r[e3 + 8], r[e3 + 12], W);
  }
  {
    float2 W = wexp((float)w * (1.0f / 256.0f));
    #pragma unroll
    for (int e4 = 0; e4 < 4; ++e4)
      bfly(r[(e4 << 2) + 0], r[(e4 << 2) + 1], r[(e4 << 2) + 2], r[(e4 << 2) + 3], W);
  }
  #pragma unroll
  for (int s = 0; s < 16; ++s) buf[sA((s << 6) + w)] = r[s];
  __syncthreads();
  {
    const int e0 = w & 3;
    const int pbase = ((w >> 4) << 8) + (((w >> 2) & 3) << 6) + e0;
    float2 rb[16];
    #pragma unroll
    for (int e2 = 0; e2 < 4; ++e2)
      #pragma unroll
      for (int e1 = 0; e1 < 4; ++e1)
        rb[(e2 << 2) + e1] = buf[sA(pbase + (e2 << 4) + (e1 << 2))];
    #pragma unroll
    for (int e1 = 0; e1 < 4; ++e1) {
      float2 W = wexp((float)((e1 << 2) + e0) * (1.0f / 64.0f));
      bfly(rb[e1], rb[e1 + 4], rb[e1 + 8], rb[e1 + 12], W);
    }
    {
      float2 W = wexp((float)e0 * (1.0f / 16.0f));
      #pragma unroll
      for (int e2 = 0; e2 < 4; ++e2)
        bfly(rb[(e2 << 2) + 0], rb[(e2 << 2) + 1], rb[(e2 << 2) + 2], rb[(e2 << 2) + 3], W);
    }
    #pragma unroll
    for (int e2 = 0; e2 < 4; ++e2)
      #pragma unroll
      for (int e1 = 0; e1 < 4; ++e1)
        buf[sA(pbase + (e2 << 4) + (e1 << 2))] = rb[(e2 << 2) + e1];
  }
  __syncthreads();
  {
    const int cbase = ((w >> 4) << 8) + (((w >> 2) & 3) << 6) + ((w & 3) << 4);
    #pragma unroll
    for (int e1 = 0; e1 < 4; ++e1)
      #pragma unroll
      for (int e0 = 0; e0 < 4; ++e0)
        rc[(e1 << 2) + e0] = buf[sA(cbase + (e1 << 2) + e0)];
    #pragma unroll
    for (int e1 = 0; e1 < 4; ++e1) {
      float2 x0 = rc[(e1 << 2)], x1 = rc[(e1 << 2) + 1], x2 = rc[(e1 << 2) + 2], x3 = rc[(e1 << 2) + 3];
      float2 a = cadd(x0, x2), b = csub(x0, x2);
      float2 c = cadd(x1, x3), d = cmuli(csub(x1, x3));
      rc[(e1 << 2)]     = cadd(a, c);
      rc[(e1 << 2) + 1] = cadd(b, d);
      rc[(e1 << 2) + 2] = csub(a, c);
      rc[(e1 << 2) + 3] = csub(b, d);
    }
  }
}

// ---- scalars ----------------------------------------------------------------
__device__ inline float med8_dev(const float* p) {
  float v[8];
  for (int i = 0; i < 8; ++i) v[i] = p[i];
  for (int i = 1; i < 8; ++i) { float key = v[i]; int j = i - 1;
    while (j >= 0 && v[j] > key) { v[j + 1] = v[j]; --j; } v[j + 1] = key; }
  return 0.5f * (v[3] + v[4]);
}

__global__ void k_scalars(Hdr* h, const float* er, const float* ei, const float* ar,
                          const float* ai, const float* pr, const float* pim) {
  if (threadIdx.x || blockIdx.x) return;
  float mer = med8_dev(er), mei = med8_dev(ei);
  h->e_r = mer; h->e_i = mei;
  h->amp_r = med8_dev(ar); h->amp_i = med8_dev(ai);
  h->phi_r = (int)med8_dev(pr);
  h->phi_i = (int)med8_dev(pim);
  h->nhe_r = -0.5f * mer; h->nhe_i = -0.5f * mei;
}

__global__ void k_sumw2(const Hdr* __restrict__ h, float* __restrict__ partials) {
  __shared__ float sr_[256], si_[256];
  const float nher = h->nhe_r, nhei = h->nhe_i;
  float sr = 0.f, si = 0.f;
  for (int j = 0; j < 4; ++j) {
    uint32_t k = (uint32_t)(blockIdx.x * 1024 + j * 256 + threadIdx.x) + 1u;
    float fk = (float)k * (1.0f / 1048576.0f);
    float wr = powf(fk, nher), wi = powf(fk, nhei);
    if (k == NHALF) { wr *= 0.5f; wi *= 0.5f; }
    sr += wr * wr; si += wi * wi;
  }
  sr_[threadIdx.x] = sr; si_[threadIdx.x] = si; __syncthreads();
  for (int off = 128; off > 0; off >>= 1) {
    if ((int)threadIdx.x < off) { sr_[threadIdx.x] += sr_[threadIdx.x + off];
                                  si_[threadIdx.x] += si_[threadIdx.x + off]; }
    __syncthreads();
  }
  if (!threadIdx.x) { partials[blockIdx.x * 2] = sr_[0]; partials[blockIdx.x * 2 + 1] = si_[0]; }
}

__global__ void k_sumw2_fin(Hdr* h, const float* partials) {
  if (threadIdx.x || blockIdx.x) return;
  float Sr = 0.f, Si = 0.f;
  for (int b = 0; b < 512; ++b) { Sr += partials[b * 2]; Si += partials[b * 2 + 1]; }
  float sig_r = 2.0f * sqrtf(Sr) * (1.0f / 1048576.0f);
  float sig_i = 2.0f * sqrtf(Si) * (1.0f / 1048576.0f);
  float s0 = h->amp_r / (sig_r * 1048576.0f);
  float s1 = (h->amp_i * h->amp_i) / (sig_i * 1048576.0f);
  h->scale_s[0] = s0; h->scale_s[1] = s1; h->scale_s[2] = s0; h->scale_s[3] = s1;
}

// ---- wsum -------------------------------------------------------------------
__global__ void k_wsum(const float* __restrict__ w1, const float* __restrict__ w2,
                       float2* __restrict__ wsum) {
  int idx = blockIdx.x * 256 + threadIdx.x;
  int sel = idx >> 16, rem = idx & 65535;
  const float* w = sel ? w2 : w1;
  int c = rem >> 10, m1 = (rem >> 5) & 31, m2 = rem & 31;
  size_t base = (size_t)c * 131072 + (size_t)m1 * 64 + (size_t)m2 * 2;
  float sr = 0.f, si = 0.f;
  for (int oc = 0; oc < 64; ++oc) { sr += w[base + (size_t)oc * 2048]; si += w[base + (size_t)oc * 2048 + 1]; }
  wsum[idx] = make_float2(sr, si);
}

// ---- noise spectra ----------------------------------------------------------
__global__ void k_noise_spec(float2* __restrict__ spec, const Hdr* __restrict__ h, KeyArgs ka) {
  const int combo = blockIdx.y;
  const int s = combo >> 1, part = combo & 1;
  const float nhe = ((s & 1) == 0) ? h->nhe_r : h->nhe_i;
  const uint32_t K0 = ka.k[combo][0], K1 = ka.k[combo][1];
  float2* sp = spec + (size_t)s * SPEC_STRIDE;
  const int i = blockIdx.x * 256 + threadIdx.x;
#if JPART
  if (i >= (int)NSPEC) return;
  uint32_t o0, o1; tf2x32(K0, K1, 0u, (uint32_t)i, o0, o1);
#if PART_XOR
  uint32_t bits = o0 ^ o1;
#else
  uint32_t bits = o1;
#endif
  float val = normal_from_bits(bits) * sscale_f((uint32_t)i, nhe);
  if (i == 0 || i == (int)NHALF) val = part ? 0.0f : val * 1.41421356f;
  if (part) sp[i].y = val; else sp[i].x = val;
#else
  if (i >= 262145) return;
  uint32_t c1 = (i == 262144) ? 0u : (uint32_t)(i + 262145);
  uint32_t o0, o1; tf2x32(K0, K1, (uint32_t)i, c1, o0, o1);
  {
    uint32_t k = (uint32_t)i;
    float v = normal_from_bits(o0) * sscale_f(k, nhe);
    if (k == 0u) v = part ? 0.0f : v * 1.41421356f;
    if (part) sp[k].y = v; else sp[k].x = v;
  }
  if (i < 262144) {
    uint32_t k = (uint32_t)i + 262145u;
    float v = normal_from_bits(o1) * sscale_f(k, nhe);
    if (k == NHALF) v = part ? 0.0f : v * 1.41421356f;
    if (part) sp[k].y = v; else sp[k].x = v;
  }
#endif
}

// ---- irfft(2^20) stage 1 ----------------------------------------------------
__global__ __launch_bounds__(256) void k_fft_s1(const float2* __restrict__ spec,
                                                float2* __restrict__ G) {
  __shared__ float2 buf4[4][1024];
  const int b = blockIdx.x;
  const int lin = (b & 7) * 128 + (b >> 3);
  const int arr = lin >> 8;
  const int g = threadIdx.x >> 6, w = threadIdx.x & 63;
  const int k1 = ((lin & 255) << 2) + g;
  const float2* sp = spec + (size_t)arr * SPEC_STRIDE;

  float2 r[16], rc[16];
  #pragma unroll
  for (int s = 0; s < 16; ++s) {
    int p = (s << 6) + w;
    uint32_t k = (uint32_t)k1 + ((uint32_t)p << 10);
    float2 cv;
    if (k <= NHALF) cv = sp[k];
    else { float2 v = sp[N20 - k]; cv = make_float2(v.x, -v.y); }
    r[s] = cv;
  }
  fft1024_core(r, rc, buf4[g], w);
  float2* gp = G + ((size_t)arr << 20) + ((size_t)k1 << 10);
  const int klo = ((w & 3) << 4) + (((w >> 2) & 3) << 2) + (w >> 4);
  #pragma unroll
  for (int e1 = 0; e1 < 4; ++e1)
    #pragma unroll
    for (int e0 = 0; e0 < 4; ++e0) {
      int k = (e0 << 8) + (e1 << 6) + klo;
      float2 tw = wexp((float)(k * k1) * (1.0f / 1048576.0f));
      gp[k] = cmul(rc[(e1 << 2) + e0], tw);
    }
}

// ---- stage 2: per j2, FFT over k1; noiseP[arr][j2][j1] ----------------------
__global__ __launch_bounds__(256) void k_fft_s2(const float2* __restrict__ G,
                                                float* __restrict__ noiseP,
                                                const Hdr* __restrict__ h) {
  __shared__ float2 buf4[4][1024];
  const int b = blockIdx.x;
  const int lin = (b & 7) * 128 + (b >> 3);
  const int arr = lin >> 8;
  const int g = threadIdx.x >> 6, w = threadIdx.x & 63;
  const int j2 = ((lin & 255) << 2) + g;

  float2 r[16], rc[16];
  const float2* gp = G + ((size_t)arr << 20) + (size_t)j2;
  #pragma unroll
  for (int s = 0; s < 16; ++s) r[s] = gp[(size_t)((s << 6) + w) << 10];
  fft1024_core(r, rc, buf4[g], w);
  const float sc = h->scale_s[arr];
  float* np_ = noiseP + ((size_t)arr << 20) + ((size_t)j2 << 10);
  const int klo = ((w & 3) << 4) + (((w >> 2) & 3) << 2) + (w >> 4);
  #pragma unroll
  for (int e1 = 0; e1 < 4; ++e1)
    #pragma unroll
    for (int e0 = 0; e0 < 4; ++e0) {
      int k = (e0 << 8) + (e1 << 6) + klo;
      np_[k] = rc[(e1 << 2) + e0].x * sc;
    }
}

// ---- noise linearize: transpose 1024x1024 + roll fold -----------------------
__global__ __launch_bounds__(256) void k_ntrans(const float* __restrict__ noiseP,
                                                float* __restrict__ noiseL,
                                                const Hdr* __restrict__ h) {
  __shared__ float tile[64][65];
  const int b = blockIdx.x;               // 1024 = 4 streams * 256 tiles
  const int s = b >> 8, tid = b & 255;
  const int R0 = (tid >> 4) << 6;
  const int C0 = (tid & 15) << 6;
  const int t = threadIdx.x;
  const int tx = t & 63, ty = t >> 6;
  const int phi = (s & 1) ? h->phi_i : h->phi_r;
  const float* src = noiseP + ((size_t)s << 20);
  float* dst = noiseL + ((size_t)s << 20);
  #pragma unroll
  for (int i = 0; i < 16; ++i) {
    int r = (i << 2) + ty;
    tile[r][tx] = src[(size_t)((R0 + r) << 10) + (size_t)(C0 + tx)];
  }
  __syncthreads();
  #pragma unroll
  for (int i = 0; i < 16; ++i) {
    int c = (i << 2) + ty;
    int n = ((C0 + c) << 10) + R0 + tx;
    uint32_t q = (uint32_t)(n + phi) & (N20 - 1u);
    dst[q] = tile[tx][c];
  }
}

// ---- constants: A_E, B2T (inverse) + ET, Fc, Fs, Fns (forward) --------------
__global__ __launch_bounds__(256) void k_prep(unsigned short* __restrict__ A_E,
                                              unsigned short* __restrict__ B2T,
                                              unsigned short* __restrict__ ET,
                                              unsigned short* __restrict__ Fc,
                                              unsigned short* __restrict__ Fs,
                                              unsigned short* __restrict__ Fns) {
  int t = blockIdx.x * 256 + threadIdx.x;
  if (t < 32768) {
    int y = t >> 7, p = t & 127;
    int kyp = p & 63; int ky = (kyp < 32) ? kyp : kyp + 192;
    float s, c; sincospif(2.0f * (float)((ky * y) & 255) * (1.0f / 256.0f), &s, &c);
    A_E[t] = f2bf((p < 64) ? c : s);
  } else if (t < 49152) {
    int u = t - 32768;
    int x = u >> 6, j = u & 63, kx = j & 31;
    float s, c; sincospif(2.0f * (float)((kx * x) & 255) * (1.0f / 256.0f), &s, &c);
    float v = (j < 32) ? ((kx == 0) ? 1.0f : 2.0f * c)
                       : ((kx == 0) ? 0.0f : -2.0f * s);
    B2T[u] = f2bf(v * (1.0f / 65536.0f));
  } else if (t < 65536) {
    int u = t - 49152;
    int col = u >> 8, xx = u & 255; int kx = col & 31;
    float s, c; sincospif(2.0f * (float)((kx * xx) & 255) * (1.0f / 256.0f), &s, &c);
    ET[u] = f2bf((col < 32) ? c : -s);
  } else if (t < 114688) {
    int u = (t - 65536) & 16383;
    int which = (t - 65536) >> 14;
    int kyp = u >> 8, y = u & 255; int ky = (kyp < 32) ? kyp : kyp + 192;
    float s, c; sincospif(2.0f * (float)((ky * y) & 255) * (1.0f / 256.0f), &s, &c);
    if (which == 0) Fc[u] = f2bf(c);
    else if (which == 1) Fs[u] = f2bf(s);
    else Fns[u] = f2bf(-s);
  }
}

// ---- forward via MFMA (separate kernel; linear noise) ------------------------
__global__ __launch_bounds__(256) void k_forward(const float* __restrict__ x,
    const float2* __restrict__ wsum, const float* __restrict__ noiseL,
    const unsigned short* __restrict__ ET, const unsigned short* __restrict__ Fc,
    const unsigned short* __restrict__ Fs, const unsigned short* __restrict__ Fns,
    float2* __restrict__ oftg) {
  __shared__ char lds[65536];
  char* X1T = lds + 32768;
  const int bc = blockIdx.x, t = threadIdx.x;
  const int c = bc & 63;
  const int l = t & 63, w = t >> 6, lr = l & 31, kg = l >> 5;
  const int rt = w >> 1, ct = w & 1;
  const float* xim = x + ((size_t)bc << 16);

  for (int yt = 0; yt < 4; ++yt) {
    __syncthreads();
    #pragma unroll
    for (int i = 0; i < 16; ++i) {
      int f4 = i * 256 + t;
      int r = f4 >> 6, c4 = f4 & 63;
      float4 v = *(const float4*)(xim + (size_t)(((yt << 6) + r) << 8) + (c4 << 2));
      ushort4 b4; b4.x = f2bf(v.x); b4.y = f2bf(v.y); b4.z = f2bf(v.z); b4.w = f2bf(v.w);
      int byte = ((r << 9) + (c4 << 3)) ^ ((r & 7) << 4);
      *(ushort4*)(lds + byte) = b4;
    }
    __syncthreads();
    f32x16 a1 = zero16();
    const int arow = (rt << 5) + lr;
    const int bcol = (ct << 5) + lr;
    #pragma unroll
    for (int s = 0; s < 16; ++s) {
      short8 af = *(const short8*)(lds + (((arow << 9) + (s << 5) + (kg << 4)) ^ ((arow & 7) << 4)));
      short8 bf = *(const short8*)(ET + (bcol << 8) + (s << 4) + (kg << 3));
      a1 = __builtin_amdgcn_mfma_f32_32x32x16_bf16(af, bf, a1, 0, 0, 0);
    }
    #pragma unroll
    for (int r4 = 0; r4 < 4; ++r4) {
      int y0 = (yt << 6) + (rt << 5) + (r4 << 3) + (kg << 2);
      ushort4 p4;
      p4.x = f2bf(a1[r4 * 4 + 0]); p4.y = f2bf(a1[r4 * 4 + 1]);
      p4.z = f2bf(a1[r4 * 4 + 2]); p4.w = f2bf(a1[r4 * 4 + 3]);
      int byte = ((bcol << 9) + (y0 << 1)) ^ ((bcol & 7) << 4);
      *(ushort4*)(X1T + byte) = p4;
    }
  }
  __syncthreads();

  const int re_im = w >> 1, kt = w & 1;
  const unsigned short* A1p = re_im ? Fns : Fs;
  const int b0row = (re_im ? 32 : 0) + lr;
  const int b1row = (re_im ? 0 : 32) + lr;
  const int a2row = (kt << 5) + lr;
  f32x16 a2 = zero16();
  #pragma unroll
  for (int s = 0; s < 16; ++s) {
    short8 a0f = *(const short8*)(Fc  + (a2row << 8) + (s << 4) + (kg << 3));
    short8 a1f = *(const short8*)(A1p + (a2row << 8) + (s << 4) + (kg << 3));
    short8 b0f = *(const short8*)(X1T + (((b0row << 9) + (s << 5) + (kg << 4)) ^ ((b0row & 7) << 4)));
    short8 b1f = *(const short8*)(X1T + (((b1row << 9) + (s << 5) + (kg << 4)) ^ ((b1row & 7) << 4)));
    a2 = __builtin_amdgcn_mfma_f32_32x32x16_bf16(a0f, b0f, a2, 0, 0, 0);
    a2 = __builtin_amdgcn_mfma_f32_32x32x16_bf16(a1f, b1f, a2, 0, 0, 0);
  }
  float* Osm = (float*)(lds + (re_im << 13));
  #pragma unroll
  for (int i = 0; i < 16; ++i) {
    int row = (kt << 5) + (i & 3) + ((i >> 2) << 3) + (kg << 2);
    Osm[(row << 5) + lr] = a2[i];
  }
  __syncthreads();

  const float* Ore = (const float*)lds;
  const float* Oim = (const float*)(lds + 8192);
  #pragma unroll
  for (int r = 0; r < 8; ++r) {
    int idx = (r << 8) + t;
    int kyp = idx >> 5, kx = idx & 31;
    int sel = kyp >> 5, m1 = kyp & 31;
    float2 av = make_float2(Ore[idx], Oim[idx]);
    float2 wv = wsum[((size_t)sel << 16) + (size_t)(((c << 5) | m1) << 5) + (size_t)kx];
    float2 v;
    v.x = av.x * wv.x - av.y * wv.y;
    v.y = av.x * wv.y + av.y * wv.x;
    uint32_t p = ((uint32_t)((bc << 5) | m1) << 5) | (uint32_t)kx;
    const float* nlr = noiseL + ((size_t)(sel ? 2 : 0) << 20);
    const float* nli = noiseL + ((size_t)(sel ? 3 : 1) << 20);
    v.x -= nlr[p];
    v.y -= nli[p];
    oftg[((size_t)bc << 11) + (size_t)idx] = v;
  }
}

// ---- inverse via two bf16 MFMA GEMMs per image ------------------------------
__global__ __launch_bounds__(256) void k_inverse(const float2* __restrict__ oftg,
    const unsigned short* __restrict__ A_E, const unsigned short* __restrict__ B2T,
    float* __restrict__ out) {
  __shared__ char smem[49152];
  char* Tb = smem + 16384;
  float* ofs = (float*)(smem + 16384);

  const int bc = blockIdx.x, t = threadIdx.x;
  const int l = t & 63, w = t >> 6, lr = l & 31, kg = l >> 5;

  {
    const float4* src = (const float4*)(oftg + ((size_t)bc << 11));
    float4* dst = (float4*)ofs;
    #pragma unroll
    for (int i = 0; i < 4; ++i) dst[t + (i << 8)] = src[t + (i << 8)];
  }
  __syncthreads();

  #pragma unroll
  for (int i = 0; i < 32; ++i) {
    int idx = t + (i << 8);
    int p = idx >> 6, j = idx & 63;
    int kyp = p & 63;
    float v;
    if (p < 64) v = (j < 32) ? ofs[(kyp << 6) + (j << 1)]
                             : ofs[(kyp << 6) + ((j - 32) << 1) + 1];
    else        v = (j < 32) ? -ofs[(kyp << 6) + (j << 1) + 1]
                             : ofs[(kyp << 6) + ((j - 32) << 1)];
    int byte = ((j << 8) + (p << 1)) ^ ((j & 7) << 4);
    *(unsigned short*)(smem + byte) = f2bf(v);
  }
  __syncthreads();

  f32x16 acc[2][2];
  acc[0][0] = zero16(); acc[0][1] = zero16(); acc[1][0] = zero16(); acc[1][1] = zero16();
  #pragma unroll
  for (int s = 0; s < 8; ++s) {
    short8 af[2], bf[2];
    #pragma unroll
    for (int rt = 0; rt < 2; ++rt) {
      int row = (w << 6) + (rt << 5) + lr;
      af[rt] = *(const short8*)(A_E + (row << 7) + (s << 4) + (kg << 3));
    }
    #pragma unroll
    for (int ct = 0; ct < 2; ++ct) {
      int j = (ct << 5) + lr;
      int byte = ((j << 8) + (s << 5) + (kg << 4)) ^ ((j & 7) << 4);
      bf[ct] = *(const short8*)(smem + byte);
    }
    #pragma unroll
    for (int rt = 0; rt < 2; ++rt)
      #pragma unroll
      for (int ct = 0; ct < 2; ++ct)
        acc[rt][ct] = __builtin_amdgcn_mfma_f32_32x32x16_bf16(af[rt], bf[ct], acc[rt][ct], 0, 0, 0);
  }

  #pragma unroll
  for (int rt = 0; rt < 2; ++rt)
    #pragma unroll
    for (int ct = 0; ct < 2; ++ct)
      #pragma unroll
      for (int r = 0; r < 16; ++r) {
        int row = (w << 6) + (rt << 5) + (r & 3) + (((r >> 2) & 3) << 3) + (kg << 2);
        int col = (ct << 5) + lr;
        int byte = ((row << 7) + (col << 1)) ^ ((row & 7) << 4);
        *(unsigned short*)(Tb + byte) = f2bf(acc[rt][ct][r]);
      }
  __syncthreads();

  short8 ta[2][4];
  #pragma unroll
  for (int rt = 0; rt < 2; ++rt)
    #pragma unroll
    for (int ks = 0; ks < 4; ++ks) {
      int row = (w << 6) + (rt << 5) + lr;
      int byte = ((row << 7) + (ks << 5) + (kg << 4)) ^ ((row & 7) << 4);
      ta[rt][ks] = *(const short8*)(Tb + byte);
    }
  float* op = out + ((size_t)bc << 16);
  #pragma unroll
  for (int cc = 0; cc < 4; ++cc) {
    short8 b2[2][4];
    #pragma unroll
    for (int cx = 0; cx < 2; ++cx)
      #pragma unroll
      for (int ks = 0; ks < 4; ++ks) {
        int xx = (cc << 6) + (cx << 5) + lr;
        b2[cx][ks] = *(const short8*)(B2T + (xx << 6) + (ks << 4) + (kg << 3));
      }
    f32x16 a2[2][2];
    a2[0][0] = zero16(); a2[0][1] = zero16(); a2[1][0] = zero16(); a2[1][1] = zero16();
    #pragma unroll
    for (int ks = 0; ks < 4; ++ks)
      #pragma unroll
      for (int rt = 0; rt < 2; ++rt)
        #pragma unroll
        for (int cx = 0; cx < 2; ++cx)
          a2[rt][cx] = __builtin_amdgcn_mfma_f32_32x32x16_bf16(ta[rt][ks], b2[cx][ks], a2[rt][cx], 0, 0, 0);
    #pragma unroll
    for (int rt = 0; rt < 2; ++rt)
      #pragma unroll
      for (int cx = 0; cx < 2; ++cx)
        #pragma unroll
        for (int r = 0; r < 16; ++r) {
          int row = (w << 6) + (rt << 5) + (r & 3) + (((r >> 2) & 3) << 3) + (kg << 2);
          int xx = (cc << 6) + (cx << 5) + lr;
          op[(row << 8) + xx] = a2[rt][cx][r];
        }
  }
}

// ---- host -------------------------------------------------------------------
extern "C" void kernel_launch(void* const* d_in, const int* in_sizes, int n_in,
                              void* d_out, int out_size, void* d_ws, size_t ws_size,
                              hipStream_t stream) {
  (void)in_sizes; (void)n_in; (void)out_size; (void)ws_size;
  const float* x   = (const float*)d_in[0];
  const float* w1  = (const float*)d_in[1];
  const float* w2  = (const float*)d_in[2];
  const float* er  = (const float*)d_in[3];
  const float* ei  = (const float*)d_in[4];
  const float* ar  = (const float*)d_in[5];
  const float* ai  = (const float*)d_in[6];
  const float* pr  = (const float*)d_in[7];
  const float* pim = (const float*)d_in[8];
  float* out = (float*)d_out;

  char* ws = (char*)d_ws;
  Hdr*    hdr      = (Hdr*)ws;
  float*  partials = (float*)(ws + 0x1000);
  float2* wsum     = (float2*)(ws + 0x10000);
  unsigned short* A_E = (unsigned short*)(ws + 0x130000);
  unsigned short* B2T = (unsigned short*)(ws + 0x140000);
  unsigned short* ET  = (unsigned short*)(ws + 0x148000);
  unsigned short* Fc  = (unsigned short*)(ws + 0x150000);
  unsigned short* Fs  = (unsigned short*)(ws + 0x158000);
  unsigned short* Fns = (unsigned short*)(ws + 0x160000);
  float2* spec     = (float2*)(ws + 0x200000);
  float2* G        = (float2*)(ws + 0x1400000);   // 32MB; dead after fft_s2
  float*  noiseL   = (float*)(ws + 0x1400000);    // 16MB over lower G
  float2* oft      = (float2*)(ws + 0x2400000);   // 16MB over upper G
  float*  noiseP   = (float*)(ws + 0x3400000);    // 16MB

  auto splitk = [](const uint32_t k[2], uint32_t a[2], uint32_t b[2]) {
#if JPART
    tf2x32(k[0], k[1], 0u, 0u, a[0], a[1]);
    tf2x32(k[0], k[1], 0u, 1u, b[0], b[1]);
#else
    uint32_t r0[2], r1[2];
    tf2x32(k[0], k[1], 0u, 2u, r0[0], r0[1]);
    tf2x32(k[0], k[1], 1u, 3u, r1[0], r1[1]);
    a[0] = r0[0]; a[1] = r1[0]; b[0] = r0[1]; b[1] = r1[1];
#endif
  };
  uint32_t root[2] = { 0u, 42u };
  uint32_t kA[2], kB[2], k1A[2], k2A[2], k1B[2], k2B[2];
  splitk(root, kA, kB);
  splitk(kA, k1A, k2A);
  splitk(kB, k1B, k2B);
  KeyArgs ka;
  splitk(k1A, ka.k[0], ka.k[1]);
  splitk(k2A, ka.k[2], ka.k[3]);
  splitk(k1B, ka.k[4], ka.k[5]);
  splitk(k2B, ka.k[6], ka.k[7]);

  hipLaunchKernelGGL(k_scalars,    dim3(1),        dim3(64),  0, stream, hdr, er, ei, ar, ai, pr, pim);
  hipLaunchKernelGGL(k_sumw2,      dim3(512),      dim3(256), 0, stream, hdr, partials);
  hipLaunchKernelGGL(k_sumw2_fin,  dim3(1),        dim3(64),  0, stream, hdr, partials);
  hipLaunchKernelGGL(k_wsum,       dim3(512),      dim3(256), 0, stream, w1, w2, wsum);
  hipLaunchKernelGGL(k_prep,       dim3(448),      dim3(256), 0, stream, A_E, B2T, ET, Fc, Fs, Fns);
  hipLaunchKernelGGL(k_noise_spec, dim3(2049, 8),  dim3(256), 0, stream, spec, hdr, ka);
  hipLaunchKernelGGL(k_fft_s1,     dim3(1024),     dim3(256), 0, stream, spec, G);
  hipLaunchKernelGGL(k_fft_s2,     dim3(1024),     dim3(256), 0, stream, G, noiseP, hdr);
  hipLaunchKernelGGL(k_ntrans,     dim3(1024),     dim3(256), 0, stream, noiseP, noiseL, hdr);
  hipLaunchKernelGGL(k_forward,    dim3(1024),     dim3(256), 0, stream, x, wsum, noiseL, ET, Fc, Fs, Fns, oft);
  hipLaunchKernelGGL(k_inverse,    dim3(1024),     dim3(256), 0, stream, oft, A_E, B2T, out);
}

// Round 9
// 287.880 us; speedup vs baseline: 1.2817x; 1.0883x over previous
//
#include <hip/hip_runtime.h>
#include <cstdint>

// ---- JAX PRNG mode switches -------------------------------------------------
#define JPART 1
#define PART_XOR 1

constexpr uint32_t N20   = 1u << 20;
constexpr uint32_t NHALF = 1u << 19;
constexpr int SPT_STRIDE = 520;   // padded row stride (float4 elems) for spT

struct Hdr {
  float e_r, e_i, amp_r, amp_i;
  int   phi_r, phi_i;
  float nhe_r, nhe_i;
  float scale_s[4];
};
struct KeyArgs { uint32_t k[8][2]; };

typedef __attribute__((ext_vector_type(8))) short short8;
typedef __attribute__((ext_vector_type(16))) float f32x16;

__device__ inline f32x16 zero16() {
  f32x16 v;
  #pragma unroll
  for (int i = 0; i < 16; ++i) v[i] = 0.f;
  return v;
}

__device__ inline unsigned short f2bf(float f) {
  uint32_t u = __float_as_uint(f);
  return (unsigned short)((u + 0x7fffu + ((u >> 16) & 1u)) >> 16);
}

// ---- Threefry2x32-20 (exact JAX cipher) ------------------------------------
__host__ __device__ inline void tf2x32(uint32_t k0, uint32_t k1, uint32_t x0, uint32_t x1,
                                       uint32_t& o0, uint32_t& o1) {
  const uint32_t ks0 = k0, ks1 = k1, ks2 = k0 ^ k1 ^ 0x1BD11BDAu;
  const uint32_t ks[3] = { ks0, ks1, ks2 };
  x0 += ks0; x1 += ks1;
  const int rot[2][4] = { {13,15,26,6}, {17,29,16,24} };
  for (int g = 0; g < 5; ++g) {
    const int* rr = rot[g & 1];
    for (int i = 0; i < 4; ++i) {
      x0 += x1;
      x1 = (x1 << rr[i]) | (x1 >> (32 - rr[i]));
      x1 ^= x0;
    }
    x0 += ks[(g + 1) % 3];
    x1 += ks[(g + 2) % 3] + (uint32_t)(g + 1);
  }
  o0 = x0; o1 = x1;
}

// ---- XLA ErfInv32 polynomial ------------------------------------------------
__device__ inline float erfinv_xla(float x) {
  float w = -log1pf(-x * x);
  float p;
  if (w < 5.0f) {
    w -= 2.5f;
    p = 2.81022636e-08f;
    p = fmaf(p, w, 3.43273939e-07f);
    p = fmaf(p, w, -3.5233877e-06f);
    p = fmaf(p, w, -4.39150654e-06f);
    p = fmaf(p, w, 0.00021858087f);
    p = fmaf(p, w, -0.00125372503f);
    p = fmaf(p, w, -0.00417768164f);
    p = fmaf(p, w, 0.246640727f);
    p = fmaf(p, w, 1.50140941f);
  } else {
    w = sqrtf(w) - 3.0f;
    p = -0.000200214257f;
    p = fmaf(p, w, 0.000100950558f);
    p = fmaf(p, w, 0.00134934322f);
    p = fmaf(p, w, -0.00367342844f);
    p = fmaf(p, w, 0.00573950773f);
    p = fmaf(p, w, -0.0076224613f);
    p = fmaf(p, w, 0.00943887047f);
    p = fmaf(p, w, 1.00167406f);
    p = fmaf(p, w, 2.83297682f);
  }
  return p * x;
}

__device__ inline float normal_from_bits(uint32_t bits) {
  uint32_t fb = (bits >> 9) | 0x3f800000u;
  float f = __uint_as_float(fb) - 1.0f;
  const float LO = -0.99999994f;
  float u = f * 2.0f + LO;
  u = fmaxf(LO, u);
  return 1.41421356f * erfinv_xla(u);
}

__device__ inline float sscale_f(uint32_t k, float nhe) {
  uint32_t kk = k ? k : 1u;
  return powf((float)kk * (1.0f / 1048576.0f), nhe);
}

__device__ inline float2 cmul(float2 a, float2 b) {
  return make_float2(a.x * b.x - a.y * b.y, a.x * b.y + a.y * b.x);
}
__device__ inline float2 wexp(float u) {
  float s, c; sincospif(2.0f * u, &s, &c); return make_float2(c, s);
}
__device__ inline float2 cadd(float2 a, float2 b){ return make_float2(a.x+b.x, a.y+b.y); }
__device__ inline float2 csub(float2 a, float2 b){ return make_float2(a.x-b.x, a.y-b.y); }
__device__ inline float2 cmuli(float2 a){ return make_float2(-a.y, a.x); }  // * (+i)

// LDS address swizzle for the FFT exchanges: <=4-way on all phases
__device__ inline int sA(int p) { return p ^ (((p >> 6) & 3) << 2) ^ ((p >> 8) & 3); }

// radix-4 DIF butterfly, sign +i, with twiddle W = omega^{n'}
__device__ inline void bfly(float2& y0, float2& y1, float2& y2, float2& y3, float2 W) {
  float2 a = cadd(y0, y2), b = csub(y0, y2);
  float2 c = cadd(y1, y3), d = cmuli(csub(y1, y3));
  float2 W2 = cmul(W, W), W3 = cmul(W2, W);
  y0 = cadd(a, c);
  y1 = cmul(cadd(b, d), W);
  y2 = cmul(csub(a, c), W2);
  y3 = cmul(csub(b, d), W3);
}

// 1024-pt FFT core (sign +), 64 threads, 16 pts/thread, 2 barriers.
__device__ inline void fft1024_core(float2* r, float2* rc, float2* buf, int w) {
  #pragma unroll
  for (int e3 = 0; e3 < 4; ++e3) {
    float2 W = wexp((float)((e3 << 6) + w) * (1.0f / 1024.0f));
    bfly(r[e3], r[e3 + 4], r[e3 + 8], r[e3 + 12], W);
  }
  {
    float2 W = wexp((float)w * (1.0f / 256.0f));
    #pragma unroll
    for (int e4 = 0; e4 < 4; ++e4)
      bfly(r[(e4 << 2) + 0], r[(e4 << 2) + 1], r[(e4 << 2) + 2], r[(e4 << 2) + 3], W);
  }
  #pragma unroll
  for (int s = 0; s < 16; ++s) buf[sA((s << 6) + w)] = r[s];
  __syncthreads();
  {
    const int e0 = w & 3;
    const int pbase = ((w >> 4) << 8) + (((w >> 2) & 3) << 6) + e0;
    float2 rb[16];
    #pragma unroll
    for (int e2 = 0; e2 < 4; ++e2)
      #pragma unroll
      for (int e1 = 0; e1 < 4; ++e1)
        rb[(e2 << 2) + e1] = buf[sA(pbase + (e2 << 4) + (e1 << 2))];
    #pragma unroll
    for (int e1 = 0; e1 < 4; ++e1) {
      float2 W = wexp((float)((e1 << 2) + e0) * (1.0f / 64.0f));
      bfly(rb[e1], rb[e1 + 4], rb[e1 + 8], rb[e1 + 12], W);
    }
    {
      float2 W = wexp((float)e0 * (1.0f / 16.0f));
      #pragma unroll
      for (int e2 = 0; e2 < 4; ++e2)
        bfly(rb[(e2 << 2) + 0], rb[(e2 << 2) + 1], rb[(e2 << 2) + 2], rb[(e2 << 2) + 3], W);
    }
    #pragma unroll
    for (int e2 = 0; e2 < 4; ++e2)
      #pragma unroll
      for (int e1 = 0; e1 < 4; ++e1)
        buf[sA(pbase + (e2 << 4) + (e1 << 2))] = rb[(e2 << 2) + e1];
  }
  __syncthreads();
  {
    const int cbase = ((w >> 4) << 8) + (((w >> 2) & 3) << 6) + ((w & 3) << 4);
    #pragma unroll
    for (int e1 = 0; e1 < 4; ++e1)
      #pragma unroll
      for (int e0 = 0; e0 < 4; ++e0)
        rc[(e1 << 2) + e0] = buf[sA(cbase + (e1 << 2) + e0)];
    #pragma unroll
    for (int e1 = 0; e1 < 4; ++e1) {
      float2 x0 = rc[(e1 << 2)], x1 = rc[(e1 << 2) + 1], x2 = rc[(e1 << 2) + 2], x3 = rc[(e1 << 2) + 3];
      float2 a = cadd(x0, x2), b = csub(x0, x2);
      float2 c = cadd(x1, x3), d = cmuli(csub(x1, x3));
      rc[(e1 << 2)]     = cadd(a, c);
      rc[(e1 << 2) + 1] = cadd(b, d);
      rc[(e1 << 2) + 2] = csub(a, c);
      rc[(e1 << 2) + 3] = csub(b, d);
    }
  }
}

// ---- scalars ----------------------------------------------------------------
__device__ inline float med8_dev(const float* p) {
  float v[8];
  for (int i = 0; i < 8; ++i) v[i] = p[i];
  for (int i = 1; i < 8; ++i) { float key = v[i]; int j = i - 1;
    while (j >= 0 && v[j] > key) { v[j + 1] = v[j]; --j; } v[j + 1] = key; }
  return 0.5f * (v[3] + v[4]);
}

__global__ void k_scalars(Hdr* h, const float* er, const float* ei, const float* ar,
                          const float* ai, const float* pr, const float* pim) {
  if (threadIdx.x || blockIdx.x) return;
  float mer = med8_dev(er), mei = med8_dev(ei);
  h->e_r = mer; h->e_i = mei;
  h->amp_r = med8_dev(ar); h->amp_i = med8_dev(ai);
  h->phi_r = (int)med8_dev(pr);
  h->phi_i = (int)med8_dev(pim);
  h->nhe_r = -0.5f * mer; h->nhe_i = -0.5f * mei;
}

__global__ void k_sumw2(const Hdr* __restrict__ h, float* __restrict__ partials) {
  __shared__ float sr_[256], si_[256];
  const float nher = h->nhe_r, nhei = h->nhe_i;
  float sr = 0.f, si = 0.f;
  for (int j = 0; j < 4; ++j) {
    uint32_t k = (uint32_t)(blockIdx.x * 1024 + j * 256 + threadIdx.x) + 1u;
    float fk = (float)k * (1.0f / 1048576.0f);
    float wr = powf(fk, nher), wi = powf(fk, nhei);
    if (k == NHALF) { wr *= 0.5f; wi *= 0.5f; }
    sr += wr * wr; si += wi * wi;
  }
  sr_[threadIdx.x] = sr; si_[threadIdx.x] = si; __syncthreads();
  for (int off = 128; off > 0; off >>= 1) {
    if ((int)threadIdx.x < off) { sr_[threadIdx.x] += sr_[threadIdx.x + off];
                                  si_[threadIdx.x] += si_[threadIdx.x + off]; }
    __syncthreads();
  }
  if (!threadIdx.x) { partials[blockIdx.x * 2] = sr_[0]; partials[blockIdx.x * 2 + 1] = si_[0]; }
}

__global__ void k_sumw2_fin(Hdr* h, const float* partials) {
  if (threadIdx.x || blockIdx.x) return;
  float Sr = 0.f, Si = 0.f;
  for (int b = 0; b < 512; ++b) { Sr += partials[b * 2]; Si += partials[b * 2 + 1]; }
  float sig_r = 2.0f * sqrtf(Sr) * (1.0f / 1048576.0f);
  float sig_i = 2.0f * sqrtf(Si) * (1.0f / 1048576.0f);
  float s0 = h->amp_r / (sig_r * 1048576.0f);
  float s1 = (h->amp_i * h->amp_i) / (sig_i * 1048576.0f);
  h->scale_s[0] = s0; h->scale_s[1] = s1; h->scale_s[2] = s0; h->scale_s[3] = s1;
}

// ---- wsum -------------------------------------------------------------------
__global__ void k_wsum(const float* __restrict__ w1, const float* __restrict__ w2,
                       float2* __restrict__ wsum) {
  int idx = blockIdx.x * 256 + threadIdx.x;
  int sel = idx >> 16, rem = idx & 65535;
  const float* w = sel ? w2 : w1;
  int c = rem >> 10, m1 = (rem >> 5) & 31, m2 = rem & 31;
  size_t base = (size_t)c * 131072 + (size_t)m1 * 64 + (size_t)m2 * 2;
  float sr = 0.f, si = 0.f;
  for (int oc = 0; oc < 64; ++oc) { sr += w[base + (size_t)oc * 2048]; si += w[base + (size_t)oc * 2048 + 1]; }
  wsum[idx] = make_float2(sr, si);
}

// ---- noise spectra: transposed float4 layout spT[pair][k1][k2] --------------
// f4 = (S1.re, S1.im, S2.re, S2.im); S1 = nr spectrum, S2 = ni spectrum
__global__ void k_noise_spec(float4* __restrict__ spT, const Hdr* __restrict__ h, KeyArgs ka) {
  const int pair = blockIdx.y;                 // 0 = A, 1 = B
  const int bx = blockIdx.x;                   // 0..2047
  const int k1 = bx >> 1, chunk = bx & 1;
  const int k2 = (chunk << 8) + (int)threadIdx.x;     // 0..511
  const float nher = h->nhe_r, nhei = h->nhe_i;
  float4* row = spT + (size_t)pair * (1024 * SPT_STRIDE) + (size_t)k1 * SPT_STRIDE;
  const bool extra = (k1 == 0) && (chunk == 1) && (threadIdx.x == 255);  // bin NHALF
  const int niter = extra ? 2 : 1;
  for (int it = 0; it < niter; ++it) {
    const int kk2 = (it == 0) ? k2 : 512;
    const uint32_t i = (uint32_t)k1 + ((uint32_t)kk2 << 10);
    float vals[4];
    #pragma unroll
    for (int j = 0; j < 4; ++j) {
      const uint32_t K0 = ka.k[pair * 4 + j][0], K1 = ka.k[pair * 4 + j][1];
      uint32_t o0, o1; tf2x32(K0, K1, 0u, i, o0, o1);
#if PART_XOR
      uint32_t bits = o0 ^ o1;
#else
      uint32_t bits = o1;
#endif
      float nhe = (j < 2) ? nher : nhei;
      float v = normal_from_bits(bits) * sscale_f(i, nhe);
      if (i == 0u || i == NHALF) v = (j & 1) ? 0.0f : v * 1.41421356f;
      vals[j] = v;
    }
    row[kk2] = make_float4(vals[0], vals[1], vals[2], vals[3]);
  }
}

// ---- irfft(2^20) stage 1 (complex-pair trick; 512 blocks) -------------------
__global__ __launch_bounds__(256) void k_fft_s1(const float4* __restrict__ spT,
                                                float2* __restrict__ G) {
  __shared__ float2 buf4[4][1024];
  const int b = blockIdx.x;
  const int lin = (b & 7) * 64 + (b >> 3);     // XCD-chunked (512 = 8*64)
  const int pair = lin >> 8;
  const int g = threadIdx.x >> 6, w = threadIdx.x & 63;
  const int k1 = ((lin & 255) << 2) + g;
  const float4* sp = spT + (size_t)pair * (1024 * SPT_STRIDE);
  const int mrow = (1024 - k1) & 1023;

  float2 r[16], rc[16];
  #pragma unroll
  for (int s = 0; s < 16; ++s) {
    int k2 = (s << 6) + w;
    uint32_t k = (uint32_t)k1 + ((uint32_t)k2 << 10);
    float4 f; float2 z;
    if (k <= NHALF) {
      f = sp[(size_t)k1 * SPT_STRIDE + k2];
      z = make_float2(f.x - f.w, f.y + f.z);       // Z = S1 + i*S2
    } else {
      int k2p = (k1 == 0) ? (1024 - k2) : (1023 - k2);
      f = sp[(size_t)mrow * SPT_STRIDE + k2p];
      z = make_float2(f.x + f.w, f.z - f.y);       // Z = conj(S1) + i*conj(S2)
    }
    r[s] = z;
  }
  fft1024_core(r, rc, buf4[g], w);
  float2* gp = G + ((size_t)pair << 20) + ((size_t)k1 << 10);
  const int klo = ((w & 3) << 4) + (((w >> 2) & 3) << 2) + (w >> 4);
  #pragma unroll
  for (int e1 = 0; e1 < 4; ++e1)
    #pragma unroll
    for (int e0 = 0; e0 < 4; ++e0) {
      int k = (e0 << 8) + (e1 << 6) + klo;
      float2 tw = wexp((float)(k * k1) * (1.0f / 1048576.0f));
      gp[k] = cmul(rc[(e1 << 2) + e0], tw);
    }
}

// ---- stage 2: per j2, FFT over k1; noiseP[pair][j2][j1] (float2: re=nr,im=ni)
__global__ __launch_bounds__(256) void k_fft_s2(const float2* __restrict__ G,
                                                float2* __restrict__ noiseP,
                                                const Hdr* __restrict__ h) {
  __shared__ float2 buf4[4][1024];
  const int b = blockIdx.x;
  const int lin = (b & 7) * 64 + (b >> 3);
  const int pair = lin >> 8;
  const int g = threadIdx.x >> 6, w = threadIdx.x & 63;
  const int j2 = ((lin & 255) << 2) + g;

  float2 r[16], rc[16];
  const float2* gp = G + ((size_t)pair << 20) + (size_t)j2;
  #pragma unroll
  for (int s = 0; s < 16; ++s) r[s] = gp[(size_t)((s << 6) + w) << 10];
  fft1024_core(r, rc, buf4[g], w);
  const float scr = h->scale_s[0], sci = h->scale_s[1];
  float2* np_ = noiseP + ((size_t)pair << 20) + ((size_t)j2 << 10);
  const int klo = ((w & 3) << 4) + (((w >> 2) & 3) << 2) + (w >> 4);
  #pragma unroll
  for (int e1 = 0; e1 < 4; ++e1)
    #pragma unroll
    for (int e0 = 0; e0 < 4; ++e0) {
      int k = (e0 << 8) + (e1 << 6) + klo;
      np_[k] = make_float2(rc[(e1 << 2) + e0].x * scr, rc[(e1 << 2) + e0].y * sci);
    }
}

// ---- noise linearize: transpose 1024x1024 (pairs) + roll fold ---------------
__global__ __launch_bounds__(256) void k_ntrans(const float2* __restrict__ noiseP,
                                                float* __restrict__ noiseL,
                                                const Hdr* __restrict__ h) {
  __shared__ float tr[64][65];
  __shared__ float ti[64][65];
  const int b = blockIdx.x;               // 512 = 2 pairs * 256 tiles
  const int pair = b >> 8, tid = b & 255;
  const int R0 = (tid >> 4) << 6;
  const int C0 = (tid & 15) << 6;
  const int t = threadIdx.x;
  const int tx = t & 63, ty = t >> 6;
  const int phir = h->phi_r, phii = h->phi_i;
  const float2* src = noiseP + ((size_t)pair << 20);
  float* dstr = noiseL + ((size_t)(pair * 2) << 20);
  float* dsti = noiseL + ((size_t)(pair * 2 + 1) << 20);
  #pragma unroll
  for (int i = 0; i < 16; ++i) {
    int r = (i << 2) + ty;
    float2 v = src[(size_t)((R0 + r) << 10) + (size_t)(C0 + tx)];
    tr[r][tx] = v.x; ti[r][tx] = v.y;
  }
  __syncthreads();
  #pragma unroll
  for (int i = 0; i < 16; ++i) {
    int c = (i << 2) + ty;
    int n = ((C0 + c) << 10) + R0 + tx;
    dstr[(uint32_t)(n + phir) & (N20 - 1u)] = tr[tx][c];
    dsti[(uint32_t)(n + phii) & (N20 - 1u)] = ti[tx][c];
  }
}

// ---- constants: A_E, B2T (inverse) + ET, Fc, Fs, Fns (forward) --------------
__global__ __launch_bounds__(256) void k_prep(unsigned short* __restrict__ A_E,
                                              unsigned short* __restrict__ B2T,
                                              unsigned short* __restrict__ ET,
                                              unsigned short* __restrict__ Fc,
                                              unsigned short* __restrict__ Fs,
                                              unsigned short* __restrict__ Fns) {
  int t = blockIdx.x * 256 + threadIdx.x;
  if (t < 32768) {
    int y = t >> 7, p = t & 127;
    int kyp = p & 63; int ky = (kyp < 32) ? kyp : kyp + 192;
    float s, c; sincospif(2.0f * (float)((ky * y) & 255) * (1.0f / 256.0f), &s, &c);
    A_E[t] = f2bf((p < 64) ? c : s);
  } else if (t < 49152) {
    int u = t - 32768;
    int x = u >> 6, j = u & 63, kx = j & 31;
    float s, c; sincospif(2.0f * (float)((kx * x) & 255) * (1.0f / 256.0f), &s, &c);
    float v = (j < 32) ? ((kx == 0) ? 1.0f : 2.0f * c)
                       : ((kx == 0) ? 0.0f : -2.0f * s);
    B2T[u] = f2bf(v * (1.0f / 65536.0f));
  } else if (t < 65536) {
    int u = t - 49152;
    int col = u >> 8, xx = u & 255; int kx = col & 31;
    float s, c; sincospif(2.0f * (float)((kx * xx) & 255) * (1.0f / 256.0f), &s, &c);
    ET[u] = f2bf((col < 32) ? c : -s);
  } else if (t < 114688) {
    int u = (t - 65536) & 16383;
    int which = (t - 65536) >> 14;
    int kyp = u >> 8, y = u & 255; int ky = (kyp < 32) ? kyp : kyp + 192;
    float s, c; sincospif(2.0f * (float)((ky * y) & 255) * (1.0f / 256.0f), &s, &c);
    if (which == 0) Fc[u] = f2bf(c);
    else if (which == 1) Fs[u] = f2bf(s);
    else Fns[u] = f2bf(-s);
  }
}

// ---- forward via MFMA (linear noise) ----------------------------------------
__global__ __launch_bounds__(256) void k_forward(const float* __restrict__ x,
    const float2* __restrict__ wsum, const float* __restrict__ noiseL,
    const unsigned short* __restrict__ ET, const unsigned short* __restrict__ Fc,
    const unsigned short* __restrict__ Fs, const unsigned short* __restrict__ Fns,
    float2* __restrict__ oftg) {
  __shared__ char lds[65536];
  char* X1T = lds + 32768;
  const int bc = blockIdx.x, t = threadIdx.x;
  const int c = bc & 63;
  const int l = t & 63, w = t >> 6, lr = l & 31, kg = l >> 5;
  const int rt = w >> 1, ct = w & 1;
  const float* xim = x + ((size_t)bc << 16);

  for (int yt = 0; yt < 4; ++yt) {
    __syncthreads();
    #pragma unroll
    for (int i = 0; i < 16; ++i) {
      int f4 = i * 256 + t;
      int r = f4 >> 6, c4 = f4 & 63;
      float4 v = *(const float4*)(xim + (size_t)(((yt << 6) + r) << 8) + (c4 << 2));
      ushort4 b4; b4.x = f2bf(v.x); b4.y = f2bf(v.y); b4.z = f2bf(v.z); b4.w = f2bf(v.w);
      int byte = ((r << 9) + (c4 << 3)) ^ ((r & 7) << 4);
      *(ushort4*)(lds + byte) = b4;
    }
    __syncthreads();
    f32x16 a1 = zero16();
    const int arow = (rt << 5) + lr;
    const int bcol = (ct << 5) + lr;
    #pragma unroll
    for (int s = 0; s < 16; ++s) {
      short8 af = *(const short8*)(lds + (((arow << 9) + (s << 5) + (kg << 4)) ^ ((arow & 7) << 4)));
      short8 bf = *(const short8*)(ET + (bcol << 8) + (s << 4) + (kg << 3));
      a1 = __builtin_amdgcn_mfma_f32_32x32x16_bf16(af, bf, a1, 0, 0, 0);
    }
    #pragma unroll
    for (int r4 = 0; r4 < 4; ++r4) {
      int y0 = (yt << 6) + (rt << 5) + (r4 << 3) + (kg << 2);
      ushort4 p4;
      p4.x = f2bf(a1[r4 * 4 + 0]); p4.y = f2bf(a1[r4 * 4 + 1]);
      p4.z = f2bf(a1[r4 * 4 + 2]); p4.w = f2bf(a1[r4 * 4 + 3]);
      int byte = ((bcol << 9) + (y0 << 1)) ^ ((bcol & 7) << 4);
      *(ushort4*)(X1T + byte) = p4;
    }
  }
  __syncthreads();

  const int re_im = w >> 1, kt = w & 1;
  const unsigned short* A1p = re_im ? Fns : Fs;
  const int b0row = (re_im ? 32 : 0) + lr;
  const int b1row = (re_im ? 0 : 32) + lr;
  const int a2row = (kt << 5) + lr;
  f32x16 a2 = zero16();
  #pragma unroll
  for (int s = 0; s < 16; ++s) {
    short8 a0f = *(const short8*)(Fc  + (a2row << 8) + (s << 4) + (kg << 3));
    short8 a1f = *(const short8*)(A1p + (a2row << 8) + (s << 4) + (kg << 3));
    short8 b0f = *(const short8*)(X1T + (((b0row << 9) + (s << 5) + (kg << 4)) ^ ((b0row & 7) << 4)));
    short8 b1f = *(const short8*)(X1T + (((b1row << 9) + (s << 5) + (kg << 4)) ^ ((b1row & 7) << 4)));
    a2 = __builtin_amdgcn_mfma_f32_32x32x16_bf16(a0f, b0f, a2, 0, 0, 0);
    a2 = __builtin_amdgcn_mfma_f32_32x32x16_bf16(a1f, b1f, a2, 0, 0, 0);
  }
  float* Osm = (float*)(lds + (re_im << 13));
  #pragma unroll
  for (int i = 0; i < 16; ++i) {
    int row = (kt << 5) + (i & 3) + ((i >> 2) << 3) + (kg << 2);
    Osm[(row << 5) + lr] = a2[i];
  }
  __syncthreads();

  const float* Ore = (const float*)lds;
  const float* Oim = (const float*)(lds + 8192);
  #pragma unroll
  for (int r = 0; r < 8; ++r) {
    int idx = (r << 8) + t;
    int kyp = idx >> 5, kx = idx & 31;
    int sel = kyp >> 5, m1 = kyp & 31;
    float2 av = make_float2(Ore[idx], Oim[idx]);
    float2 wv = wsum[((size_t)sel << 16) + (size_t)(((c << 5) | m1) << 5) + (size_t)kx];
    float2 v;
    v.x = av.x * wv.x - av.y * wv.y;
    v.y = av.x * wv.y + av.y * wv.x;
    uint32_t p = ((uint32_t)((bc << 5) | m1) << 5) | (uint32_t)kx;
    const float* nlr = noiseL + ((size_t)(sel ? 2 : 0) << 20);
    const float* nli = noiseL + ((size_t)(sel ? 3 : 1) << 20);
    v.x -= nlr[p];
    v.y -= nli[p];
    oftg[((size_t)bc << 11) + (size_t)idx] = v;
  }
}

// ---- inverse via two bf16 MFMA GEMMs per image ------------------------------
__global__ __launch_bounds__(256) void k_inverse(const float2* __restrict__ oftg,
    const unsigned short* __restrict__ A_E, const unsigned short* __restrict__ B2T,
    float* __restrict__ out) {
  __shared__ char smem[49152];
  char* Tb = smem + 16384;
  float* ofs = (float*)(smem + 16384);

  const int bc = blockIdx.x, t = threadIdx.x;
  const int l = t & 63, w = t >> 6, lr = l & 31, kg = l >> 5;

  {
    const float4* src = (const float4*)(oftg + ((size_t)bc << 11));
    float4* dst = (float4*)ofs;
    #pragma unroll
    for (int i = 0; i < 4; ++i) dst[t + (i << 8)] = src[t + (i << 8)];
  }
  __syncthreads();

  #pragma unroll
  for (int i = 0; i < 32; ++i) {
    int idx = t + (i << 8);
    int p = idx >> 6, j = idx & 63;
    int kyp = p & 63;
    float v;
    if (p < 64) v = (j < 32) ? ofs[(kyp << 6) + (j << 1)]
                             : ofs[(kyp << 6) + ((j - 32) << 1) + 1];
    else        v = (j < 32) ? -ofs[(kyp << 6) + (j << 1) + 1]
                             : ofs[(kyp << 6) + ((j - 32) << 1)];
    int byte = ((j << 8) + (p << 1)) ^ ((j & 7) << 4);
    *(unsigned short*)(smem + byte) = f2bf(v);
  }
  __syncthreads();

  f32x16 acc[2][2];
  acc[0][0] = zero16(); acc[0][1] = zero16(); acc[1][0] = zero16(); acc[1][1] = zero16();
  #pragma unroll
  for (int s = 0; s < 8; ++s) {
    short8 af[2], bf[2];
    #pragma unroll
    for (int rt = 0; rt < 2; ++rt) {
      int row = (w << 6) + (rt << 5) + lr;
      af[rt] = *(const short8*)(A_E + (row << 7) + (s << 4) + (kg << 3));
    }
    #pragma unroll
    for (int ct = 0; ct < 2; ++ct) {
      int j = (ct << 5) + lr;
      int byte = ((j << 8) + (s << 5) + (kg << 4)) ^ ((j & 7) << 4);
      bf[ct] = *(const short8*)(smem + byte);
    }
    #pragma unroll
    for (int rt = 0; rt < 2; ++rt)
      #pragma unroll
      for (int ct = 0; ct < 2; ++ct)
        acc[rt][ct] = __builtin_amdgcn_mfma_f32_32x32x16_bf16(af[rt], bf[ct], acc[rt][ct], 0, 0, 0);
  }

  #pragma unroll
  for (int rt = 0; rt < 2; ++rt)
    #pragma unroll
    for (int ct = 0; ct < 2; ++ct)
      #pragma unroll
      for (int r = 0; r < 16; ++r) {
        int row = (w << 6) + (rt << 5) + (r & 3) + (((r >> 2) & 3) << 3) + (kg << 2);
        int col = (ct << 5) + lr;
        int byte = ((row << 7) + (col << 1)) ^ ((row & 7) << 4);
        *(unsigned short*)(Tb + byte) = f2bf(acc[rt][ct][r]);
      }
  __syncthreads();

  short8 ta[2][4];
  #pragma unroll
  for (int rt = 0; rt < 2; ++rt)
    #pragma unroll
    for (int ks = 0; ks < 4; ++ks) {
      int row = (w << 6) + (rt << 5) + lr;
      int byte = ((row << 7) + (ks << 5) + (kg << 4)) ^ ((row & 7) << 4);
      ta[rt][ks] = *(const short8*)(Tb + byte);
    }
  float* op = out + ((size_t)bc << 16);
  #pragma unroll
  for (int cc = 0; cc < 4; ++cc) {
    short8 b2[2][4];
    #pragma unroll
    for (int cx = 0; cx < 2; ++cx)
      #pragma unroll
      for (int ks = 0; ks < 4; ++ks) {
        int xx = (cc << 6) + (cx << 5) + lr;
        b2[cx][ks] = *(const short8*)(B2T + (xx << 6) + (ks << 4) + (kg << 3));
      }
    f32x16 a2[2][2];
    a2[0][0] = zero16(); a2[0][1] = zero16(); a2[1][0] = zero16(); a2[1][1] = zero16();
    #pragma unroll
    for (int ks = 0; ks < 4; ++ks)
      #pragma unroll
      for (int rt = 0; rt < 2; ++rt)
        #pragma unroll
        for (int cx = 0; cx < 2; ++cx)
          a2[rt][cx] = __builtin_amdgcn_mfma_f32_32x32x16_bf16(ta[rt][ks], b2[cx][ks], a2[rt][cx], 0, 0, 0);
    #pragma unroll
    for (int rt = 0; rt < 2; ++rt)
      #pragma unroll
      for (int cx = 0; cx < 2; ++cx)
        #pragma unroll
        for (int r = 0; r < 16; ++r) {
          int row = (w << 6) + (rt << 5) + (r & 3) + (((r >> 2) & 3) << 3) + (kg << 2);
          int xx = (cc << 6) + (cx << 5) + lr;
          op[(row << 8) + xx] = a2[rt][cx][r];
        }
  }
}

// ---- host -------------------------------------------------------------------
extern "C" void kernel_launch(void* const* d_in, const int* in_sizes, int n_in,
                              void* d_out, int out_size, void* d_ws, size_t ws_size,
                              hipStream_t stream) {
  (void)in_sizes; (void)n_in; (void)out_size; (void)ws_size;
  const float* x   = (const float*)d_in[0];
  const float* w1  = (const float*)d_in[1];
  const float* w2  = (const float*)d_in[2];
  const float* er  = (const float*)d_in[3];
  const float* ei  = (const float*)d_in[4];
  const float* ar  = (const float*)d_in[5];
  const float* ai  = (const float*)d_in[6];
  const float* pr  = (const float*)d_in[7];
  const float* pim = (const float*)d_in[8];
  float* out = (float*)d_out;

  char* ws = (char*)d_ws;
  Hdr*    hdr      = (Hdr*)ws;
  float*  partials = (float*)(ws + 0x1000);
  float2* wsum     = (float2*)(ws + 0x10000);
  unsigned short* A_E = (unsigned short*)(ws + 0x130000);
  unsigned short* B2T = (unsigned short*)(ws + 0x140000);
  unsigned short* ET  = (unsigned short*)(ws + 0x148000);
  unsigned short* Fc  = (unsigned short*)(ws + 0x150000);
  unsigned short* Fs  = (unsigned short*)(ws + 0x158000);
  unsigned short* Fns = (unsigned short*)(ws + 0x160000);
  float4* spT      = (float4*)(ws + 0x200000);    // 2*1024*520*16B ~ 17MB -> ends < 0x1400000
  float2* G        = (float2*)(ws + 0x1400000);   // 16MB (2 pairs)
  float2* oft      = (float2*)(ws + 0x1400000);   // reuses G (dead after s2)... see note
  float2* noiseP   = (float2*)(ws + 0x2400000);   // 16MB
  float*  noiseL   = (float*)(ws + 0x3400000);    // 16MB

  // NOTE: oft aliases G. G is dead after k_fft_s2; k_forward (writes oft) runs
  // after k_ntrans, so no overlap in live ranges.

  auto splitk = [](const uint32_t k[2], uint32_t a[2], uint32_t b[2]) {
#if JPART
    tf2x32(k[0], k[1], 0u, 0u, a[0], a[1]);
    tf2x32(k[0], k[1], 0u, 1u, b[0], b[1]);
#else
    uint32_t r0[2], r1[2];
    tf2x32(k[0], k[1], 0u, 2u, r0[0], r0[1]);
    tf2x32(k[0], k[1], 1u, 3u, r1[0], r1[1]);
    a[0] = r0[0]; a[1] = r1[0]; b[0] = r0[1]; b[1] = r1[1];
#endif
  };
  uint32_t root[2] = { 0u, 42u };
  uint32_t kA[2], kB[2], k1A[2], k2A[2], k1B[2], k2B[2];
  splitk(root, kA, kB);
  splitk(kA, k1A, k2A);
  splitk(kB, k1B, k2B);
  KeyArgs ka;
  splitk(k1A, ka.k[0], ka.k[1]);
  splitk(k2A, ka.k[2], ka.k[3]);
  splitk(k1B, ka.k[4], ka.k[5]);
  splitk(k2B, ka.k[6], ka.k[7]);

  hipLaunchKernelGGL(k_scalars,    dim3(1),        dim3(64),  0, stream, hdr, er, ei, ar, ai, pr, pim);
  hipLaunchKernelGGL(k_sumw2,      dim3(512),      dim3(256), 0, stream, hdr, partials);
  hipLaunchKernelGGL(k_sumw2_fin,  dim3(1),        dim3(64),  0, stream, hdr, partials);
  hipLaunchKernelGGL(k_wsum,       dim3(512),      dim3(256), 0, stream, w1, w2, wsum);
  hipLaunchKernelGGL(k_prep,       dim3(448),      dim3(256), 0, stream, A_E, B2T, ET, Fc, Fs, Fns);
  hipLaunchKernelGGL(k_noise_spec, dim3(2048, 2),  dim3(256), 0, stream, spT, hdr, ka);
  hipLaunchKernelGGL(k_fft_s1,     dim3(512),      dim3(256), 0, stream, spT, G);
  hipLaunchKernelGGL(k_fft_s2,     dim3(512),      dim3(256), 0, stream, G, noiseP, hdr);
  hipLaunchKernelGGL(k_ntrans,     dim3(512),      dim3(256), 0, stream, noiseP, noiseL, hdr);
  hipLaunchKernelGGL(k_forward,    dim3(1024),     dim3(256), 0, stream, x, wsum, noiseL, ET, Fc, Fs, Fns, oft);
  hipLaunchKernelGGL(k_inverse,    dim3(1024),     dim3(256), 0, stream, oft, A_E, B2T, out);
}

// Round 10
// 270.661 us; speedup vs baseline: 1.3633x; 1.0636x over previous
//
#include <hip/hip_runtime.h>
#include <cstdint>

// ---- JAX PRNG mode switches -------------------------------------------------
#define JPART 1
#define PART_XOR 1

constexpr uint32_t N20   = 1u << 20;
constexpr uint32_t NHALF = 1u << 19;
constexpr int SPT_STRIDE = 520;   // padded row stride (float4 elems) for spT

struct Hdr {
  float e_r, e_i, amp_r, amp_i;
  int   phi_r, phi_i;
  float nhe_r, nhe_i;
  float scale_s[4];
};
struct KeyArgs { uint32_t k[8][2]; };

typedef __attribute__((ext_vector_type(8))) short short8;
typedef __attribute__((ext_vector_type(16))) float f32x16;

__device__ inline f32x16 zero16() {
  f32x16 v;
  #pragma unroll
  for (int i = 0; i < 16; ++i) v[i] = 0.f;
  return v;
}

__device__ inline unsigned short f2bf(float f) {
  uint32_t u = __float_as_uint(f);
  return (unsigned short)((u + 0x7fffu + ((u >> 16) & 1u)) >> 16);
}

// ---- Threefry2x32-20 (exact JAX cipher) ------------------------------------
__host__ __device__ inline void tf2x32(uint32_t k0, uint32_t k1, uint32_t x0, uint32_t x1,
                                       uint32_t& o0, uint32_t& o1) {
  const uint32_t ks0 = k0, ks1 = k1, ks2 = k0 ^ k1 ^ 0x1BD11BDAu;
  const uint32_t ks[3] = { ks0, ks1, ks2 };
  x0 += ks0; x1 += ks1;
  const int rot[2][4] = { {13,15,26,6}, {17,29,16,24} };
  for (int g = 0; g < 5; ++g) {
    const int* rr = rot[g & 1];
    for (int i = 0; i < 4; ++i) {
      x0 += x1;
      x1 = (x1 << rr[i]) | (x1 >> (32 - rr[i]));
      x1 ^= x0;
    }
    x0 += ks[(g + 1) % 3];
    x1 += ks[(g + 2) % 3] + (uint32_t)(g + 1);
  }
  o0 = x0; o1 = x1;
}

// ---- XLA ErfInv32 polynomial ------------------------------------------------
__device__ inline float erfinv_xla(float x) {
  float w = -log1pf(-x * x);
  float p;
  if (w < 5.0f) {
    w -= 2.5f;
    p = 2.81022636e-08f;
    p = fmaf(p, w, 3.43273939e-07f);
    p = fmaf(p, w, -3.5233877e-06f);
    p = fmaf(p, w, -4.39150654e-06f);
    p = fmaf(p, w, 0.00021858087f);
    p = fmaf(p, w, -0.00125372503f);
    p = fmaf(p, w, -0.00417768164f);
    p = fmaf(p, w, 0.246640727f);
    p = fmaf(p, w, 1.50140941f);
  } else {
    w = sqrtf(w) - 3.0f;
    p = -0.000200214257f;
    p = fmaf(p, w, 0.000100950558f);
    p = fmaf(p, w, 0.00134934322f);
    p = fmaf(p, w, -0.00367342844f);
    p = fmaf(p, w, 0.00573950773f);
    p = fmaf(p, w, -0.0076224613f);
    p = fmaf(p, w, 0.00943887047f);
    p = fmaf(p, w, 1.00167406f);
    p = fmaf(p, w, 2.83297682f);
  }
  return p * x;
}

__device__ inline float normal_from_bits(uint32_t bits) {
  uint32_t fb = (bits >> 9) | 0x3f800000u;
  float f = __uint_as_float(fb) - 1.0f;
  const float LO = -0.99999994f;
  float u = f * 2.0f + LO;
  u = fmaxf(LO, u);
  return 1.41421356f * erfinv_xla(u);
}

__device__ inline float sscale_f(uint32_t k, float nhe) {
  uint32_t kk = k ? k : 1u;
  return powf((float)kk * (1.0f / 1048576.0f), nhe);
}

__device__ inline float2 cmul(float2 a, float2 b) {
  return make_float2(a.x * b.x - a.y * b.y, a.x * b.y + a.y * b.x);
}
__device__ inline float2 wexp(float u) {
  float s, c; sincospif(2.0f * u, &s, &c); return make_float2(c, s);
}
__device__ inline float2 cadd(float2 a, float2 b){ return make_float2(a.x+b.x, a.y+b.y); }
__device__ inline float2 csub(float2 a, float2 b){ return make_float2(a.x-b.x, a.y-b.y); }
__device__ inline float2 cmuli(float2 a){ return make_float2(-a.y, a.x); }  // * (+i)

// LDS address swizzle for the FFT exchanges: <=4-way on all phases
__device__ inline int sA(int p) { return p ^ (((p >> 6) & 3) << 2) ^ ((p >> 8) & 3); }

// radix-4 DIF butterfly, sign +i, with twiddle W = omega^{n'}
__device__ inline void bfly(float2& y0, float2& y1, float2& y2, float2& y3, float2 W) {
  float2 a = cadd(y0, y2), b = csub(y0, y2);
  float2 c = cadd(y1, y3), d = cmuli(csub(y1, y3));
  float2 W2 = cmul(W, W), W3 = cmul(W2, W);
  y0 = cadd(a, c);
  y1 = cmul(cadd(b, d), W);
  y2 = cmul(csub(a, c), W2);
  y3 = cmul(csub(b, d), W3);
}

// 1024-pt FFT core (sign +), 64 threads, 16 pts/thread, 2 barriers.
__device__ inline void fft1024_core(float2* r, float2* rc, float2* buf, int w) {
  #pragma unroll
  for (int e3 = 0; e3 < 4; ++e3) {
    float2 W = wexp((float)((e3 << 6) + w) * (1.0f / 1024.0f));
    bfly(r[e3], r[e3 + 4], r[e3 + 8], r[e3 + 12], W);
  }
  {
    float2 W = wexp((float)w * (1.0f / 256.0f));
    #pragma unroll
    for (int e4 = 0; e4 < 4; ++e4)
      bfly(r[(e4 << 2) + 0], r[(e4 << 2) + 1], r[(e4 << 2) + 2], r[(e4 << 2) + 3], W);
  }
  #pragma unroll
  for (int s = 0; s < 16; ++s) buf[sA((s << 6) + w)] = r[s];
  __syncthreads();
  {
    const int e0 = w & 3;
    const int pbase = ((w >> 4) << 8) + (((w >> 2) & 3) << 6) + e0;
    float2 rb[16];
    #pragma unroll
    for (int e2 = 0; e2 < 4; ++e2)
      #pragma unroll
      for (int e1 = 0; e1 < 4; ++e1)
        rb[(e2 << 2) + e1] = buf[sA(pbase + (e2 << 4) + (e1 << 2))];
    #pragma unroll
    for (int e1 = 0; e1 < 4; ++e1) {
      float2 W = wexp((float)((e1 << 2) + e0) * (1.0f / 64.0f));
      bfly(rb[e1], rb[e1 + 4], rb[e1 + 8], rb[e1 + 12], W);
    }
    {
      float2 W = wexp((float)e0 * (1.0f / 16.0f));
      #pragma unroll
      for (int e2 = 0; e2 < 4; ++e2)
        bfly(rb[(e2 << 2) + 0], rb[(e2 << 2) + 1], rb[(e2 << 2) + 2], rb[(e2 << 2) + 3], W);
    }
    #pragma unroll
    for (int e2 = 0; e2 < 4; ++e2)
      #pragma unroll
      for (int e1 = 0; e1 < 4; ++e1)
        buf[sA(pbase + (e2 << 4) + (e1 << 2))] = rb[(e2 << 2) + e1];
  }
  __syncthreads();
  {
    const int cbase = ((w >> 4) << 8) + (((w >> 2) & 3) << 6) + ((w & 3) << 4);
    #pragma unroll
    for (int e1 = 0; e1 < 4; ++e1)
      #pragma unroll
      for (int e0 = 0; e0 < 4; ++e0)
        rc[(e1 << 2) + e0] = buf[sA(cbase + (e1 << 2) + e0)];
    #pragma unroll
    for (int e1 = 0; e1 < 4; ++e1) {
      float2 x0 = rc[(e1 << 2)], x1 = rc[(e1 << 2) + 1], x2 = rc[(e1 << 2) + 2], x3 = rc[(e1 << 2) + 3];
      float2 a = cadd(x0, x2), b = csub(x0, x2);
      float2 c = cadd(x1, x3), d = cmuli(csub(x1, x3));
      rc[(e1 << 2)]     = cadd(a, c);
      rc[(e1 << 2) + 1] = cadd(b, d);
      rc[(e1 << 2) + 2] = csub(a, c);
      rc[(e1 << 2) + 3] = csub(b, d);
    }
  }
}

// ---- scalars ----------------------------------------------------------------
__device__ inline float med8_dev(const float* p) {
  float v[8];
  for (int i = 0; i < 8; ++i) v[i] = p[i];
  for (int i = 1; i < 8; ++i) { float key = v[i]; int j = i - 1;
    while (j >= 0 && v[j] > key) { v[j + 1] = v[j]; --j; } v[j + 1] = key; }
  return 0.5f * (v[3] + v[4]);
}

__global__ void k_scalars(Hdr* h, const float* er, const float* ei, const float* ar,
                          const float* ai, const float* pr, const float* pim) {
  if (threadIdx.x || blockIdx.x) return;
  float mer = med8_dev(er), mei = med8_dev(ei);
  h->e_r = mer; h->e_i = mei;
  h->amp_r = med8_dev(ar); h->amp_i = med8_dev(ai);
  h->phi_r = (int)med8_dev(pr);
  h->phi_i = (int)med8_dev(pim);
  h->nhe_r = -0.5f * mer; h->nhe_i = -0.5f * mei;
}

__global__ void k_sumw2(const Hdr* __restrict__ h, float* __restrict__ partials) {
  __shared__ float sr_[256], si_[256];
  const float nher = h->nhe_r, nhei = h->nhe_i;
  float sr = 0.f, si = 0.f;
  for (int j = 0; j < 4; ++j) {
    uint32_t k = (uint32_t)(blockIdx.x * 1024 + j * 256 + threadIdx.x) + 1u;
    float fk = (float)k * (1.0f / 1048576.0f);
    float wr = powf(fk, nher), wi = powf(fk, nhei);
    if (k == NHALF) { wr *= 0.5f; wi *= 0.5f; }
    sr += wr * wr; si += wi * wi;
  }
  sr_[threadIdx.x] = sr; si_[threadIdx.x] = si; __syncthreads();
  for (int off = 128; off > 0; off >>= 1) {
    if ((int)threadIdx.x < off) { sr_[threadIdx.x] += sr_[threadIdx.x + off];
                                  si_[threadIdx.x] += si_[threadIdx.x + off]; }
    __syncthreads();
  }
  if (!threadIdx.x) { partials[blockIdx.x * 2] = sr_[0]; partials[blockIdx.x * 2 + 1] = si_[0]; }
}

__global__ void k_sumw2_fin(Hdr* h, const float* partials) {
  if (threadIdx.x || blockIdx.x) return;
  float Sr = 0.f, Si = 0.f;
  for (int b = 0; b < 512; ++b) { Sr += partials[b * 2]; Si += partials[b * 2 + 1]; }
  float sig_r = 2.0f * sqrtf(Sr) * (1.0f / 1048576.0f);
  float sig_i = 2.0f * sqrtf(Si) * (1.0f / 1048576.0f);
  float s0 = h->amp_r / (sig_r * 1048576.0f);
  float s1 = (h->amp_i * h->amp_i) / (sig_i * 1048576.0f);
  h->scale_s[0] = s0; h->scale_s[1] = s1; h->scale_s[2] = s0; h->scale_s[3] = s1;
}

// ---- wsum -------------------------------------------------------------------
__global__ void k_wsum(const float* __restrict__ w1, const float* __restrict__ w2,
                       float2* __restrict__ wsum) {
  int idx = blockIdx.x * 256 + threadIdx.x;
  int sel = idx >> 16, rem = idx & 65535;
  const float* w = sel ? w2 : w1;
  int c = rem >> 10, m1 = (rem >> 5) & 31, m2 = rem & 31;
  size_t base = (size_t)c * 131072 + (size_t)m1 * 64 + (size_t)m2 * 2;
  float sr = 0.f, si = 0.f;
  for (int oc = 0; oc < 64; ++oc) { sr += w[base + (size_t)oc * 2048]; si += w[base + (size_t)oc * 2048 + 1]; }
  wsum[idx] = make_float2(sr, si);
}

// ---- noise spectra: transposed float4 layout spT[pair][k1][k2] --------------
__global__ void k_noise_spec(float4* __restrict__ spT, const Hdr* __restrict__ h, KeyArgs ka) {
  const int pair = blockIdx.y;
  const int bx = blockIdx.x;
  const int k1 = bx >> 1, chunk = bx & 1;
  const int k2 = (chunk << 8) + (int)threadIdx.x;
  const float nher = h->nhe_r, nhei = h->nhe_i;
  float4* row = spT + (size_t)pair * (1024 * SPT_STRIDE) + (size_t)k1 * SPT_STRIDE;
  const bool extra = (k1 == 0) && (chunk == 1) && (threadIdx.x == 255);
  const int niter = extra ? 2 : 1;
  for (int it = 0; it < niter; ++it) {
    const int kk2 = (it == 0) ? k2 : 512;
    const uint32_t i = (uint32_t)k1 + ((uint32_t)kk2 << 10);
    float vals[4];
    #pragma unroll
    for (int j = 0; j < 4; ++j) {
      const uint32_t K0 = ka.k[pair * 4 + j][0], K1 = ka.k[pair * 4 + j][1];
      uint32_t o0, o1; tf2x32(K0, K1, 0u, i, o0, o1);
#if PART_XOR
      uint32_t bits = o0 ^ o1;
#else
      uint32_t bits = o1;
#endif
      float nhe = (j < 2) ? nher : nhei;
      float v = normal_from_bits(bits) * sscale_f(i, nhe);
      if (i == 0u || i == NHALF) v = (j & 1) ? 0.0f : v * 1.41421356f;
      vals[j] = v;
    }
    row[kk2] = make_float4(vals[0], vals[1], vals[2], vals[3]);
  }
}

// ---- irfft(2^20) stage 1 (complex-pair trick; 512 blocks) -------------------
__global__ __launch_bounds__(256) void k_fft_s1(const float4* __restrict__ spT,
                                                float2* __restrict__ G) {
  __shared__ float2 buf4[4][1024];
  const int b = blockIdx.x;
  const int lin = (b & 7) * 64 + (b >> 3);
  const int pair = lin >> 8;
  const int g = threadIdx.x >> 6, w = threadIdx.x & 63;
  const int k1 = ((lin & 255) << 2) + g;
  const float4* sp = spT + (size_t)pair * (1024 * SPT_STRIDE);
  const int mrow = (1024 - k1) & 1023;

  float2 r[16], rc[16];
  #pragma unroll
  for (int s = 0; s < 16; ++s) {
    int k2 = (s << 6) + w;
    uint32_t k = (uint32_t)k1 + ((uint32_t)k2 << 10);
    float4 f; float2 z;
    if (k <= NHALF) {
      f = sp[(size_t)k1 * SPT_STRIDE + k2];
      z = make_float2(f.x - f.w, f.y + f.z);
    } else {
      int k2p = (k1 == 0) ? (1024 - k2) : (1023 - k2);
      f = sp[(size_t)mrow * SPT_STRIDE + k2p];
      z = make_float2(f.x + f.w, f.z - f.y);
    }
    r[s] = z;
  }
  fft1024_core(r, rc, buf4[g], w);
  float2* gp = G + ((size_t)pair << 20) + ((size_t)k1 << 10);
  const int klo = ((w & 3) << 4) + (((w >> 2) & 3) << 2) + (w >> 4);
  #pragma unroll
  for (int e1 = 0; e1 < 4; ++e1)
    #pragma unroll
    for (int e0 = 0; e0 < 4; ++e0) {
      int k = (e0 << 8) + (e1 << 6) + klo;
      float2 tw = wexp((float)(k * k1) * (1.0f / 1048576.0f));
      gp[k] = cmul(rc[(e1 << 2) + e0], tw);
    }
}

// ---- stage 2: per j2, FFT over k1; noiseP[pair][j2][j1] ---------------------
__global__ __launch_bounds__(256) void k_fft_s2(const float2* __restrict__ G,
                                                float2* __restrict__ noiseP,
                                                const Hdr* __restrict__ h) {
  __shared__ float2 buf4[4][1024];
  const int b = blockIdx.x;
  const int lin = (b & 7) * 64 + (b >> 3);
  const int pair = lin >> 8;
  const int g = threadIdx.x >> 6, w = threadIdx.x & 63;
  const int j2 = ((lin & 255) << 2) + g;

  float2 r[16], rc[16];
  const float2* gp = G + ((size_t)pair << 20) + (size_t)j2;
  #pragma unroll
  for (int s = 0; s < 16; ++s) r[s] = gp[(size_t)((s << 6) + w) << 10];
  fft1024_core(r, rc, buf4[g], w);
  const float scr = h->scale_s[0], sci = h->scale_s[1];
  float2* np_ = noiseP + ((size_t)pair << 20) + ((size_t)j2 << 10);
  const int klo = ((w & 3) << 4) + (((w >> 2) & 3) << 2) + (w >> 4);
  #pragma unroll
  for (int e1 = 0; e1 < 4; ++e1)
    #pragma unroll
    for (int e0 = 0; e0 < 4; ++e0) {
      int k = (e0 << 8) + (e1 << 6) + klo;
      np_[k] = make_float2(rc[(e1 << 2) + e0].x * scr, rc[(e1 << 2) + e0].y * sci);
    }
}

// ---- noise linearize: transpose 1024x1024 (pairs) + roll fold ---------------
__global__ __launch_bounds__(256) void k_ntrans(const float2* __restrict__ noiseP,
                                                float* __restrict__ noiseL,
                                                const Hdr* __restrict__ h) {
  __shared__ float tr[64][65];
  __shared__ float ti[64][65];
  const int b = blockIdx.x;
  const int pair = b >> 8, tid = b & 255;
  const int R0 = (tid >> 4) << 6;
  const int C0 = (tid & 15) << 6;
  const int t = threadIdx.x;
  const int tx = t & 63, ty = t >> 6;
  const int phir = h->phi_r, phii = h->phi_i;
  const float2* src = noiseP + ((size_t)pair << 20);
  float* dstr = noiseL + ((size_t)(pair * 2) << 20);
  float* dsti = noiseL + ((size_t)(pair * 2 + 1) << 20);
  #pragma unroll
  for (int i = 0; i < 16; ++i) {
    int r = (i << 2) + ty;
    float2 v = src[(size_t)((R0 + r) << 10) + (size_t)(C0 + tx)];
    tr[r][tx] = v.x; ti[r][tx] = v.y;
  }
  __syncthreads();
  #pragma unroll
  for (int i = 0; i < 16; ++i) {
    int c = (i << 2) + ty;
    int n = ((C0 + c) << 10) + R0 + tx;
    dstr[(uint32_t)(n + phir) & (N20 - 1u)] = tr[tx][c];
    dsti[(uint32_t)(n + phii) & (N20 - 1u)] = ti[tx][c];
  }
}

// ---- constants: A_E, B2T (inverse) + ET, Fc, Fs, Fns (forward) --------------
__global__ __launch_bounds__(256) void k_prep(unsigned short* __restrict__ A_E,
                                              unsigned short* __restrict__ B2T,
                                              unsigned short* __restrict__ ET,
                                              unsigned short* __restrict__ Fc,
                                              unsigned short* __restrict__ Fs,
                                              unsigned short* __restrict__ Fns) {
  int t = blockIdx.x * 256 + threadIdx.x;
  if (t < 32768) {
    int y = t >> 7, p = t & 127;
    int kyp = p & 63; int ky = (kyp < 32) ? kyp : kyp + 192;
    float s, c; sincospif(2.0f * (float)((ky * y) & 255) * (1.0f / 256.0f), &s, &c);
    A_E[t] = f2bf((p < 64) ? c : s);
  } else if (t < 49152) {
    int u = t - 32768;
    int x = u >> 6, j = u & 63, kx = j & 31;
    float s, c; sincospif(2.0f * (float)((kx * x) & 255) * (1.0f / 256.0f), &s, &c);
    float v = (j < 32) ? ((kx == 0) ? 1.0f : 2.0f * c)
                       : ((kx == 0) ? 0.0f : -2.0f * s);
    B2T[u] = f2bf(v * (1.0f / 65536.0f));
  } else if (t < 65536) {
    int u = t - 49152;
    int col = u >> 8, xx = u & 255; int kx = col & 31;
    float s, c; sincospif(2.0f * (float)((kx * xx) & 255) * (1.0f / 256.0f), &s, &c);
    ET[u] = f2bf((col < 32) ? c : -s);
  } else if (t < 114688) {
    int u = (t - 65536) & 16383;
    int which = (t - 65536) >> 14;
    int kyp = u >> 8, y = u & 255; int ky = (kyp < 32) ? kyp : kyp + 192;
    float s, c; sincospif(2.0f * (float)((ky * y) & 255) * (1.0f / 256.0f), &s, &c);
    if (which == 0) Fc[u] = f2bf(c);
    else if (which == 1) Fs[u] = f2bf(s);
    else Fns[u] = f2bf(-s);
  }
}

// ---- forward via MFMA (register-prefetch pipelined x staging) ----------------
__global__ __launch_bounds__(256, 2) void k_forward(const float* __restrict__ x,
    const float2* __restrict__ wsum, const float* __restrict__ noiseL,
    const unsigned short* __restrict__ ET, const unsigned short* __restrict__ Fc,
    const unsigned short* __restrict__ Fs, const unsigned short* __restrict__ Fns,
    float2* __restrict__ oftg) {
  __shared__ char lds[65536];
  char* X1T = lds + 32768;
  const int bc = blockIdx.x, t = threadIdx.x;
  const int c = bc & 63;
  const int l = t & 63, w = t >> 6, lr = l & 31, kg = l >> 5;
  const int rt = w >> 1, ct = w & 1;
  const float* xim = x + ((size_t)bc << 16);

  // per-thread staging map (fixed across tiles)
  const int r_  = t >> 2;            // row within 64-row tile for loads 0..15: r = (i*256+t)>>6
  (void)r_;
  float4 pf[16];
  // prefetch tile 0
  #pragma unroll
  for (int i = 0; i < 16; ++i) {
    int f4 = i * 256 + t;
    int r = f4 >> 6, c4 = f4 & 63;
    pf[i] = *(const float4*)(xim + (size_t)((r) << 8) + (c4 << 2));
  }

  #pragma unroll
  for (int yt = 0; yt < 4; ++yt) {
    __syncthreads();                       // xs consumers of prev tile done
    #pragma unroll
    for (int i = 0; i < 16; ++i) {
      int f4 = i * 256 + t;
      int r = f4 >> 6, c4 = f4 & 63;
      ushort4 b4; b4.x = f2bf(pf[i].x); b4.y = f2bf(pf[i].y);
      b4.z = f2bf(pf[i].z); b4.w = f2bf(pf[i].w);
      int byte = ((r << 9) + (c4 << 3)) ^ ((r & 7) << 4);
      *(ushort4*)(lds + byte) = b4;
    }
    __syncthreads();
    if (yt < 3) {                          // issue next tile's loads (T14: hide under MFMA)
      #pragma unroll
      for (int i = 0; i < 16; ++i) {
        int f4 = i * 256 + t;
        int r = f4 >> 6, c4 = f4 & 63;
        pf[i] = *(const float4*)(xim + (size_t)((((yt + 1) << 6) + r) << 8) + (c4 << 2));
      }
    }
    f32x16 a1 = zero16();
    const int arow = (rt << 5) + lr;
    const int bcol = (ct << 5) + lr;
    #pragma unroll
    for (int s = 0; s < 16; ++s) {
      short8 af = *(const short8*)(lds + (((arow << 9) + (s << 5) + (kg << 4)) ^ ((arow & 7) << 4)));
      short8 bf = *(const short8*)(ET + (bcol << 8) + (s << 4) + (kg << 3));
      a1 = __builtin_amdgcn_mfma_f32_32x32x16_bf16(af, bf, a1, 0, 0, 0);
    }
    #pragma unroll
    for (int r4 = 0; r4 < 4; ++r4) {
      int y0 = (yt << 6) + (rt << 5) + (r4 << 3) + (kg << 2);
      ushort4 p4;
      p4.x = f2bf(a1[r4 * 4 + 0]); p4.y = f2bf(a1[r4 * 4 + 1]);
      p4.z = f2bf(a1[r4 * 4 + 2]); p4.w = f2bf(a1[r4 * 4 + 3]);
      int byte = ((bcol << 9) + (y0 << 1)) ^ ((bcol & 7) << 4);
      *(ushort4*)(X1T + byte) = p4;
    }
  }
  __syncthreads();

  const int re_im = w >> 1, kt = w & 1;
  const unsigned short* A1p = re_im ? Fns : Fs;
  const int b0row = (re_im ? 32 : 0) + lr;
  const int b1row = (re_im ? 0 : 32) + lr;
  const int a2row = (kt << 5) + lr;
  f32x16 a2 = zero16();
  #pragma unroll
  for (int s = 0; s < 16; ++s) {
    short8 a0f = *(const short8*)(Fc  + (a2row << 8) + (s << 4) + (kg << 3));
    short8 a1f = *(const short8*)(A1p + (a2row << 8) + (s << 4) + (kg << 3));
    short8 b0f = *(const short8*)(X1T + (((b0row << 9) + (s << 5) + (kg << 4)) ^ ((b0row & 7) << 4)));
    short8 b1f = *(const short8*)(X1T + (((b1row << 9) + (s << 5) + (kg << 4)) ^ ((b1row & 7) << 4)));
    a2 = __builtin_amdgcn_mfma_f32_32x32x16_bf16(a0f, b0f, a2, 0, 0, 0);
    a2 = __builtin_amdgcn_mfma_f32_32x32x16_bf16(a1f, b1f, a2, 0, 0, 0);
  }
  float* Osm = (float*)(lds + (re_im << 13));
  #pragma unroll
  for (int i = 0; i < 16; ++i) {
    int row = (kt << 5) + (i & 3) + ((i >> 2) << 3) + (kg << 2);
    Osm[(row << 5) + lr] = a2[i];
  }
  __syncthreads();

  const float* Ore = (const float*)lds;
  const float* Oim = (const float*)(lds + 8192);
  #pragma unroll
  for (int r = 0; r < 8; ++r) {
    int idx = (r << 8) + t;
    int kyp = idx >> 5, kx = idx & 31;
    int sel = kyp >> 5, m1 = kyp & 31;
    float2 av = make_float2(Ore[idx], Oim[idx]);
    float2 wv = wsum[((size_t)sel << 16) + (size_t)(((c << 5) | m1) << 5) + (size_t)kx];
    float2 v;
    v.x = av.x * wv.x - av.y * wv.y;
    v.y = av.x * wv.y + av.y * wv.x;
    uint32_t p = ((uint32_t)((bc << 5) | m1) << 5) | (uint32_t)kx;
    const float* nlr = noiseL + ((size_t)(sel ? 2 : 0) << 20);
    const float* nli = noiseL + ((size_t)(sel ? 3 : 1) << 20);
    v.x -= nlr[p];
    v.y -= nli[p];
    oftg[((size_t)bc << 11) + (size_t)idx] = v;
  }
}

// ---- inverse via two bf16 MFMA GEMMs per image ------------------------------
__global__ __launch_bounds__(256) void k_inverse(const float2* __restrict__ oftg,
    const unsigned short* __restrict__ A_E, const unsigned short* __restrict__ B2T,
    float* __restrict__ out) {
  __shared__ char smem[49152];
  char* Tb = smem + 16384;
  float* ofs = (float*)(smem + 16384);

  const int bc = blockIdx.x, t = threadIdx.x;
  const int l = t & 63, w = t >> 6, lr = l & 31, kg = l >> 5;

  {
    const float4* src = (const float4*)(oftg + ((size_t)bc << 11));
    float4* dst = (float4*)ofs;
    #pragma unroll
    for (int i = 0; i < 4; ++i) dst[t + (i << 8)] = src[t + (i << 8)];
  }
  __syncthreads();

  #pragma unroll
  for (int i = 0; i < 32; ++i) {
    int idx = t + (i << 8);
    int p = idx >> 6, j = idx & 63;
    int kyp = p & 63;
    float v;
    if (p < 64) v = (j < 32) ? ofs[(kyp << 6) + (j << 1)]
                             : ofs[(kyp << 6) + ((j - 32) << 1) + 1];
    else        v = (j < 32) ? -ofs[(kyp << 6) + (j << 1) + 1]
                             : ofs[(kyp << 6) + ((j - 32) << 1)];
    int byte = ((j << 8) + (p << 1)) ^ ((j & 7) << 4);
    *(unsigned short*)(smem + byte) = f2bf(v);
  }
  __syncthreads();

  f32x16 acc[2][2];
  acc[0][0] = zero16(); acc[0][1] = zero16(); acc[1][0] = zero16(); acc[1][1] = zero16();
  #pragma unroll
  for (int s = 0; s < 8; ++s) {
    short8 af[2], bf[2];
    #pragma unroll
    for (int rt = 0; rt < 2; ++rt) {
      int row = (w << 6) + (rt << 5) + lr;
      af[rt] = *(const short8*)(A_E + (row << 7) + (s << 4) + (kg << 3));
    }
    #pragma unroll
    for (int ct = 0; ct < 2; ++ct) {
      int j = (ct << 5) + lr;
      int byte = ((j << 8) + (s << 5) + (kg << 4)) ^ ((j & 7) << 4);
      bf[ct] = *(const short8*)(smem + byte);
    }
    #pragma unroll
    for (int rt = 0; rt < 2; ++rt)
      #pragma unroll
      for (int ct = 0; ct < 2; ++ct)
        acc[rt][ct] = __builtin_amdgcn_mfma_f32_32x32x16_bf16(af[rt], bf[ct], acc[rt][ct], 0, 0, 0);
  }

  #pragma unroll
  for (int rt = 0; rt < 2; ++rt)
    #pragma unroll
    for (int ct = 0; ct < 2; ++ct)
      #pragma unroll
      for (int r = 0; r < 16; ++r) {
        int row = (w << 6) + (rt << 5) + (r & 3) + (((r >> 2) & 3) << 3) + (kg << 2);
        int col = (ct << 5) + lr;
        int byte = ((row << 7) + (col << 1)) ^ ((row & 7) << 4);
        *(unsigned short*)(Tb + byte) = f2bf(acc[rt][ct][r]);
      }
  __syncthreads();

  short8 ta[2][4];
  #pragma unroll
  for (int rt = 0; rt < 2; ++rt)
    #pragma unroll
    for (int ks = 0; ks < 4; ++ks) {
      int row = (w << 6) + (rt << 5) + lr;
      int byte = ((row << 7) + (ks << 5) + (kg << 4)) ^ ((row & 7) << 4);
      ta[rt][ks] = *(const short8*)(Tb + byte);
    }
  float* op = out + ((size_t)bc << 16);
  #pragma unroll
  for (int cc = 0; cc < 4; ++cc) {
    short8 b2[2][4];
    #pragma unroll
    for (int cx = 0; cx < 2; ++cx)
      #pragma unroll
      for (int ks = 0; ks < 4; ++ks) {
        int xx = (cc << 6) + (cx << 5) + lr;
        b2[cx][ks] = *(const short8*)(B2T + (xx << 6) + (ks << 4) + (kg << 3));
      }
    f32x16 a2[2][2];
    a2[0][0] = zero16(); a2[0][1] = zero16(); a2[1][0] = zero16(); a2[1][1] = zero16();
    #pragma unroll
    for (int ks = 0; ks < 4; ++ks)
      #pragma unroll
      for (int rt = 0; rt < 2; ++rt)
        #pragma unroll
        for (int cx = 0; cx < 2; ++cx)
          a2[rt][cx] = __builtin_amdgcn_mfma_f32_32x32x16_bf16(ta[rt][ks], b2[cx][ks], a2[rt][cx], 0, 0, 0);
    #pragma unroll
    for (int rt = 0; rt < 2; ++rt)
      #pragma unroll
      for (int cx = 0; cx < 2; ++cx)
        #pragma unroll
        for (int r = 0; r < 16; ++r) {
          int row = (w << 6) + (rt << 5) + (r & 3) + (((r >> 2) & 3) << 3) + (kg << 2);
          int xx = (cc << 6) + (cx << 5) + lr;
          op[(row << 8) + xx] = a2[rt][cx][r];
        }
  }
}

// ---- host -------------------------------------------------------------------
extern "C" void kernel_launch(void* const* d_in, const int* in_sizes, int n_in,
                              void* d_out, int out_size, void* d_ws, size_t ws_size,
                              hipStream_t stream) {
  (void)in_sizes; (void)n_in; (void)out_size; (void)ws_size;
  const float* x   = (const float*)d_in[0];
  const float* w1  = (const float*)d_in[1];
  const float* w2  = (const float*)d_in[2];
  const float* er  = (const float*)d_in[3];
  const float* ei  = (const float*)d_in[4];
  const float* ar  = (const float*)d_in[5];
  const float* ai  = (const float*)d_in[6];
  const float* pr  = (const float*)d_in[7];
  const float* pim = (const float*)d_in[8];
  float* out = (float*)d_out;

  char* ws = (char*)d_ws;
  Hdr*    hdr      = (Hdr*)ws;
  float*  partials = (float*)(ws + 0x1000);
  float2* wsum     = (float2*)(ws + 0x10000);
  unsigned short* A_E = (unsigned short*)(ws + 0x130000);
  unsigned short* B2T = (unsigned short*)(ws + 0x140000);
  unsigned short* ET  = (unsigned short*)(ws + 0x148000);
  unsigned short* Fc  = (unsigned short*)(ws + 0x150000);
  unsigned short* Fs  = (unsigned short*)(ws + 0x158000);
  unsigned short* Fns = (unsigned short*)(ws + 0x160000);
  float4* spT      = (float4*)(ws + 0x200000);
  float2* G        = (float2*)(ws + 0x1400000);
  float2* oft      = (float2*)(ws + 0x1400000);   // aliases G (dead after s2)
  float2* noiseP   = (float2*)(ws + 0x2400000);
  float*  noiseL   = (float*)(ws + 0x3400000);

  auto splitk = [](const uint32_t k[2], uint32_t a[2], uint32_t b[2]) {
#if JPART
    tf2x32(k[0], k[1], 0u, 0u, a[0], a[1]);
    tf2x32(k[0], k[1], 0u, 1u, b[0], b[1]);
#else
    uint32_t r0[2], r1[2];
    tf2x32(k[0], k[1], 0u, 2u, r0[0], r0[1]);
    tf2x32(k[0], k[1], 1u, 3u, r1[0], r1[1]);
    a[0] = r0[0]; a[1] = r1[0]; b[0] = r0[1]; b[1] = r1[1];
#endif
  };
  uint32_t root[2] = { 0u, 42u };
  uint32_t kA[2], kB[2], k1A[2], k2A[2], k1B[2], k2B[2];
  splitk(root, kA, kB);
  splitk(kA, k1A, k2A);
  splitk(kB, k1B, k2B);
  KeyArgs ka;
  splitk(k1A, ka.k[0], ka.k[1]);
  splitk(k2A, ka.k[2], ka.k[3]);
  splitk(k1B, ka.k[4], ka.k[5]);
  splitk(k2B, ka.k[6], ka.k[7]);

  hipLaunchKernelGGL(k_scalars,    dim3(1),        dim3(64),  0, stream, hdr, er, ei, ar, ai, pr, pim);
  hipLaunchKernelGGL(k_sumw2,      dim3(512),      dim3(256), 0, stream, hdr, partials);
  hipLaunchKernelGGL(k_sumw2_fin,  dim3(1),        dim3(64),  0, stream, hdr, partials);
  hipLaunchKernelGGL(k_wsum,       dim3(512),      dim3(256), 0, stream, w1, w2, wsum);
  hipLaunchKernelGGL(k_prep,       dim3(448),      dim3(256), 0, stream, A_E, B2T, ET, Fc, Fs, Fns);
  hipLaunchKernelGGL(k_noise_spec, dim3(2048, 2),  dim3(256), 0, stream, spT, hdr, ka);
  hipLaunchKernelGGL(k_fft_s1,     dim3(512),      dim3(256), 0, stream, spT, G);
  hipLaunchKernelGGL(k_fft_s2,     dim3(512),      dim3(256), 0, stream, G, noiseP, hdr);
  hipLaunchKernelGGL(k_ntrans,     dim3(512),      dim3(256), 0, stream, noiseP, noiseL, hdr);
  hipLaunchKernelGGL(k_forward,    dim3(1024),     dim3(256), 0, stream, x, wsum, noiseL, ET, Fc, Fs, Fns, oft);
  hipLaunchKernelGGL(k_inverse,    dim3(1024),     dim3(256), 0, stream, oft, A_E, B2T, out);
}

// Round 11
// 267.751 us; speedup vs baseline: 1.3781x; 1.0109x over previous
//
#include <hip/hip_runtime.h>
#include <cstdint>

// ---- JAX PRNG mode switches -------------------------------------------------
#define JPART 1
#define PART_XOR 1

constexpr uint32_t N20   = 1u << 20;
constexpr uint32_t NHALF = 1u << 19;
constexpr int SPT_STRIDE = 520;   // padded row stride (float4 elems) for spT

struct Hdr {
  float e_r, e_i, amp_r, amp_i;
  int   phi_r, phi_i;
  float nhe_r, nhe_i;
  float scale_s[4];
};
struct KeyArgs { uint32_t k[8][2]; };

typedef __attribute__((ext_vector_type(8))) short short8;
typedef __attribute__((ext_vector_type(16))) float f32x16;

__device__ inline f32x16 zero16() {
  f32x16 v;
  #pragma unroll
  for (int i = 0; i < 16; ++i) v[i] = 0.f;
  return v;
}

__device__ inline unsigned short f2bf(float f) {
  uint32_t u = __float_as_uint(f);
  return (unsigned short)((u + 0x7fffu + ((u >> 16) & 1u)) >> 16);
}

// ---- Threefry2x32-20 (exact JAX cipher) ------------------------------------
__host__ __device__ inline void tf2x32(uint32_t k0, uint32_t k1, uint32_t x0, uint32_t x1,
                                       uint32_t& o0, uint32_t& o1) {
  const uint32_t ks0 = k0, ks1 = k1, ks2 = k0 ^ k1 ^ 0x1BD11BDAu;
  const uint32_t ks[3] = { ks0, ks1, ks2 };
  x0 += ks0; x1 += ks1;
  const int rot[2][4] = { {13,15,26,6}, {17,29,16,24} };
  for (int g = 0; g < 5; ++g) {
    const int* rr = rot[g & 1];
    for (int i = 0; i < 4; ++i) {
      x0 += x1;
      x1 = (x1 << rr[i]) | (x1 >> (32 - rr[i]));
      x1 ^= x0;
    }
    x0 += ks[(g + 1) % 3];
    x1 += ks[(g + 2) % 3] + (uint32_t)(g + 1);
  }
  o0 = x0; o1 = x1;
}

// ---- XLA ErfInv32 polynomial ------------------------------------------------
__device__ inline float erfinv_xla(float x) {
  float w = -log1pf(-x * x);
  float p;
  if (w < 5.0f) {
    w -= 2.5f;
    p = 2.81022636e-08f;
    p = fmaf(p, w, 3.43273939e-07f);
    p = fmaf(p, w, -3.5233877e-06f);
    p = fmaf(p, w, -4.39150654e-06f);
    p = fmaf(p, w, 0.00021858087f);
    p = fmaf(p, w, -0.00125372503f);
    p = fmaf(p, w, -0.00417768164f);
    p = fmaf(p, w, 0.246640727f);
    p = fmaf(p, w, 1.50140941f);
  } else {
    w = sqrtf(w) - 3.0f;
    p = -0.000200214257f;
    p = fmaf(p, w, 0.000100950558f);
    p = fmaf(p, w, 0.00134934322f);
    p = fmaf(p, w, -0.00367342844f);
    p = fmaf(p, w, 0.00573950773f);
    p = fmaf(p, w, -0.0076224613f);
    p = fmaf(p, w, 0.00943887047f);
    p = fmaf(p, w, 1.00167406f);
    p = fmaf(p, w, 2.83297682f);
  }
  return p * x;
}

__device__ inline float normal_from_bits(uint32_t bits) {
  uint32_t fb = (bits >> 9) | 0x3f800000u;
  float f = __uint_as_float(fb) - 1.0f;
  const float LO = -0.99999994f;
  float u = f * 2.0f + LO;
  u = fmaxf(LO, u);
  return 1.41421356f * erfinv_xla(u);
}

__device__ inline float sscale_f(uint32_t k, float nhe) {
  uint32_t kk = k ? k : 1u;
  return powf((float)kk * (1.0f / 1048576.0f), nhe);
}

__device__ inline float2 cmul(float2 a, float2 b) {
  return make_float2(a.x * b.x - a.y * b.y, a.x * b.y + a.y * b.x);
}
__device__ inline float2 wexp(float u) {
  float s, c; sincospif(2.0f * u, &s, &c); return make_float2(c, s);
}
__device__ inline float2 cadd(float2 a, float2 b){ return make_float2(a.x+b.x, a.y+b.y); }
__device__ inline float2 csub(float2 a, float2 b){ return make_float2(a.x-b.x, a.y-b.y); }
__device__ inline float2 cmuli(float2 a){ return make_float2(-a.y, a.x); }  // * (+i)

// LDS address swizzle for the FFT exchanges: <=4-way on all phases
__device__ inline int sA(int p) { return p ^ (((p >> 6) & 3) << 2) ^ ((p >> 8) & 3); }

// radix-4 DIF butterfly, sign +i, with twiddle W = omega^{n'}
__device__ inline void bfly(float2& y0, float2& y1, float2& y2, float2& y3, float2 W) {
  float2 a = cadd(y0, y2), b = csub(y0, y2);
  float2 c = cadd(y1, y3), d = cmuli(csub(y1, y3));
  float2 W2 = cmul(W, W), W3 = cmul(W2, W);
  y0 = cadd(a, c);
  y1 = cmul(cadd(b, d), W);
  y2 = cmul(csub(a, c), W2);
  y3 = cmul(csub(b, d), W3);
}

// 1024-pt FFT core (sign +), 64 threads, 16 pts/thread, 2 barriers.
__device__ inline void fft1024_core(float2* r, float2* rc, float2* buf, int w) {
  #pragma unroll
  for (int e3 = 0; e3 < 4; ++e3) {
    float2 W = wexp((float)((e3 << 6) + w) * (1.0f / 1024.0f));
    bfly(r[e3], r[e3 + 4], r[e3 + 8], r[e3 + 12], W);
  }
  {
    float2 W = wexp((float)w * (1.0f / 256.0f));
    #pragma unroll
    for (int e4 = 0; e4 < 4; ++e4)
      bfly(r[(e4 << 2) + 0], r[(e4 << 2) + 1], r[(e4 << 2) + 2], r[(e4 << 2) + 3], W);
  }
  #pragma unroll
  for (int s = 0; s < 16; ++s) buf[sA((s << 6) + w)] = r[s];
  __syncthreads();
  {
    const int e0 = w & 3;
    const int pbase = ((w >> 4) << 8) + (((w >> 2) & 3) << 6) + e0;
    float2 rb[16];
    #pragma unroll
    for (int e2 = 0; e2 < 4; ++e2)
      #pragma unroll
      for (int e1 = 0; e1 < 4; ++e1)
        rb[(e2 << 2) + e1] = buf[sA(pbase + (e2 << 4) + (e1 << 2))];
    #pragma unroll
    for (int e1 = 0; e1 < 4; ++e1) {
      float2 W = wexp((float)((e1 << 2) + e0) * (1.0f / 64.0f));
      bfly(rb[e1], rb[e1 + 4], rb[e1 + 8], rb[e1 + 12], W);
    }
    {
      float2 W = wexp((float)e0 * (1.0f / 16.0f));
      #pragma unroll
      for (int e2 = 0; e2 < 4; ++e2)
        bfly(rb[(e2 << 2) + 0], rb[(e2 << 2) + 1], rb[(e2 << 2) + 2], rb[(e2 << 2) + 3], W);
    }
    #pragma unroll
    for (int e2 = 0; e2 < 4; ++e2)
      #pragma unroll
      for (int e1 = 0; e1 < 4; ++e1)
        buf[sA(pbase + (e2 << 4) + (e1 << 2))] = rb[(e2 << 2) + e1];
  }
  __syncthreads();
  {
    const int cbase = ((w >> 4) << 8) + (((w >> 2) & 3) << 6) + ((w & 3) << 4);
    #pragma unroll
    for (int e1 = 0; e1 < 4; ++e1)
      #pragma unroll
      for (int e0 = 0; e0 < 4; ++e0)
        rc[(e1 << 2) + e0] = buf[sA(cbase + (e1 << 2) + e0)];
    #pragma unroll
    for (int e1 = 0; e1 < 4; ++e1) {
      float2 x0 = rc[(e1 << 2)], x1 = rc[(e1 << 2) + 1], x2 = rc[(e1 << 2) + 2], x3 = rc[(e1 << 2) + 3];
      float2 a = cadd(x0, x2), b = csub(x0, x2);
      float2 c = cadd(x1, x3), d = cmuli(csub(x1, x3));
      rc[(e1 << 2)]     = cadd(a, c);
      rc[(e1 << 2) + 1] = cadd(b, d);
      rc[(e1 << 2) + 2] = csub(a, c);
      rc[(e1 << 2) + 3] = csub(b, d);
    }
  }
}

// ---- scalars helper ----------------------------------------------------------
__device__ inline float med8_dev(const float* p) {
  float v[8];
  for (int i = 0; i < 8; ++i) v[i] = p[i];
  for (int i = 1; i < 8; ++i) { float key = v[i]; int j = i - 1;
    while (j >= 0 && v[j] > key) { v[j + 1] = v[j]; --j; } v[j + 1] = key; }
  return 0.5f * (v[3] + v[4]);
}

// ---- merged: scalars (blk 960) + wsum (blk 0..511) + prep (blk 512..959) ----
__global__ __launch_bounds__(256) void k_misc(Hdr* h,
    const float* er, const float* ei, const float* ar, const float* ai,
    const float* pr, const float* pim,
    const float* __restrict__ w1, const float* __restrict__ w2,
    float2* __restrict__ wsum,
    unsigned short* __restrict__ A_E, unsigned short* __restrict__ B2T,
    unsigned short* __restrict__ ET, unsigned short* __restrict__ Fc,
    unsigned short* __restrict__ Fs, unsigned short* __restrict__ Fns) {
  const int b = blockIdx.x;
  if (b == 960) {
    if (threadIdx.x) return;
    float mer = med8_dev(er), mei = med8_dev(ei);
    h->e_r = mer; h->e_i = mei;
    h->amp_r = med8_dev(ar); h->amp_i = med8_dev(ai);
    h->phi_r = (int)med8_dev(pr);
    h->phi_i = (int)med8_dev(pim);
    h->nhe_r = -0.5f * mer; h->nhe_i = -0.5f * mei;
    return;
  }
  if (b < 512) {
    int idx = b * 256 + threadIdx.x;
    int sel = idx >> 16, rem = idx & 65535;
    const float* w = sel ? w2 : w1;
    int c = rem >> 10, m1 = (rem >> 5) & 31, m2 = rem & 31;
    size_t base = (size_t)c * 131072 + (size_t)m1 * 64 + (size_t)m2 * 2;
    float sr = 0.f, si = 0.f;
    for (int oc = 0; oc < 64; ++oc) { sr += w[base + (size_t)oc * 2048]; si += w[base + (size_t)oc * 2048 + 1]; }
    wsum[idx] = make_float2(sr, si);
    return;
  }
  int t = (b - 512) * 256 + threadIdx.x;
  if (t < 32768) {
    int y = t >> 7, p = t & 127;
    int kyp = p & 63; int ky = (kyp < 32) ? kyp : kyp + 192;
    float s, c; sincospif(2.0f * (float)((ky * y) & 255) * (1.0f / 256.0f), &s, &c);
    A_E[t] = f2bf((p < 64) ? c : s);
  } else if (t < 49152) {
    int u = t - 32768;
    int x = u >> 6, j = u & 63, kx = j & 31;
    float s, c; sincospif(2.0f * (float)((kx * x) & 255) * (1.0f / 256.0f), &s, &c);
    float v = (j < 32) ? ((kx == 0) ? 1.0f : 2.0f * c)
                       : ((kx == 0) ? 0.0f : -2.0f * s);
    B2T[u] = f2bf(v * (1.0f / 65536.0f));
  } else if (t < 65536) {
    int u = t - 49152;
    int col = u >> 8, xx = u & 255; int kx = col & 31;
    float s, c; sincospif(2.0f * (float)((kx * xx) & 255) * (1.0f / 256.0f), &s, &c);
    ET[u] = f2bf((col < 32) ? c : -s);
  } else if (t < 114688) {
    int u = (t - 65536) & 16383;
    int which = (t - 65536) >> 14;
    int kyp = u >> 8, y = u & 255; int ky = (kyp < 32) ? kyp : kyp + 192;
    float s, c; sincospif(2.0f * (float)((ky * y) & 255) * (1.0f / 256.0f), &s, &c);
    if (which == 0) Fc[u] = f2bf(c);
    else if (which == 1) Fs[u] = f2bf(s);
    else Fns[u] = f2bf(-s);
  }
}

// ---- merged: sumw2 (blk 0..511) + noise_spec (blk 512..4607) ----------------
__global__ __launch_bounds__(256) void k_gen(const Hdr* __restrict__ h,
                                             float* __restrict__ partials,
                                             float4* __restrict__ spT, KeyArgs ka) {
  __shared__ float sr_[256], si_[256];
  const int b = blockIdx.x;
  if (b < 512) {
    const float nher = h->nhe_r, nhei = h->nhe_i;
    float sr = 0.f, si = 0.f;
    for (int j = 0; j < 4; ++j) {
      uint32_t k = (uint32_t)(b * 1024 + j * 256 + threadIdx.x) + 1u;
      float fk = (float)k * (1.0f / 1048576.0f);
      float wr = powf(fk, nher), wi = powf(fk, nhei);
      if (k == NHALF) { wr *= 0.5f; wi *= 0.5f; }
      sr += wr * wr; si += wi * wi;
    }
    sr_[threadIdx.x] = sr; si_[threadIdx.x] = si; __syncthreads();
    for (int off = 128; off > 0; off >>= 1) {
      if ((int)threadIdx.x < off) { sr_[threadIdx.x] += sr_[threadIdx.x + off];
                                    si_[threadIdx.x] += si_[threadIdx.x + off]; }
      __syncthreads();
    }
    if (!threadIdx.x) { partials[b * 2] = sr_[0]; partials[b * 2 + 1] = si_[0]; }
    return;
  }
  const int idx = b - 512;                     // 0..4095
  const int pair = idx >> 11;                  // 0..1
  const int bx = idx & 2047;
  const int k1 = bx >> 1, chunk = bx & 1;
  const int k2 = (chunk << 8) + (int)threadIdx.x;
  const float nher = h->nhe_r, nhei = h->nhe_i;
  float4* row = spT + (size_t)pair * (1024 * SPT_STRIDE) + (size_t)k1 * SPT_STRIDE;
  const bool extra = (k1 == 0) && (chunk == 1) && (threadIdx.x == 255);
  const int niter = extra ? 2 : 1;
  for (int it = 0; it < niter; ++it) {
    const int kk2 = (it == 0) ? k2 : 512;
    const uint32_t i = (uint32_t)k1 + ((uint32_t)kk2 << 10);
    float vals[4];
    #pragma unroll
    for (int j = 0; j < 4; ++j) {
      const uint32_t K0 = ka.k[pair * 4 + j][0], K1 = ka.k[pair * 4 + j][1];
      uint32_t o0, o1; tf2x32(K0, K1, 0u, i, o0, o1);
#if PART_XOR
      uint32_t bits = o0 ^ o1;
#else
      uint32_t bits = o1;
#endif
      float nhe = (j < 2) ? nher : nhei;
      float v = normal_from_bits(bits) * sscale_f(i, nhe);
      if (i == 0u || i == NHALF) v = (j & 1) ? 0.0f : v * 1.41421356f;
      vals[j] = v;
    }
    row[kk2] = make_float4(vals[0], vals[1], vals[2], vals[3]);
  }
}

__global__ void k_sumw2_fin(Hdr* h, const float* partials) {
  if (threadIdx.x || blockIdx.x) return;
  float Sr = 0.f, Si = 0.f;
  for (int b = 0; b < 512; ++b) { Sr += partials[b * 2]; Si += partials[b * 2 + 1]; }
  float sig_r = 2.0f * sqrtf(Sr) * (1.0f / 1048576.0f);
  float sig_i = 2.0f * sqrtf(Si) * (1.0f / 1048576.0f);
  float s0 = h->amp_r / (sig_r * 1048576.0f);
  float s1 = (h->amp_i * h->amp_i) / (sig_i * 1048576.0f);
  h->scale_s[0] = s0; h->scale_s[1] = s1; h->scale_s[2] = s0; h->scale_s[3] = s1;
}

// ---- irfft(2^20) stage 1 (complex-pair trick; 512 blocks) -------------------
__global__ __launch_bounds__(256) void k_fft_s1(const float4* __restrict__ spT,
                                                float2* __restrict__ G) {
  __shared__ float2 buf4[4][1024];
  const int b = blockIdx.x;
  const int lin = (b & 7) * 64 + (b >> 3);
  const int pair = lin >> 8;
  const int g = threadIdx.x >> 6, w = threadIdx.x & 63;
  const int k1 = ((lin & 255) << 2) + g;
  const float4* sp = spT + (size_t)pair * (1024 * SPT_STRIDE);
  const int mrow = (1024 - k1) & 1023;

  float2 r[16], rc[16];
  #pragma unroll
  for (int s = 0; s < 16; ++s) {
    int k2 = (s << 6) + w;
    uint32_t k = (uint32_t)k1 + ((uint32_t)k2 << 10);
    float4 f; float2 z;
    if (k <= NHALF) {
      f = sp[(size_t)k1 * SPT_STRIDE + k2];
      z = make_float2(f.x - f.w, f.y + f.z);
    } else {
      int k2p = (k1 == 0) ? (1024 - k2) : (1023 - k2);
      f = sp[(size_t)mrow * SPT_STRIDE + k2p];
      z = make_float2(f.x + f.w, f.z - f.y);
    }
    r[s] = z;
  }
  fft1024_core(r, rc, buf4[g], w);
  float2* gp = G + ((size_t)pair << 20) + ((size_t)k1 << 10);
  const int klo = ((w & 3) << 4) + (((w >> 2) & 3) << 2) + (w >> 4);
  #pragma unroll
  for (int e1 = 0; e1 < 4; ++e1)
    #pragma unroll
    for (int e0 = 0; e0 < 4; ++e0) {
      int k = (e0 << 8) + (e1 << 6) + klo;
      float2 tw = wexp((float)(k * k1) * (1.0f / 1048576.0f));
      gp[k] = cmul(rc[(e1 << 2) + e0], tw);
    }
}

// ---- stage 2: per j2, FFT over k1; noiseP[pair][j2][j1] ---------------------
__global__ __launch_bounds__(256) void k_fft_s2(const float2* __restrict__ G,
                                                float2* __restrict__ noiseP,
                                                const Hdr* __restrict__ h) {
  __shared__ float2 buf4[4][1024];
  const int b = blockIdx.x;
  const int lin = (b & 7) * 64 + (b >> 3);
  const int pair = lin >> 8;
  const int g = threadIdx.x >> 6, w = threadIdx.x & 63;
  const int j2 = ((lin & 255) << 2) + g;

  float2 r[16], rc[16];
  const float2* gp = G + ((size_t)pair << 20) + (size_t)j2;
  #pragma unroll
  for (int s = 0; s < 16; ++s) r[s] = gp[(size_t)((s << 6) + w) << 10];
  fft1024_core(r, rc, buf4[g], w);
  const float scr = h->scale_s[0], sci = h->scale_s[1];
  float2* np_ = noiseP + ((size_t)pair << 20) + ((size_t)j2 << 10);
  const int klo = ((w & 3) << 4) + (((w >> 2) & 3) << 2) + (w >> 4);
  #pragma unroll
  for (int e1 = 0; e1 < 4; ++e1)
    #pragma unroll
    for (int e0 = 0; e0 < 4; ++e0) {
      int k = (e0 << 8) + (e1 << 6) + klo;
      np_[k] = make_float2(rc[(e1 << 2) + e0].x * scr, rc[(e1 << 2) + e0].y * sci);
    }
}

// ---- noise linearize: transpose 1024x1024 (pairs) + roll fold ---------------
__global__ __launch_bounds__(256) void k_ntrans(const float2* __restrict__ noiseP,
                                                float* __restrict__ noiseL,
                                                const Hdr* __restrict__ h) {
  __shared__ float tr[64][65];
  __shared__ float ti[64][65];
  const int b = blockIdx.x;
  const int pair = b >> 8, tid = b & 255;
  const int R0 = (tid >> 4) << 6;
  const int C0 = (tid & 15) << 6;
  const int t = threadIdx.x;
  const int tx = t & 63, ty = t >> 6;
  const int phir = h->phi_r, phii = h->phi_i;
  const float2* src = noiseP + ((size_t)pair << 20);
  float* dstr = noiseL + ((size_t)(pair * 2) << 20);
  float* dsti = noiseL + ((size_t)(pair * 2 + 1) << 20);
  #pragma unroll
  for (int i = 0; i < 16; ++i) {
    int r = (i << 2) + ty;
    float2 v = src[(size_t)((R0 + r) << 10) + (size_t)(C0 + tx)];
    tr[r][tx] = v.x; ti[r][tx] = v.y;
  }
  __syncthreads();
  #pragma unroll
  for (int i = 0; i < 16; ++i) {
    int c = (i << 2) + ty;
    int n = ((C0 + c) << 10) + R0 + tx;
    dstr[(uint32_t)(n + phir) & (N20 - 1u)] = tr[tx][c];
    dsti[(uint32_t)(n + phii) & (N20 - 1u)] = ti[tx][c];
  }
}

// ---- forward via MFMA (register-prefetch pipelined x staging) ----------------
__global__ __launch_bounds__(256, 2) void k_forward(const float* __restrict__ x,
    const float2* __restrict__ wsum, const float* __restrict__ noiseL,
    const unsigned short* __restrict__ ET, const unsigned short* __restrict__ Fc,
    const unsigned short* __restrict__ Fs, const unsigned short* __restrict__ Fns,
    float2* __restrict__ oftg) {
  __shared__ char lds[65536];
  char* X1T = lds + 32768;
  const int bc = blockIdx.x, t = threadIdx.x;
  const int c = bc & 63;
  const int l = t & 63, w = t >> 6, lr = l & 31, kg = l >> 5;
  const int rt = w >> 1, ct = w & 1;
  const float* xim = x + ((size_t)bc << 16);

  float4 pf[16];
  #pragma unroll
  for (int i = 0; i < 16; ++i) {
    int f4 = i * 256 + t;
    int r = f4 >> 6, c4 = f4 & 63;
    pf[i] = *(const float4*)(xim + (size_t)((r) << 8) + (c4 << 2));
  }

  #pragma unroll
  for (int yt = 0; yt < 4; ++yt) {
    __syncthreads();
    #pragma unroll
    for (int i = 0; i < 16; ++i) {
      int f4 = i * 256 + t;
      int r = f4 >> 6, c4 = f4 & 63;
      ushort4 b4; b4.x = f2bf(pf[i].x); b4.y = f2bf(pf[i].y);
      b4.z = f2bf(pf[i].z); b4.w = f2bf(pf[i].w);
      int byte = ((r << 9) + (c4 << 3)) ^ ((r & 7) << 4);
      *(ushort4*)(lds + byte) = b4;
    }
    __syncthreads();
    if (yt < 3) {
      #pragma unroll
      for (int i = 0; i < 16; ++i) {
        int f4 = i * 256 + t;
        int r = f4 >> 6, c4 = f4 & 63;
        pf[i] = *(const float4*)(xim + (size_t)((((yt + 1) << 6) + r) << 8) + (c4 << 2));
      }
    }
    f32x16 a1 = zero16();
    const int arow = (rt << 5) + lr;
    const int bcol = (ct << 5) + lr;
    #pragma unroll
    for (int s = 0; s < 16; ++s) {
      short8 af = *(const short8*)(lds + (((arow << 9) + (s << 5) + (kg << 4)) ^ ((arow & 7) << 4)));
      short8 bf = *(const short8*)(ET + (bcol << 8) + (s << 4) + (kg << 3));
      a1 = __builtin_amdgcn_mfma_f32_32x32x16_bf16(af, bf, a1, 0, 0, 0);
    }
    #pragma unroll
    for (int r4 = 0; r4 < 4; ++r4) {
      int y0 = (yt << 6) + (rt << 5) + (r4 << 3) + (kg << 2);
      ushort4 p4;
      p4.x = f2bf(a1[r4 * 4 + 0]); p4.y = f2bf(a1[r4 * 4 + 1]);
      p4.z = f2bf(a1[r4 * 4 + 2]); p4.w = f2bf(a1[r4 * 4 + 3]);
      int byte = ((bcol << 9) + (y0 << 1)) ^ ((bcol & 7) << 4);
      *(ushort4*)(X1T + byte) = p4;
    }
  }
  __syncthreads();

  const int re_im = w >> 1, kt = w & 1;
  const unsigned short* A1p = re_im ? Fns : Fs;
  const int b0row = (re_im ? 32 : 0) + lr;
  const int b1row = (re_im ? 0 : 32) + lr;
  const int a2row = (kt << 5) + lr;
  f32x16 a2 = zero16();
  #pragma unroll
  for (int s = 0; s < 16; ++s) {
    short8 a0f = *(const short8*)(Fc  + (a2row << 8) + (s << 4) + (kg << 3));
    short8 a1f = *(const short8*)(A1p + (a2row << 8) + (s << 4) + (kg << 3));
    short8 b0f = *(const short8*)(X1T + (((b0row << 9) + (s << 5) + (kg << 4)) ^ ((b0row & 7) << 4)));
    short8 b1f = *(const short8*)(X1T + (((b1row << 9) + (s << 5) + (kg << 4)) ^ ((b1row & 7) << 4)));
    a2 = __builtin_amdgcn_mfma_f32_32x32x16_bf16(a0f, b0f, a2, 0, 0, 0);
    a2 = __builtin_amdgcn_mfma_f32_32x32x16_bf16(a1f, b1f, a2, 0, 0, 0);
  }
  float* Osm = (float*)(lds + (re_im << 13));
  #pragma unroll
  for (int i = 0; i < 16; ++i) {
    int row = (kt << 5) + (i & 3) + ((i >> 2) << 3) + (kg << 2);
    Osm[(row << 5) + lr] = a2[i];
  }
  __syncthreads();

  const float* Ore = (const float*)lds;
  const float* Oim = (const float*)(lds + 8192);
  #pragma unroll
  for (int r = 0; r < 8; ++r) {
    int idx = (r << 8) + t;
    int kyp = idx >> 5, kx = idx & 31;
    int sel = kyp >> 5, m1 = kyp & 31;
    float2 av = make_float2(Ore[idx], Oim[idx]);
    float2 wv = wsum[((size_t)sel << 16) + (size_t)(((c << 5) | m1) << 5) + (size_t)kx];
    float2 v;
    v.x = av.x * wv.x - av.y * wv.y;
    v.y = av.x * wv.y + av.y * wv.x;
    uint32_t p = ((uint32_t)((bc << 5) | m1) << 5) | (uint32_t)kx;
    const float* nlr = noiseL + ((size_t)(sel ? 2 : 0) << 20);
    const float* nli = noiseL + ((size_t)(sel ? 3 : 1) << 20);
    v.x -= nlr[p];
    v.y -= nli[p];
    oftg[((size_t)bc << 11) + (size_t)idx] = v;
  }
}

// ---- inverse via two bf16 MFMA GEMMs per image (32KB LDS, 4 blocks/CU) ------
__global__ __launch_bounds__(256) void k_inverse(const float2* __restrict__ oftg,
    const unsigned short* __restrict__ A_E, const unsigned short* __restrict__ B2T,
    float* __restrict__ out) {
  __shared__ char smem[32768];   // Mt in [0,16384) during GEMM1; Tb in [0,32768) after

  const int bc = blockIdx.x, t = threadIdx.x;
  const int l = t & 63, w = t >> 6, lr = l & 31, kg = l >> 5;

  // build Mt[64 j][128 p] bf16 swizzled, reading oft directly from global (L2)
  {
    const float* ob = (const float*)(oftg + ((size_t)bc << 11));  // 4096 floats
    #pragma unroll
    for (int i = 0; i < 32; ++i) {
      int idx = t + (i << 8);
      int p = idx >> 6, j = idx & 63;
      int kyp = p & 63;
      float v;
      if (p < 64) v = (j < 32) ? ob[(kyp << 6) + (j << 1)]
                               : ob[(kyp << 6) + ((j - 32) << 1) + 1];
      else        v = (j < 32) ? -ob[(kyp << 6) + (j << 1) + 1]
                               : ob[(kyp << 6) + ((j - 32) << 1)];
      int byte = ((j << 8) + (p << 1)) ^ ((j & 7) << 4);
      *(unsigned short*)(smem + byte) = f2bf(v);
    }
  }
  __syncthreads();

  f32x16 acc[2][2];
  acc[0][0] = zero16(); acc[0][1] = zero16(); acc[1][0] = zero16(); acc[1][1] = zero16();
  #pragma unroll
  for (int s = 0; s < 8; ++s) {
    short8 af[2], bf[2];
    #pragma unroll
    for (int rt = 0; rt < 2; ++rt) {
      int row = (w << 6) + (rt << 5) + lr;
      af[rt] = *(const short8*)(A_E + (row << 7) + (s << 4) + (kg << 3));
    }
    #pragma unroll
    for (int ct = 0; ct < 2; ++ct) {
      int j = (ct << 5) + lr;
      int byte = ((j << 8) + (s << 5) + (kg << 4)) ^ ((j & 7) << 4);
      bf[ct] = *(const short8*)(smem + byte);
    }
    #pragma unroll
    for (int rt = 0; rt < 2; ++rt)
      #pragma unroll
      for (int ct = 0; ct < 2; ++ct)
        acc[rt][ct] = __builtin_amdgcn_mfma_f32_32x32x16_bf16(af[rt], bf[ct], acc[rt][ct], 0, 0, 0);
  }
  __syncthreads();   // all Mt reads complete before Tb overwrites [0,16384)

  #pragma unroll
  for (int rt = 0; rt < 2; ++rt)
    #pragma unroll
    for (int ct = 0; ct < 2; ++ct)
      #pragma unroll
      for (int r = 0; r < 16; ++r) {
        int row = (w << 6) + (rt << 5) + (r & 3) + (((r >> 2) & 3) << 3) + (kg << 2);
        int col = (ct << 5) + lr;
        int byte = ((row << 7) + (col << 1)) ^ ((row & 7) << 4);
        *(unsigned short*)(smem + byte) = f2bf(acc[rt][ct][r]);
      }
  __syncthreads();

  short8 ta[2][4];
  #pragma unroll
  for (int rt = 0; rt < 2; ++rt)
    #pragma unroll
    for (int ks = 0; ks < 4; ++ks) {
      int row = (w << 6) + (rt << 5) + lr;
      int byte = ((row << 7) + (ks << 5) + (kg << 4)) ^ ((row & 7) << 4);
      ta[rt][ks] = *(const short8*)(smem + byte);
    }
  float* op = out + ((size_t)bc << 16);
  #pragma unroll
  for (int cc = 0; cc < 4; ++cc) {
    short8 b2[2][4];
    #pragma unroll
    for (int cx = 0; cx < 2; ++cx)
      #pragma unroll
      for (int ks = 0; ks < 4; ++ks) {
        int xx = (cc << 6) + (cx << 5) + lr;
        b2[cx][ks] = *(const short8*)(B2T + (xx << 6) + (ks << 4) + (kg << 3));
      }
    f32x16 a2[2][2];
    a2[0][0] = zero16(); a2[0][1] = zero16(); a2[1][0] = zero16(); a2[1][1] = zero16();
    #pragma unroll
    for (int ks = 0; ks < 4; ++ks)
      #pragma unroll
      for (int rt = 0; rt < 2; ++rt)
        #pragma unroll
        for (int cx = 0; cx < 2; ++cx)
          a2[rt][cx] = __builtin_amdgcn_mfma_f32_32x32x16_bf16(ta[rt][ks], b2[cx][ks], a2[rt][cx], 0, 0, 0);
    #pragma unroll
    for (int rt = 0; rt < 2; ++rt)
      #pragma unroll
      for (int cx = 0; cx < 2; ++cx)
        #pragma unroll
        for (int r = 0; r < 16; ++r) {
          int row = (w << 6) + (rt << 5) + (r & 3) + (((r >> 2) & 3) << 3) + (kg << 2);
          int xx = (cc << 6) + (cx << 5) + lr;
          op[(row << 8) + xx] = a2[rt][cx][r];
        }
  }
}

// ---- host -------------------------------------------------------------------
extern "C" void kernel_launch(void* const* d_in, const int* in_sizes, int n_in,
                              void* d_out, int out_size, void* d_ws, size_t ws_size,
                              hipStream_t stream) {
  (void)in_sizes; (void)n_in; (void)out_size; (void)ws_size;
  const float* x   = (const float*)d_in[0];
  const float* w1  = (const float*)d_in[1];
  const float* w2  = (const float*)d_in[2];
  const float* er  = (const float*)d_in[3];
  const float* ei  = (const float*)d_in[4];
  const float* ar  = (const float*)d_in[5];
  const float* ai  = (const float*)d_in[6];
  const float* pr  = (const float*)d_in[7];
  const float* pim = (const float*)d_in[8];
  float* out = (float*)d_out;

  char* ws = (char*)d_ws;
  Hdr*    hdr      = (Hdr*)ws;
  float*  partials = (float*)(ws + 0x1000);
  float2* wsum     = (float2*)(ws + 0x10000);
  unsigned short* A_E = (unsigned short*)(ws + 0x130000);
  unsigned short* B2T = (unsigned short*)(ws + 0x140000);
  unsigned short* ET  = (unsigned short*)(ws + 0x148000);
  unsigned short* Fc  = (unsigned short*)(ws + 0x150000);
  unsigned short* Fs  = (unsigned short*)(ws + 0x158000);
  unsigned short* Fns = (unsigned short*)(ws + 0x160000);
  float4* spT      = (float4*)(ws + 0x200000);
  float2* G        = (float2*)(ws + 0x1400000);
  float2* oft      = (float2*)(ws + 0x1400000);   // aliases G (dead after s2)
  float2* noiseP   = (float2*)(ws + 0x2400000);
  float*  noiseL   = (float*)(ws + 0x3400000);

  auto splitk = [](const uint32_t k[2], uint32_t a[2], uint32_t b[2]) {
#if JPART
    tf2x32(k[0], k[1], 0u, 0u, a[0], a[1]);
    tf2x32(k[0], k[1], 0u, 1u, b[0], b[1]);
#else
    uint32_t r0[2], r1[2];
    tf2x32(k[0], k[1], 0u, 2u, r0[0], r0[1]);
    tf2x32(k[0], k[1], 1u, 3u, r1[0], r1[1]);
    a[0] = r0[0]; a[1] = r1[0]; b[0] = r0[1]; b[1] = r1[1];
#endif
  };
  uint32_t root[2] = { 0u, 42u };
  uint32_t kA[2], kB[2], k1A[2], k2A[2], k1B[2], k2B[2];
  splitk(root, kA, kB);
  splitk(kA, k1A, k2A);
  splitk(kB, k1B, k2B);
  KeyArgs ka;
  splitk(k1A, ka.k[0], ka.k[1]);
  splitk(k2A, ka.k[2], ka.k[3]);
  splitk(k1B, ka.k[4], ka.k[5]);
  splitk(k2B, ka.k[6], ka.k[7]);

  hipLaunchKernelGGL(k_misc,      dim3(961),      dim3(256), 0, stream, hdr, er, ei, ar, ai, pr, pim,
                     w1, w2, wsum, A_E, B2T, ET, Fc, Fs, Fns);
  hipLaunchKernelGGL(k_gen,       dim3(4608),     dim3(256), 0, stream, hdr, partials, spT, ka);
  hipLaunchKernelGGL(k_sumw2_fin, dim3(1),        dim3(64),  0, stream, hdr, partials);
  hipLaunchKernelGGL(k_fft_s1,    dim3(512),      dim3(256), 0, stream, spT, G);
  hipLaunchKernelGGL(k_fft_s2,    dim3(512),      dim3(256), 0, stream, G, noiseP, hdr);
  hipLaunchKernelGGL(k_ntrans,    dim3(512),      dim3(256), 0, stream, noiseP, noiseL, hdr);
  hipLaunchKernelGGL(k_forward,   dim3(1024),     dim3(256), 0, stream, x, wsum, noiseL, ET, Fc, Fs, Fns, oft);
  hipLaunchKernelGGL(k_inverse,   dim3(1024),     dim3(256), 0, stream, oft, A_E, B2T, out);
}